// Round 8
// baseline (69.653 us; speedup 1.0000x reference)
//
#include <hip/hip_runtime.h>
#include <cstddef>

#define N_NODES 4096
#define HIDDEN  256
#define NHEAD   4
#define DHEAD   64
#define EDGE_DIM 16
#define DEG     32
#define NEDGE   (N_NODES * DEG)
#define LN_EPS  1e-5f
#define QKV_STRIDE 768

typedef short  s16x8 __attribute__((ext_vector_type(8)));
typedef float  f32x4 __attribute__((ext_vector_type(4)));
typedef unsigned short u16x8 __attribute__((ext_vector_type(8)));
typedef unsigned short u16x4 __attribute__((ext_vector_type(4)));

__device__ __forceinline__ unsigned short f2b(float f) {
    union { float f; unsigned u; } c{f};
    unsigned u = c.u;
    return (unsigned short)((u + 0x7fffu + ((u >> 16) & 1u)) >> 16);
}
__device__ __forceinline__ float b2f(unsigned short s) {
    union { unsigned u; float f; } c;
    c.u = ((unsigned)s) << 16;
    return c.f;
}

// ---------------------------------------------------------------------------
// pack one 64x64 tile: fp32 src[K][Nn] -> bf16 dst[Nn][K] (transposed), via
// a caller-provided LDS tile (float [64][65]).
// ---------------------------------------------------------------------------
__device__ __forceinline__ void pack_tile(const float* __restrict__ src,
                                          unsigned short* __restrict__ dst,
                                          int K, int Nn, int tt, int rowoff,
                                          float (*tile)[65], int tid) {
    const int tk = K / 64;
    const int k0 = (tt % tk) * 64, n0 = (tt / tk) * 64;

    const int kk = tid >> 2, nq = (tid & 3) * 16;
#pragma unroll
    for (int i = 0; i < 16; i += 4) {
        float4 vv = *(const float4*)&src[(size_t)(k0 + kk) * Nn + n0 + nq + i];
        tile[kk][nq + i + 0] = vv.x;
        tile[kk][nq + i + 1] = vv.y;
        tile[kk][nq + i + 2] = vv.z;
        tile[kk][nq + i + 3] = vv.w;
    }
    __syncthreads();
    const int nn = tid >> 2, kq = (tid & 3) * 16;
    unsigned short tmp[16];
#pragma unroll
    for (int i = 0; i < 16; ++i) tmp[i] = f2b(tile[kq + i][nn]);
    unsigned short* drow = dst + (size_t)(rowoff + n0 + nn) * K + k0 + kq;
    *(u16x8*)(drow + 0) = *(u16x8*)&tmp[0];
    *(u16x8*)(drow + 8) = *(u16x8*)&tmp[8];
}

// ---------------------------------------------------------------------------
// pack_kernel (49 blocks): 0..47 pack Wqkv into [768][256]; 48 packs bias768.
// ---------------------------------------------------------------------------
__global__ __launch_bounds__(256) void pack_kernel(
    const float* __restrict__ Wq, const float* __restrict__ Wk,
    const float* __restrict__ Wv,
    const float* __restrict__ bq, const float* __restrict__ bk,
    const float* __restrict__ bv,
    unsigned short* __restrict__ Wqkv_t, float* __restrict__ bias768) {
    const int b = blockIdx.x;
    const int tid = threadIdx.x;
    __shared__ float tile[64][65];

    if (b < 48) {
        int m = b / 16, tt = b % 16;
        const float* src = (m == 0) ? Wq : ((m == 1) ? Wk : Wv);
        pack_tile(src, Wqkv_t, 256, 256, tt, m * 256, tile, tid);
    } else {
        bias768[tid]       = bq[tid];
        bias768[256 + tid] = bk[tid];
        bias768[512 + tid] = bv[tid];
    }
}

// ---------------------------------------------------------------------------
// gemm_qkv (912 blocks): 0..767 compute qkv bf16 = x(fp32) @ Wqkv_t^T + bias.
// Blocks 768..911 pack Wo (16), Wf1 (64), Wf2 (64) for later dispatches.
// ---------------------------------------------------------------------------
__global__ __launch_bounds__(256) void gemm_qkv(const float* __restrict__ X,
                                                const unsigned short* __restrict__ Bt,
                                                const float* __restrict__ bias,
                                                unsigned short* __restrict__ Cout,
                                                const float* __restrict__ Wo,
                                                const float* __restrict__ Wf1,
                                                const float* __restrict__ Wf2,
                                                unsigned short* __restrict__ Wo_t,
                                                unsigned short* __restrict__ Wf1_t,
                                                unsigned short* __restrict__ Wf2_t) {
    __shared__ __align__(16) char smem[64 * 65 * 4];   // union: gemm | pack
    const int bid = blockIdx.x;
    const int tid = threadIdx.x;

    if (bid >= 768) {                                   // ---- pack tail ----
        float (*tile)[65] = (float(*)[65])smem;
        const int b2 = bid - 768;
        if (b2 < 16)       pack_tile(Wo,  Wo_t,  256,  256,  b2,      0, tile, tid);
        else if (b2 < 80)  pack_tile(Wf1, Wf1_t, 256,  1024, b2 - 16, 0, tile, tid);
        else               pack_tile(Wf2, Wf2_t, 1024, 256,  b2 - 80, 0, tile, tid);
        return;
    }

    unsigned short* sA = (unsigned short*)smem;         // 8KB
    unsigned short* sB = sA + 64 * 64;                  // 8KB
    const int wave = tid >> 6, lane = tid & 63;
    const int row0 = (bid / 12) * 64, col0 = (bid % 12) * 64;
    const int wr = wave >> 1, wc = wave & 1;

    f32x4 acc[2][2] = {};

    const int lo0 = tid * 16, lo1 = lo0 + 4096;
    const int r0 = lo0 >> 7, c0 = lo0 & 127;
    const int r1 = lo1 >> 7, c1 = lo1 & 127;
    const int so0 = (lo0 & ~127) | (c0 ^ ((r0 & 7) << 4));
    const int so1 = (lo1 & ~127) | (c1 ^ ((r1 & 7) << 4));

    const int ar  = tid >> 2;
    const int akb = (tid & 3) * 16;
    const int acb = akb * 2;
    const int axr = (ar & 7) << 4;
    const int aso0 = (ar * 128) | ((acb +  0) ^ axr);
    const int aso1 = (ar * 128) | ((acb + 16) ^ axr);

    float4 f0, f1, f2v, f3;
    s16x8 b0r, b1r;

#define QKV_LOAD(KT)                                                          \
    {                                                                         \
        const float* Ap = X + (size_t)(row0 + ar) * 256 + (KT) * 64 + akb;    \
        f0  = *(const float4*)(Ap + 0);                                       \
        f1  = *(const float4*)(Ap + 4);                                       \
        f2v = *(const float4*)(Ap + 8);                                       \
        f3  = *(const float4*)(Ap + 12);                                      \
        const char* Bb = (const char*)Bt + ((size_t)col0 * 256 + (KT) * 64) * 2; \
        b0r = *(const s16x8*)(Bb + (size_t)r0 * 512 + c0);                    \
        b1r = *(const s16x8*)(Bb + (size_t)r1 * 512 + c1);                    \
    }

    QKV_LOAD(0);
#pragma unroll
    for (int kt = 0; kt < 4; ++kt) {
        if (kt) __syncthreads();
        u16x8 pa0 = {f2b(f0.x), f2b(f0.y), f2b(f0.z), f2b(f0.w),
                     f2b(f1.x), f2b(f1.y), f2b(f1.z), f2b(f1.w)};
        u16x8 pa1 = {f2b(f2v.x), f2b(f2v.y), f2b(f2v.z), f2b(f2v.w),
                     f2b(f3.x), f2b(f3.y), f2b(f3.z), f2b(f3.w)};
        *(u16x8*)((char*)sA + aso0) = pa0;
        *(u16x8*)((char*)sA + aso1) = pa1;
        *(s16x8*)((char*)sB + so0) = b0r;
        *(s16x8*)((char*)sB + so1) = b1r;
        __syncthreads();
        if (kt < 3) QKV_LOAD(kt + 1);

        const char* sAc = (const char*)sA;
        const char* sBc = (const char*)sB;
#pragma unroll
        for (int kk = 0; kk < 64; kk += 32) {
            const int koffb = (kk + ((lane >> 4) << 3)) * 2;
            s16x8 a[2], bfr[2];
#pragma unroll
            for (int m = 0; m < 2; ++m) {
                const int r = wr * 32 + m * 16 + (lane & 15);
                int off = r * 128 + koffb;
                off ^= (r & 7) << 4;
                a[m] = *(const s16x8*)(sAc + off);
            }
#pragma unroll
            for (int n = 0; n < 2; ++n) {
                const int c = wc * 32 + n * 16 + (lane & 15);
                int off = c * 128 + koffb;
                off ^= (c & 7) << 4;
                bfr[n] = *(const s16x8*)(sBc + off);
            }
#pragma unroll
            for (int m = 0; m < 2; ++m)
#pragma unroll
                for (int n = 0; n < 2; ++n)
                    acc[m][n] = __builtin_amdgcn_mfma_f32_16x16x32_bf16(
                        a[m], bfr[n], acc[m][n], 0, 0, 0);
        }
    }
#undef QKV_LOAD

    const int crow = row0 + wr * 32 + ((lane >> 4) << 2);
    const int ccol = col0 + wc * 32 + (lane & 15);
#pragma unroll
    for (int n = 0; n < 2; ++n) {
        const int c = ccol + n * 16;
        const float bv = bias[c];
#pragma unroll
        for (int m = 0; m < 2; ++m)
#pragma unroll
            for (int j = 0; j < 4; ++j)
                Cout[(size_t)(crow + m * 16 + j) * QKV_STRIDE + c] =
                    f2b(acc[m][n][j] + bv);
    }
}

// ---------------------------------------------------------------------------
// gemm_ln: fused C = A @ Bt^T + bias ; out = LayerNorm(resid + C)*g + b.
// BM=16 x 256 cols per block (grid = 256), 512 threads = 8 waves; wave w owns
// cols [w*32, w*32+32). LDS double-buffer + register prefetch.
// ---------------------------------------------------------------------------
template <int K, bool WRITE_BF16>
__global__ __launch_bounds__(512) void gemm_ln(const unsigned short* __restrict__ A,
                                               const unsigned short* __restrict__ Bt,
                                               const float* __restrict__ bias,
                                               const float* __restrict__ resid,
                                               const float* __restrict__ g,
                                               const float* __restrict__ b,
                                               float* __restrict__ out,
                                               unsigned short* __restrict__ outb) {
    constexpr int NT = K / 64;
    __shared__ unsigned short sA[2][16 * 64];    // 2 x 2KB
    __shared__ unsigned short sB[2][256 * 64];   // 2 x 32KB
    __shared__ float rs[16][8], rq[16][8];

    const int tid = threadIdx.x;
    const int wave = tid >> 6, lane = tid & 63;
    const int row0 = blockIdx.x * 16;

    f32x4 acc[2] = {};

    const int alo = tid * 16;                 // valid for tid < 128
    const int ar = alo >> 7, ac = alo & 127;
    const int aso = (alo & ~127) | (ac ^ ((ar & 7) << 4));

    s16x8 areg;
    s16x8 breg[4];

#define LN_LOAD(KT)                                                           \
    {                                                                         \
        if (tid < 128) {                                                      \
            const char* Ab = (const char*)A + ((size_t)row0 * K + (KT) * 64) * 2; \
            areg = *(const s16x8*)(Ab + (size_t)ar * (K * 2) + ac);           \
        }                                                                     \
        const char* Bb = (const char*)Bt + ((size_t)(KT) * 64) * 2;           \
        _Pragma("unroll")                                                     \
        for (int p = 0; p < 4; ++p) {                                         \
            const int lo = tid * 16 + p * 8192;                               \
            const int r = lo >> 7, c = lo & 127;                              \
            breg[p] = *(const s16x8*)(Bb + (size_t)r * (K * 2) + c);          \
        }                                                                     \
    }

#define LN_STORE(BUF)                                                         \
    {                                                                         \
        if (tid < 128) *(s16x8*)((char*)sA[BUF] + aso) = areg;                \
        _Pragma("unroll")                                                     \
        for (int p = 0; p < 4; ++p) {                                         \
            const int lo = tid * 16 + p * 8192;                               \
            const int r = lo >> 7, c = lo & 127;                              \
            const int so = (lo & ~127) | (c ^ ((r & 7) << 4));                \
            *(s16x8*)((char*)sB[BUF] + so) = breg[p];                         \
        }                                                                     \
    }

    LN_LOAD(0);
    LN_STORE(0);
    __syncthreads();

#pragma unroll
    for (int kt = 0; kt < NT; ++kt) {
        if (kt + 1 < NT) LN_LOAD(kt + 1);    // early-issue next tile

        const char* sAc = (const char*)sA[kt & 1];
        const char* sBc = (const char*)sB[kt & 1];
#pragma unroll
        for (int kk = 0; kk < 64; kk += 32) {
            const int koffb = (kk + ((lane >> 4) << 3)) * 2;
            s16x8 a;
            {
                const int r = lane & 15;
                int off = r * 128 + koffb;
                off ^= (r & 7) << 4;
                a = *(const s16x8*)(sAc + off);
            }
            s16x8 bfr[2];
#pragma unroll
            for (int n = 0; n < 2; ++n) {
                const int c = wave * 32 + n * 16 + (lane & 15);
                int off = c * 128 + koffb;
                off ^= (c & 7) << 4;
                bfr[n] = *(const s16x8*)(sBc + off);
            }
#pragma unroll
            for (int n = 0; n < 2; ++n)
                acc[n] = __builtin_amdgcn_mfma_f32_16x16x32_bf16(
                    a, bfr[n], acc[n], 0, 0, 0);
        }

        if (kt + 1 < NT) {
            LN_STORE((kt + 1) & 1);
            __syncthreads();
        }
    }
#undef LN_LOAD
#undef LN_STORE

    const int rbase = ((lane >> 4) << 2);
    const int cbase = wave * 32 + (lane & 15);

    float sm[4] = {}, sq_[4] = {};
#pragma unroll
    for (int n = 0; n < 2; ++n) {
        const int c = cbase + n * 16;
        const float bv = bias[c];
#pragma unroll
        for (int j = 0; j < 4; ++j) {
            const int r = rbase + j;
            float v = acc[n][j] + bv + resid[(size_t)(row0 + r) * HIDDEN + c];
            acc[n][j] = v;
            sm[j] += v;
            sq_[j] = fmaf(v, v, sq_[j]);
        }
    }
#pragma unroll
    for (int off = 8; off >= 1; off >>= 1) {
#pragma unroll
        for (int j = 0; j < 4; ++j) {
            sm[j] += __shfl_xor(sm[j], off);
            sq_[j] += __shfl_xor(sq_[j], off);
        }
    }
    if ((lane & 15) == 0) {
#pragma unroll
        for (int j = 0; j < 4; ++j) {
            rs[rbase + j][wave] = sm[j];
            rq[rbase + j][wave] = sq_[j];
        }
    }
    __syncthreads();

#pragma unroll
    for (int j = 0; j < 4; ++j) {
        const int r = rbase + j;
        float tot = 0.f, totq = 0.f;
#pragma unroll
        for (int w = 0; w < 8; ++w) { tot += rs[r][w]; totq += rq[r][w]; }
        const float mean = tot * (1.f / HIDDEN);
        const float var  = totq * (1.f / HIDDEN) - mean * mean;
        const float inv  = rsqrtf(var + LN_EPS);
#pragma unroll
        for (int n = 0; n < 2; ++n) {
            const int c = cbase + n * 16;
            const float res = (acc[n][j] - mean) * inv * g[c] + b[c];
            out[(size_t)(row0 + r) * HIDDEN + c] = res;
            if (WRITE_BF16)
                outb[(size_t)(row0 + r) * HIDDEN + c] = f2b(res);
        }
    }
}

// ---------------------------------------------------------------------------
// ffn_ln: fully fused FFN + LN2. Per block: rows [row0, row0+16).
// Phase A: h1[16][1024] = relu(yb @ Wf1_t^T + bf1) -> bf16 in LDS (swizzled).
// Phase B: C = h1 @ Wf2_t^T + bf2 ; out = LayerNorm(y + C)*g2 + b2.
// 512 thr = 8 waves; wave w owns 32 cols of each 256-col chunk.
// ---------------------------------------------------------------------------
__global__ __launch_bounds__(512) void ffn_ln(const unsigned short* __restrict__ yb,
                                              const float* __restrict__ y,
                                              const unsigned short* __restrict__ Wf1_t,
                                              const unsigned short* __restrict__ Wf2_t,
                                              const float* __restrict__ bf1,
                                              const float* __restrict__ bf2,
                                              const float* __restrict__ g,
                                              const float* __restrict__ b,
                                              float* __restrict__ out) {
    __shared__ unsigned short sB[2][256 * 64];   // 2 x 32KB staging (A & B phases)
    __shared__ unsigned short sA[16 * 256];      // 8KB: yb rows (phase A input)
    __shared__ unsigned short sH[16 * 1024];     // 32KB: h1 bf16
    __shared__ float rs[16][8], rq[16][8];

    const int tid = threadIdx.x;
    const int wave = tid >> 6, lane = tid & 63;
    const int row0 = blockIdx.x * 16;

    // ---- stage yb rows once: [16][256] bf16, swizzled ----
    {
        const int lo = tid * 16;               // 512 x 16B = 8KB
        const int r = lo >> 9, c = lo & 511;
        const int so = r * 512 + (c ^ ((r & 7) << 4));
        s16x8 v = *(const s16x8*)((const char*)yb + (size_t)(row0 + r) * 512 + c);
        *(s16x8*)((char*)sA + so) = v;
    }

    s16x8 breg[4];

    // B-tile staging maps (32KB -> 4 x 16B per thread), tile layout [256][64]
#define FFN_BLOAD(BB, KSTRIDE)                                                \
    {                                                                         \
        _Pragma("unroll")                                                     \
        for (int p = 0; p < 4; ++p) {                                         \
            const int lo = tid * 16 + p * 8192;                               \
            const int r = lo >> 7, c = lo & 127;                              \
            breg[p] = *(const s16x8*)((BB) + (size_t)r * (KSTRIDE) + c);      \
        }                                                                     \
    }
#define FFN_BSTORE(BUF)                                                       \
    {                                                                         \
        _Pragma("unroll")                                                     \
        for (int p = 0; p < 4; ++p) {                                         \
            const int lo = tid * 16 + p * 8192;                               \
            const int r = lo >> 7, c = lo & 127;                              \
            const int so = (lo & ~127) | (c ^ ((r & 7) << 4));                \
            *(s16x8*)((char*)sB[BUF] + so) = breg[p];                         \
        }                                                                     \
    }

    // ================= Phase A: h1 = relu(yb @ Wf1^T + bf1) =================
    // 16 steps: s = nchunk*4 + kt  (nchunk: 256-col chunk of h1; kt: K-tile)
#define FA_ADDR(S) ((const char*)Wf1_t + (size_t)((S) >> 2) * 131072 + ((S) & 3) * 128)

    FFN_BLOAD(FA_ADDR(0), 512);
    FFN_BSTORE(0);
    __syncthreads();

    f32x4 acc[2] = {};
#pragma unroll
    for (int s = 0; s < 16; ++s) {
        const int kt = s & 3;
        if ((s & 3) == 0) { acc[0] = (f32x4){}; acc[1] = (f32x4){}; }
        if (s + 1 < 16) FFN_BLOAD(FA_ADDR(s + 1), 512);

        const char* sBc = (const char*)sB[s & 1];
#pragma unroll
        for (int kk = 0; kk < 64; kk += 32) {
            const int lk = ((lane >> 4) << 3);
            s16x8 a;
            {
                const int r = lane & 15;
                const int koffb = (kt * 64 + kk + lk) * 2;
                a = *(const s16x8*)((const char*)sA + r * 512 + (koffb ^ ((r & 7) << 4)));
            }
            s16x8 bfr[2];
            const int boffb = (kk + lk) * 2;
#pragma unroll
            for (int n = 0; n < 2; ++n) {
                const int c = wave * 32 + n * 16 + (lane & 15);
                bfr[n] = *(const s16x8*)(sBc + c * 128 + (boffb ^ ((c & 7) << 4)));
            }
#pragma unroll
            for (int n = 0; n < 2; ++n)
                acc[n] = __builtin_amdgcn_mfma_f32_16x16x32_bf16(a, bfr[n], acc[n], 0, 0, 0);
        }

        if ((s & 3) == 3) {
            // h1 chunk done: bias + relu + bf16 -> sH (swizzled)
            const int nchunk = s >> 2;
            const int rb = ((lane >> 4) << 2);
#pragma unroll
            for (int n = 0; n < 2; ++n) {
                const int col = nchunk * 256 + wave * 32 + n * 16 + (lane & 15);
                const float bv = bf1[col];
#pragma unroll
                for (int j = 0; j < 4; ++j) {
                    const int r = rb + j;
                    const float v = fmaxf(acc[n][j] + bv, 0.f);
                    *(unsigned short*)((char*)sH + r * 2048 +
                                       ((col * 2) ^ ((r & 7) << 4))) = f2b(v);
                }
            }
        }
        if (s + 1 < 16) FFN_BSTORE((s + 1) & 1);
        __syncthreads();
    }
#undef FA_ADDR

    // ================= Phase B: out = LN(y + h1 @ Wf2^T + bf2) ==============
#define FB_ADDR(KT) ((const char*)Wf2_t + (size_t)(KT) * 128)

    FFN_BLOAD(FB_ADDR(0), 2048);
    FFN_BSTORE(0);
    __syncthreads();

    acc[0] = (f32x4){}; acc[1] = (f32x4){};
#pragma unroll
    for (int kt = 0; kt < 16; ++kt) {
        if (kt + 1 < 16) FFN_BLOAD(FB_ADDR(kt + 1), 2048);

        const char* sBc = (const char*)sB[kt & 1];
#pragma unroll
        for (int kk = 0; kk < 64; kk += 32) {
            const int lk = ((lane >> 4) << 3);
            s16x8 a;
            {
                const int r = lane & 15;
                const int koffb = (kt * 64 + kk + lk) * 2;
                a = *(const s16x8*)((const char*)sH + r * 2048 + (koffb ^ ((r & 7) << 4)));
            }
            s16x8 bfr[2];
            const int boffb = (kk + lk) * 2;
#pragma unroll
            for (int n = 0; n < 2; ++n) {
                const int c = wave * 32 + n * 16 + (lane & 15);
                bfr[n] = *(const s16x8*)(sBc + c * 128 + (boffb ^ ((c & 7) << 4)));
            }
#pragma unroll
            for (int n = 0; n < 2; ++n)
                acc[n] = __builtin_amdgcn_mfma_f32_16x16x32_bf16(a, bfr[n], acc[n], 0, 0, 0);
        }

        if (kt + 1 < 16) {
            FFN_BSTORE((kt + 1) & 1);
            __syncthreads();
        }
    }
#undef FB_ADDR
#undef FFN_BLOAD
#undef FFN_BSTORE

    // ---- LN2 epilogue ----
    const int rbase = ((lane >> 4) << 2);
    const int cbase = wave * 32 + (lane & 15);

    float sm[4] = {}, sq_[4] = {};
#pragma unroll
    for (int n = 0; n < 2; ++n) {
        const int c = cbase + n * 16;
        const float bv = bf2[c];
#pragma unroll
        for (int j = 0; j < 4; ++j) {
            const int r = rbase + j;
            float v = acc[n][j] + bv + y[(size_t)(row0 + r) * HIDDEN + c];
            acc[n][j] = v;
            sm[j] += v;
            sq_[j] = fmaf(v, v, sq_[j]);
        }
    }
#pragma unroll
    for (int off = 8; off >= 1; off >>= 1) {
#pragma unroll
        for (int j = 0; j < 4; ++j) {
            sm[j] += __shfl_xor(sm[j], off);
            sq_[j] += __shfl_xor(sq_[j], off);
        }
    }
    if ((lane & 15) == 0) {
#pragma unroll
        for (int j = 0; j < 4; ++j) {
            rs[rbase + j][wave] = sm[j];
            rq[rbase + j][wave] = sq_[j];
        }
    }
    __syncthreads();

#pragma unroll
    for (int j = 0; j < 4; ++j) {
        const int r = rbase + j;
        float tot = 0.f, totq = 0.f;
#pragma unroll
        for (int w = 0; w < 8; ++w) { tot += rs[r][w]; totq += rq[r][w]; }
        const float mean = tot * (1.f / HIDDEN);
        const float var  = totq * (1.f / HIDDEN) - mean * mean;
        const float inv  = rsqrtf(var + LN_EPS);
#pragma unroll
        for (int n = 0; n < 2; ++n) {
            const int c = cbase + n * 16;
            out[(size_t)(row0 + r) * HIDDEN + c] = (acc[n][j] - mean) * inv * g[c] + b[c];
        }
    }
}

// ---------------------------------------------------------------------------
// Attention on fused bf16 qkv [N][768]. One block per src node, wave = head.
// ---------------------------------------------------------------------------
__global__ __launch_bounds__(256) void attn_kernel(const unsigned short* __restrict__ qkv,
                                                   const int* __restrict__ edge_dst,
                                                   const float* __restrict__ edge_attr,
                                                   const float* __restrict__ We,
                                                   const float* __restrict__ be,
                                                   unsigned short* __restrict__ out) {
    const int n = blockIdx.x;
    const int tid = threadIdx.x;
    const int h = tid >> 6;
    const int lane = tid & 63;

    __shared__ float sQ[HIDDEN];
    __shared__ int   sDst[DEG];
    __shared__ float sWe[EDGE_DIM * NHEAD];
    __shared__ float sP[NHEAD][DEG];

    if (tid < HIDDEN) sQ[tid] = b2f(qkv[(size_t)n * QKV_STRIDE + tid]);
    if (tid < DEG) sDst[tid] = edge_dst[n * DEG + tid];
    if (tid < EDGE_DIM * NHEAD) sWe[tid] = We[tid];
    __syncthreads();

    const int j = lane & 31;
    const int half = lane >> 5;
    const int dstj = sDst[j];

    float dot = 0.f;
    const unsigned short* krow = qkv + (size_t)dstj * QKV_STRIDE + 256 + h * DHEAD + half * 32;
    const float* qrow = &sQ[h * DHEAD + half * 32];
#pragma unroll
    for (int q8 = 0; q8 < 4; ++q8) {
        u16x8 kv = *(const u16x8*)(krow + q8 * 8);
#pragma unroll
        for (int d = 0; d < 8; ++d)
            dot = fmaf(qrow[q8 * 8 + d], b2f(kv[d]), dot);
    }
    dot += __shfl_xor(dot, 32);
    dot *= 0.125f;

    float eb = be[h];
    const float* ea = edge_attr + (size_t)(n * DEG + j) * EDGE_DIM;
#pragma unroll
    for (int c = 0; c < EDGE_DIM; ++c) eb = fmaf(ea[c], sWe[c * NHEAD + h], eb);

    float logit = dot + eb;

    float mx = logit;
#pragma unroll
    for (int off = 16; off >= 1; off >>= 1) mx = fmaxf(mx, __shfl_xor(mx, off));
    float p = __expf(logit - mx);
    float sum = p;
#pragma unroll
    for (int off = 16; off >= 1; off >>= 1) sum += __shfl_xor(sum, off);
    p /= sum;
    if (half == 0) sP[h][j] = p;
    __syncthreads();

    float acc = 0.f;
    const int d = lane;
#pragma unroll 4
    for (int jj = 0; jj < DEG; ++jj) {
        acc = fmaf(sP[h][jj], b2f(qkv[(size_t)sDst[jj] * QKV_STRIDE + 512 + h * DHEAD + d]), acc);
    }
    out[(size_t)n * HIDDEN + h * DHEAD + d] = f2b(acc);
}

// ---------------------------------------------------------------------------
extern "C" void kernel_launch(void* const* d_in, const int* in_sizes, int n_in,
                              void* d_out, int out_size, void* d_ws, size_t ws_size,
                              hipStream_t stream) {
    const float* x   = (const float*)d_in[0];
    const int*   ei  = (const int*)d_in[1];
    const float* ea  = (const float*)d_in[2];
    const float* Wq  = (const float*)d_in[3];
    const float* bq  = (const float*)d_in[4];
    const float* Wk  = (const float*)d_in[5];
    const float* bk  = (const float*)d_in[6];
    const float* Wv  = (const float*)d_in[7];
    const float* bv  = (const float*)d_in[8];
    const float* Wo  = (const float*)d_in[9];
    const float* bo  = (const float*)d_in[10];
    const float* We  = (const float*)d_in[11];
    const float* be  = (const float*)d_in[12];
    const float* g1  = (const float*)d_in[13];
    const float* b1  = (const float*)d_in[14];
    const float* g2  = (const float*)d_in[15];
    const float* b2  = (const float*)d_in[16];
    const float* Wf1 = (const float*)d_in[17];
    const float* bf1 = (const float*)d_in[18];
    const float* Wf2 = (const float*)d_in[19];
    const float* bf2 = (const float*)d_in[20];

    // ---- workspace layout (all write-before-read within each call) ----
    char* W = (char*)d_ws;
    unsigned short* Wqkv_t  = (unsigned short*)(W + (2u << 20));                // 384KB
    unsigned short* Wo_t    = (unsigned short*)(W + (2u << 20) + 384 * 1024);   // 128KB
    unsigned short* Wf1_t   = (unsigned short*)(W + (2u << 20) + 512 * 1024);   // 512KB
    unsigned short* Wf2_t   = (unsigned short*)(W + (2u << 20) + 1024 * 1024);  // 512KB
    float*          bias768 = (float*)(W + (2u << 20) + 1536 * 1024);           // 3KB
    unsigned short* qkvb    = (unsigned short*)(W + (4u << 20));                // 6MB (dead after attn)
    float*          y       = (float*)(W + (12u << 20));                        // 4MB
    unsigned short* yb      = (unsigned short*)(W + (16u << 20));               // 2MB
    unsigned short* attnb   = (unsigned short*)(W + (18u << 20));               // 2MB

    const dim3 blk(256);

    pack_kernel<<<49, blk, 0, stream>>>(Wq, Wk, Wv, bq, bk, bv, Wqkv_t, bias768);

    gemm_qkv<<<912, blk, 0, stream>>>(x, Wqkv_t, bias768, qkvb,
                                      Wo, Wf1, Wf2, Wo_t, Wf1_t, Wf2_t);

    attn_kernel<<<N_NODES, blk, 0, stream>>>(qkvb, ei + NEDGE, ea, We, be, attnb);

    // O-proj + residual(x) + LN1 -> y (fp32) + yb (bf16)
    gemm_ln<256, true><<<N_NODES / 16, dim3(512), 0, stream>>>(
        attnb, Wo_t, bo, x, g1, b1, y, yb);

    // FFN1 + ReLU + FFN2 + residual(y) + LN2 -> d_out, all in one kernel
    ffn_ln<<<N_NODES / 16, dim3(512), 0, stream>>>(
        yb, y, Wf1_t, Wf2_t, bf1, bf2, g2, b2, (float*)d_out);
}

// Round 9
// 59.484 us; speedup vs baseline: 1.1710x; 1.1710x over previous
//
#include <hip/hip_runtime.h>
#include <cstddef>

#define N_NODES 4096
#define HIDDEN  256
#define NHEAD   4
#define DHEAD   64
#define EDGE_DIM 16
#define DEG     32
#define NEDGE   (N_NODES * DEG)
#define LN_EPS  1e-5f
#define QKV_STRIDE 768

typedef short  s16x8 __attribute__((ext_vector_type(8)));
typedef float  f32x4 __attribute__((ext_vector_type(4)));
typedef unsigned short u16x8 __attribute__((ext_vector_type(8)));
typedef unsigned short u16x4 __attribute__((ext_vector_type(4)));

__device__ __forceinline__ unsigned short f2b(float f) {
    union { float f; unsigned u; } c{f};
    unsigned u = c.u;
    return (unsigned short)((u + 0x7fffu + ((u >> 16) & 1u)) >> 16);
}
__device__ __forceinline__ float b2f(unsigned short s) {
    union { unsigned u; float f; } c;
    c.u = ((unsigned)s) << 16;
    return c.f;
}

// ---------------------------------------------------------------------------
// pack one 64x64 tile: fp32 src[K][Nn] -> bf16 dst[Nn][K] (transposed).
// ---------------------------------------------------------------------------
__device__ __forceinline__ void pack_tile(const float* __restrict__ src,
                                          unsigned short* __restrict__ dst,
                                          int K, int Nn, int tt, int rowoff,
                                          float (*tile)[65], int tid) {
    const int tk = K / 64;
    const int k0 = (tt % tk) * 64, n0 = (tt / tk) * 64;

    const int kk = tid >> 2, nq = (tid & 3) * 16;
#pragma unroll
    for (int i = 0; i < 16; i += 4) {
        float4 vv = *(const float4*)&src[(size_t)(k0 + kk) * Nn + n0 + nq + i];
        tile[kk][nq + i + 0] = vv.x;
        tile[kk][nq + i + 1] = vv.y;
        tile[kk][nq + i + 2] = vv.z;
        tile[kk][nq + i + 3] = vv.w;
    }
    __syncthreads();
    const int nn = tid >> 2, kq = (tid & 3) * 16;
    unsigned short tmp[16];
#pragma unroll
    for (int i = 0; i < 16; ++i) tmp[i] = f2b(tile[kq + i][nn]);
    unsigned short* drow = dst + (size_t)(rowoff + n0 + nn) * K + k0 + kq;
    *(u16x8*)(drow + 0) = *(u16x8*)&tmp[0];
    *(u16x8*)(drow + 8) = *(u16x8*)&tmp[8];
}

// ---------------------------------------------------------------------------
// pack_kernel (49 blocks): 0..47 pack Wqkv into [768][256]; 48 packs bias768.
// ---------------------------------------------------------------------------
__global__ __launch_bounds__(256) void pack_kernel(
    const float* __restrict__ Wq, const float* __restrict__ Wk,
    const float* __restrict__ Wv,
    const float* __restrict__ bq, const float* __restrict__ bk,
    const float* __restrict__ bv,
    unsigned short* __restrict__ Wqkv_t, float* __restrict__ bias768) {
    const int b = blockIdx.x;
    const int tid = threadIdx.x;
    __shared__ float tile[64][65];

    if (b < 48) {
        int m = b / 16, tt = b % 16;
        const float* src = (m == 0) ? Wq : ((m == 1) ? Wk : Wv);
        pack_tile(src, Wqkv_t, 256, 256, tt, m * 256, tile, tid);
    } else {
        bias768[tid]       = bq[tid];
        bias768[256 + tid] = bk[tid];
        bias768[512 + tid] = bv[tid];
    }
}

// ---------------------------------------------------------------------------
// gemm_qkv (912 blocks): 0..767 compute qkv bf16 = x(fp32) @ Wqkv_t^T + bias.
// Blocks 768..911 pack Wo (16), Wf1 (64), Wf2 (64) for later dispatches.
// ---------------------------------------------------------------------------
__global__ __launch_bounds__(256) void gemm_qkv(const float* __restrict__ X,
                                                const unsigned short* __restrict__ Bt,
                                                const float* __restrict__ bias,
                                                unsigned short* __restrict__ Cout,
                                                const float* __restrict__ Wo,
                                                const float* __restrict__ Wf1,
                                                const float* __restrict__ Wf2,
                                                unsigned short* __restrict__ Wo_t,
                                                unsigned short* __restrict__ Wf1_t,
                                                unsigned short* __restrict__ Wf2_t) {
    __shared__ __align__(16) char smem[64 * 65 * 4];   // union: gemm | pack
    const int bid = blockIdx.x;
    const int tid = threadIdx.x;

    if (bid >= 768) {                                   // ---- pack tail ----
        float (*tile)[65] = (float(*)[65])smem;
        const int b2 = bid - 768;
        if (b2 < 16)       pack_tile(Wo,  Wo_t,  256,  256,  b2,      0, tile, tid);
        else if (b2 < 80)  pack_tile(Wf1, Wf1_t, 256,  1024, b2 - 16, 0, tile, tid);
        else               pack_tile(Wf2, Wf2_t, 1024, 256,  b2 - 80, 0, tile, tid);
        return;
    }

    unsigned short* sA = (unsigned short*)smem;         // 8KB
    unsigned short* sB = sA + 64 * 64;                  // 8KB
    const int wave = tid >> 6, lane = tid & 63;
    const int row0 = (bid / 12) * 64, col0 = (bid % 12) * 64;
    const int wr = wave >> 1, wc = wave & 1;

    f32x4 acc[2][2] = {};

    const int lo0 = tid * 16, lo1 = lo0 + 4096;
    const int r0 = lo0 >> 7, c0 = lo0 & 127;
    const int r1 = lo1 >> 7, c1 = lo1 & 127;
    const int so0 = (lo0 & ~127) | (c0 ^ ((r0 & 7) << 4));
    const int so1 = (lo1 & ~127) | (c1 ^ ((r1 & 7) << 4));

    const int ar  = tid >> 2;
    const int akb = (tid & 3) * 16;
    const int acb = akb * 2;
    const int axr = (ar & 7) << 4;
    const int aso0 = (ar * 128) | ((acb +  0) ^ axr);
    const int aso1 = (ar * 128) | ((acb + 16) ^ axr);

    float4 f0, f1, f2v, f3;
    s16x8 b0r, b1r;

#define QKV_LOAD(KT)                                                          \
    {                                                                         \
        const float* Ap = X + (size_t)(row0 + ar) * 256 + (KT) * 64 + akb;    \
        f0  = *(const float4*)(Ap + 0);                                       \
        f1  = *(const float4*)(Ap + 4);                                       \
        f2v = *(const float4*)(Ap + 8);                                       \
        f3  = *(const float4*)(Ap + 12);                                      \
        const char* Bb = (const char*)Bt + ((size_t)col0 * 256 + (KT) * 64) * 2; \
        b0r = *(const s16x8*)(Bb + (size_t)r0 * 512 + c0);                    \
        b1r = *(const s16x8*)(Bb + (size_t)r1 * 512 + c1);                    \
    }

    QKV_LOAD(0);
#pragma unroll
    for (int kt = 0; kt < 4; ++kt) {
        if (kt) __syncthreads();
        u16x8 pa0 = {f2b(f0.x), f2b(f0.y), f2b(f0.z), f2b(f0.w),
                     f2b(f1.x), f2b(f1.y), f2b(f1.z), f2b(f1.w)};
        u16x8 pa1 = {f2b(f2v.x), f2b(f2v.y), f2b(f2v.z), f2b(f2v.w),
                     f2b(f3.x), f2b(f3.y), f2b(f3.z), f2b(f3.w)};
        *(u16x8*)((char*)sA + aso0) = pa0;
        *(u16x8*)((char*)sA + aso1) = pa1;
        *(s16x8*)((char*)sB + so0) = b0r;
        *(s16x8*)((char*)sB + so1) = b1r;
        __syncthreads();
        if (kt < 3) QKV_LOAD(kt + 1);

        const char* sAc = (const char*)sA;
        const char* sBc = (const char*)sB;
#pragma unroll
        for (int kk = 0; kk < 64; kk += 32) {
            const int koffb = (kk + ((lane >> 4) << 3)) * 2;
            s16x8 a[2], bfr[2];
#pragma unroll
            for (int m = 0; m < 2; ++m) {
                const int r = wr * 32 + m * 16 + (lane & 15);
                int off = r * 128 + koffb;
                off ^= (r & 7) << 4;
                a[m] = *(const s16x8*)(sAc + off);
            }
#pragma unroll
            for (int n = 0; n < 2; ++n) {
                const int c = wc * 32 + n * 16 + (lane & 15);
                int off = c * 128 + koffb;
                off ^= (c & 7) << 4;
                bfr[n] = *(const s16x8*)(sBc + off);
            }
#pragma unroll
            for (int m = 0; m < 2; ++m)
#pragma unroll
                for (int n = 0; n < 2; ++n)
                    acc[m][n] = __builtin_amdgcn_mfma_f32_16x16x32_bf16(
                        a[m], bfr[n], acc[m][n], 0, 0, 0);
        }
    }
#undef QKV_LOAD

    const int crow = row0 + wr * 32 + ((lane >> 4) << 2);
    const int ccol = col0 + wc * 32 + (lane & 15);
#pragma unroll
    for (int n = 0; n < 2; ++n) {
        const int c = ccol + n * 16;
        const float bv = bias[c];
#pragma unroll
        for (int m = 0; m < 2; ++m)
#pragma unroll
            for (int j = 0; j < 4; ++j)
                Cout[(size_t)(crow + m * 16 + j) * QKV_STRIDE + c] =
                    f2b(acc[m][n][j] + bv);
    }
}

// ---------------------------------------------------------------------------
// bf16 MFMA GEMM (64x64 tile, compile-time K): C = A @ Bt^T + bias.
// Register-rotate prefetch, XOR swizzle both sides. ReLU + bf16 out options.
// ---------------------------------------------------------------------------
template <int K, bool RELU, bool OUTB>
__global__ __launch_bounds__(256) void gemm_mfma(const unsigned short* __restrict__ A,
                                                 const unsigned short* __restrict__ Bt,
                                                 const float* __restrict__ bias,
                                                 void* __restrict__ Cout,
                                                 int Nn) {
    constexpr int NT = K / 64;
    __shared__ unsigned short sA[64 * 64];
    __shared__ unsigned short sB[64 * 64];
    const int tid = threadIdx.x;
    const int wave = tid >> 6, lane = tid & 63;
    const int row0 = blockIdx.y * 64, col0 = blockIdx.x * 64;
    const int wr = wave >> 1, wc = wave & 1;

    f32x4 acc[2][2] = {};

    const int lo0 = tid * 16;
    const int lo1 = lo0 + 4096;
    const int r0 = lo0 >> 7, c0 = lo0 & 127;
    const int r1 = lo1 >> 7, c1 = lo1 & 127;
    const int so0 = (lo0 & ~127) | (c0 ^ ((r0 & 7) << 4));
    const int so1 = (lo1 & ~127) | (c1 ^ ((r1 & 7) << 4));

    s16x8 a0r, a1r, b0r, b1r;

#define GM_LOAD(KT)                                                           \
    {                                                                         \
        const char* Ab = (const char*)A + ((size_t)row0 * K + (KT) * 64) * 2; \
        const char* Bb = (const char*)Bt + ((size_t)col0 * K + (KT) * 64) * 2;\
        a0r = *(const s16x8*)(Ab + (size_t)r0 * (K * 2) + c0);                \
        a1r = *(const s16x8*)(Ab + (size_t)r1 * (K * 2) + c1);                \
        b0r = *(const s16x8*)(Bb + (size_t)r0 * (K * 2) + c0);                \
        b1r = *(const s16x8*)(Bb + (size_t)r1 * (K * 2) + c1);                \
    }

    GM_LOAD(0);
#pragma unroll
    for (int kt = 0; kt < NT; ++kt) {
        if (kt) __syncthreads();
        *(s16x8*)((char*)sA + so0) = a0r;
        *(s16x8*)((char*)sA + so1) = a1r;
        *(s16x8*)((char*)sB + so0) = b0r;
        *(s16x8*)((char*)sB + so1) = b1r;
        __syncthreads();
        if (kt + 1 < NT) GM_LOAD(kt + 1);

        const char* sAc = (const char*)sA;
        const char* sBc = (const char*)sB;
#pragma unroll
        for (int kk = 0; kk < 64; kk += 32) {
            const int koffb = (kk + ((lane >> 4) << 3)) * 2;
            s16x8 a[2], bfr[2];
#pragma unroll
            for (int m = 0; m < 2; ++m) {
                const int r = wr * 32 + m * 16 + (lane & 15);
                int off = r * 128 + koffb;
                off ^= (r & 7) << 4;
                a[m] = *(const s16x8*)(sAc + off);
            }
#pragma unroll
            for (int n = 0; n < 2; ++n) {
                const int c = wc * 32 + n * 16 + (lane & 15);
                int off = c * 128 + koffb;
                off ^= (c & 7) << 4;
                bfr[n] = *(const s16x8*)(sBc + off);
            }
#pragma unroll
            for (int m = 0; m < 2; ++m)
#pragma unroll
                for (int n = 0; n < 2; ++n)
                    acc[m][n] = __builtin_amdgcn_mfma_f32_16x16x32_bf16(
                        a[m], bfr[n], acc[m][n], 0, 0, 0);
        }
    }
#undef GM_LOAD

    const int crow = row0 + wr * 32 + ((lane >> 4) << 2);
    const int ccol = col0 + wc * 32 + (lane & 15);
#pragma unroll
    for (int n = 0; n < 2; ++n) {
        const int c = ccol + n * 16;
        const float bv = bias[c];
#pragma unroll
        for (int m = 0; m < 2; ++m) {
#pragma unroll
            for (int j = 0; j < 4; ++j) {
                const int r = crow + m * 16 + j;
                float v = acc[m][n][j] + bv;
                if (RELU) v = fmaxf(v, 0.f);
                if (OUTB)
                    ((unsigned short*)Cout)[(size_t)r * Nn + c] = f2b(v);
                else
                    ((float*)Cout)[(size_t)r * Nn + c] = v;
            }
        }
    }
}

// ---------------------------------------------------------------------------
// gemm_partial: K-split FFN2. Grid (4 colTiles, 64 rowTiles, 4 kChunks).
// part[z][4096][256] (fp32) = h1b[:, z*256:(z+1)*256] @ Wf2_t[:, z*256:..]^T.
// ---------------------------------------------------------------------------
__global__ __launch_bounds__(256) void gemm_partial(const unsigned short* __restrict__ A,
                                                    const unsigned short* __restrict__ Bt,
                                                    float* __restrict__ part) {
    constexpr int KF = 1024;   // full K (row stride of A and Bt)
    __shared__ unsigned short sA[64 * 64];
    __shared__ unsigned short sB[64 * 64];
    const int tid = threadIdx.x;
    const int wave = tid >> 6, lane = tid & 63;
    const int row0 = blockIdx.y * 64, col0 = blockIdx.x * 64;
    const int z = blockIdx.z;
    const int wr = wave >> 1, wc = wave & 1;

    f32x4 acc[2][2] = {};

    const int lo0 = tid * 16;
    const int lo1 = lo0 + 4096;
    const int r0 = lo0 >> 7, c0 = lo0 & 127;
    const int r1 = lo1 >> 7, c1 = lo1 & 127;
    const int so0 = (lo0 & ~127) | (c0 ^ ((r0 & 7) << 4));
    const int so1 = (lo1 & ~127) | (c1 ^ ((r1 & 7) << 4));

    const char* Abase = (const char*)A + ((size_t)row0 * KF + z * 256) * 2;
    const char* Bbase = (const char*)Bt + ((size_t)col0 * KF + z * 256) * 2;

    s16x8 a0r, a1r, b0r, b1r;

#define GP_LOAD(KT)                                                           \
    {                                                                         \
        a0r = *(const s16x8*)(Abase + (KT) * 128 + (size_t)r0 * (KF * 2) + c0); \
        a1r = *(const s16x8*)(Abase + (KT) * 128 + (size_t)r1 * (KF * 2) + c1); \
        b0r = *(const s16x8*)(Bbase + (KT) * 128 + (size_t)r0 * (KF * 2) + c0); \
        b1r = *(const s16x8*)(Bbase + (KT) * 128 + (size_t)r1 * (KF * 2) + c1); \
    }

    GP_LOAD(0);
#pragma unroll
    for (int kt = 0; kt < 4; ++kt) {
        if (kt) __syncthreads();
        *(s16x8*)((char*)sA + so0) = a0r;
        *(s16x8*)((char*)sA + so1) = a1r;
        *(s16x8*)((char*)sB + so0) = b0r;
        *(s16x8*)((char*)sB + so1) = b1r;
        __syncthreads();
        if (kt + 1 < 4) GP_LOAD(kt + 1);

        const char* sAc = (const char*)sA;
        const char* sBc = (const char*)sB;
#pragma unroll
        for (int kk = 0; kk < 64; kk += 32) {
            const int koffb = (kk + ((lane >> 4) << 3)) * 2;
            s16x8 a[2], bfr[2];
#pragma unroll
            for (int m = 0; m < 2; ++m) {
                const int r = wr * 32 + m * 16 + (lane & 15);
                int off = r * 128 + koffb;
                off ^= (r & 7) << 4;
                a[m] = *(const s16x8*)(sAc + off);
            }
#pragma unroll
            for (int n = 0; n < 2; ++n) {
                const int c = wc * 32 + n * 16 + (lane & 15);
                int off = c * 128 + koffb;
                off ^= (c & 7) << 4;
                bfr[n] = *(const s16x8*)(sBc + off);
            }
#pragma unroll
            for (int m = 0; m < 2; ++m)
#pragma unroll
                for (int n = 0; n < 2; ++n)
                    acc[m][n] = __builtin_amdgcn_mfma_f32_16x16x32_bf16(
                        a[m], bfr[n], acc[m][n], 0, 0, 0);
        }
    }
#undef GP_LOAD

    const int crow = row0 + wr * 32 + ((lane >> 4) << 2);
    const int ccol = col0 + wc * 32 + (lane & 15);
    float* pz = part + (size_t)z * N_NODES * HIDDEN;
#pragma unroll
    for (int n = 0; n < 2; ++n) {
        const int c = ccol + n * 16;
#pragma unroll
        for (int m = 0; m < 2; ++m)
#pragma unroll
            for (int j = 0; j < 4; ++j)
                pz[(size_t)(crow + m * 16 + j) * HIDDEN + c] = acc[m][n][j];
    }
}

// ---------------------------------------------------------------------------
// ln2_reduce: out = LN(y + bf2 + sum_z part[z]) * g2 + b2. 256 blocks x 256
// thr; thread = (row = tid>>4, 16 cols at (tid&15)*16). Memory-bound.
// ---------------------------------------------------------------------------
__global__ __launch_bounds__(256) void ln2_reduce(const float* __restrict__ part,
                                                  const float* __restrict__ y,
                                                  const float* __restrict__ bf2,
                                                  const float* __restrict__ g2,
                                                  const float* __restrict__ b2,
                                                  float* __restrict__ out) {
    const int tid = threadIdx.x;
    const int row = blockIdx.x * 16 + (tid >> 4);
    const int cb = (tid & 15) * 16;
    const size_t rb = (size_t)row * HIDDEN;
    constexpr size_t ZS = (size_t)N_NODES * HIDDEN;

    float vals[16];
#pragma unroll
    for (int q = 0; q < 4; ++q) {
        const int c = cb + q * 4;
        float4 vy = *(const float4*)&y[rb + c];
        float4 vb = *(const float4*)&bf2[c];
        float4 s0 = *(const float4*)&part[0 * ZS + rb + c];
        float4 s1 = *(const float4*)&part[1 * ZS + rb + c];
        float4 s2 = *(const float4*)&part[2 * ZS + rb + c];
        float4 s3 = *(const float4*)&part[3 * ZS + rb + c];
        vals[q * 4 + 0] = vy.x + vb.x + s0.x + s1.x + s2.x + s3.x;
        vals[q * 4 + 1] = vy.y + vb.y + s0.y + s1.y + s2.y + s3.y;
        vals[q * 4 + 2] = vy.z + vb.z + s0.z + s1.z + s2.z + s3.z;
        vals[q * 4 + 3] = vy.w + vb.w + s0.w + s1.w + s2.w + s3.w;
    }
    float sm = 0.f, sq = 0.f;
#pragma unroll
    for (int i = 0; i < 16; ++i) { sm += vals[i]; sq = fmaf(vals[i], vals[i], sq); }
#pragma unroll
    for (int off = 8; off >= 1; off >>= 1) {
        sm += __shfl_xor(sm, off);
        sq += __shfl_xor(sq, off);
    }
    const float mean = sm * (1.f / HIDDEN);
    const float var  = sq * (1.f / HIDDEN) - mean * mean;
    const float inv  = rsqrtf(var + LN_EPS);
#pragma unroll
    for (int q = 0; q < 4; ++q) {
        const int c = cb + q * 4;
        float4 vg = *(const float4*)&g2[c];
        float4 vbb = *(const float4*)&b2[c];
        float4 o;
        o.x = (vals[q * 4 + 0] - mean) * inv * vg.x + vbb.x;
        o.y = (vals[q * 4 + 1] - mean) * inv * vg.y + vbb.y;
        o.z = (vals[q * 4 + 2] - mean) * inv * vg.z + vbb.z;
        o.w = (vals[q * 4 + 3] - mean) * inv * vg.w + vbb.w;
        *(float4*)&out[rb + c] = o;
    }
}

// ---------------------------------------------------------------------------
// attn_oproj_ln: fused attention + O-projection + residual + LN1.
// Block = 16 nodes, 512 thr (8 waves). Stage 1: logits+softmax (thread =
// (node, edge j), 4 heads each). Stage 2: PV -> sA bf16 swizzled. Stage 3:
// oproj MFMA (A from sA), residual x, LN1 -> y, yb.
// ---------------------------------------------------------------------------
__global__ __launch_bounds__(512) void attn_oproj_ln(
    const unsigned short* __restrict__ qkv,
    const int* __restrict__ edge_dst,
    const float* __restrict__ edge_attr,
    const float* __restrict__ We, const float* __restrict__ be,
    const unsigned short* __restrict__ Wo_t,
    const float* __restrict__ bo,
    const float* __restrict__ x,
    const float* __restrict__ g, const float* __restrict__ b,
    float* __restrict__ y, unsigned short* __restrict__ yb) {
    __shared__ float sQ[16][260];                 // ~16.6KB (fp32 q rows)
    __shared__ float sP[16][NHEAD][DEG];          // 8KB
    __shared__ int   sDst[16][DEG];               // 2KB
    __shared__ float sWe[EDGE_DIM * NHEAD];
    __shared__ unsigned short sA[16 * 256];       // 8KB attn-out (swizzled)
    __shared__ unsigned short sB[2][256 * 64];    // 64KB Wo staging
    __shared__ float rs[16][8], rq[16][8];

    const int tid = threadIdx.x;
    const int wave = tid >> 6, lane = tid & 63;
    const int n0 = blockIdx.x * 16;

    // stage q rows (bf16 -> fp32)
    {
        const int r = tid >> 5, e = (tid & 31) * 8;
        u16x8 v = *(const u16x8*)(qkv + (size_t)(n0 + r) * QKV_STRIDE + e);
#pragma unroll
        for (int i = 0; i < 8; ++i) sQ[r][e + i] = b2f(v[i]);
    }
    if (tid < EDGE_DIM * NHEAD) sWe[tid] = We[tid];
    __syncthreads();

    // ---- stage 1: logits + softmax ----
    {
        const int node = tid >> 5, j = tid & 31;
        const int dstj = edge_dst[(n0 + node) * DEG + j];
        sDst[node][j] = dstj;
        const unsigned short* kr = qkv + (size_t)dstj * QKV_STRIDE + 256;
        float lg[4];
#pragma unroll
        for (int h = 0; h < 4; ++h) {
            float dot = 0.f;
            const float* qh = &sQ[node][h * 64];
#pragma unroll
            for (int q8 = 0; q8 < 8; ++q8) {
                u16x8 kv = *(const u16x8*)(kr + h * 64 + q8 * 8);
#pragma unroll
                for (int d = 0; d < 8; ++d)
                    dot = fmaf(qh[q8 * 8 + d], b2f(kv[d]), dot);
            }
            lg[h] = dot * 0.125f + be[h];
        }
        const float* ea_ = edge_attr + (size_t)((n0 + node) * DEG + j) * EDGE_DIM;
#pragma unroll
        for (int c = 0; c < EDGE_DIM; ++c) {
            const float eav = ea_[c];
#pragma unroll
            for (int h = 0; h < 4; ++h)
                lg[h] = fmaf(eav, sWe[c * NHEAD + h], lg[h]);
        }
#pragma unroll
        for (int h = 0; h < 4; ++h) {
            float mx = lg[h];
#pragma unroll
            for (int off = 16; off >= 1; off >>= 1)
                mx = fmaxf(mx, __shfl_xor(mx, off));
            float p = __expf(lg[h] - mx);
            float sum = p;
#pragma unroll
            for (int off = 16; off >= 1; off >>= 1)
                sum += __shfl_xor(sum, off);
            sP[node][h][j] = p / sum;
        }
    }
    __syncthreads();

    // ---- stage 2: PV -> sA bf16 (XOR-swizzled 16B chunks) ----
    {
        const int node = tid >> 5, oct = tid & 31;
        const int h = oct >> 3;
        const int dbase = (oct & 7) * 8;
        float acc8[8] = {};
#pragma unroll 8
        for (int j = 0; j < DEG; ++j) {
            const float p = sP[node][h][j];
            const unsigned short* vr =
                qkv + (size_t)sDst[node][j] * QKV_STRIDE + 512 + h * 64 + dbase;
            u16x8 vv = *(const u16x8*)vr;
#pragma unroll
            for (int i = 0; i < 8; ++i) acc8[i] = fmaf(p, b2f(vv[i]), acc8[i]);
        }
        u16x8 pk;
#pragma unroll
        for (int i = 0; i < 8; ++i) pk[i] = f2b(acc8[i]);
        const int so = node * 512 + ((oct * 16) ^ ((node & 7) << 4));
        *(u16x8*)((char*)sA + so) = pk;
    }

    // ---- stage 3: oproj (K=256, 4 k-tiles, dbuf B staging) ----
    s16x8 breg[4];
#define WO_LOAD(KT)                                                           \
    {                                                                         \
        _Pragma("unroll")                                                     \
        for (int p = 0; p < 4; ++p) {                                         \
            const int lo = tid * 16 + p * 8192;                               \
            const int r = lo >> 7, c = lo & 127;                              \
            breg[p] = *(const s16x8*)((const char*)Wo_t + (size_t)r * 512 +   \
                                      (KT) * 128 + c);                        \
        }                                                                     \
    }
#define WO_STORE(BUF)                                                         \
    {                                                                         \
        _Pragma("unroll")                                                     \
        for (int p = 0; p < 4; ++p) {                                         \
            const int lo = tid * 16 + p * 8192;                               \
            const int r = lo >> 7, c = lo & 127;                              \
            const int so = (lo & ~127) | (c ^ ((r & 7) << 4));                \
            *(s16x8*)((char*)sB[BUF] + so) = breg[p];                         \
        }                                                                     \
    }

    WO_LOAD(0);
    WO_STORE(0);
    __syncthreads();     // also orders stage-2 sA writes before MFMA reads

    f32x4 acc[2] = {};
#pragma unroll
    for (int kt = 0; kt < 4; ++kt) {
        if (kt + 1 < 4) WO_LOAD(kt + 1);

        const char* sBc = (const char*)sB[kt & 1];
#pragma unroll
        for (int kk = 0; kk < 64; kk += 32) {
            const int lk = ((lane >> 4) << 3);
            s16x8 a;
            {
                const int r = lane & 15;
                const int koffb = (kt * 64 + kk + lk) * 2;
                a = *(const s16x8*)((const char*)sA + r * 512 +
                                    (koffb ^ ((r & 7) << 4)));
            }
            s16x8 bfr[2];
            const int boffb = (kk + lk) * 2;
#pragma unroll
            for (int n = 0; n < 2; ++n) {
                const int c = wave * 32 + n * 16 + (lane & 15);
                bfr[n] = *(const s16x8*)(sBc + c * 128 + (boffb ^ ((c & 7) << 4)));
            }
#pragma unroll
            for (int n = 0; n < 2; ++n)
                acc[n] = __builtin_amdgcn_mfma_f32_16x16x32_bf16(a, bfr[n], acc[n], 0, 0, 0);
        }

        if (kt + 1 < 4) {
            WO_STORE((kt + 1) & 1);
            __syncthreads();
        }
    }
#undef WO_LOAD
#undef WO_STORE

    // ---- LN1 epilogue (residual x) ----
    const int rbase = ((lane >> 4) << 2);
    const int cbase = wave * 32 + (lane & 15);

    float sm[4] = {}, sq_[4] = {};
#pragma unroll
    for (int n = 0; n < 2; ++n) {
        const int c = cbase + n * 16;
        const float bv = bo[c];
#pragma unroll
        for (int j = 0; j < 4; ++j) {
            const int r = rbase + j;
            float v = acc[n][j] + bv + x[(size_t)(n0 + r) * HIDDEN + c];
            acc[n][j] = v;
            sm[j] += v;
            sq_[j] = fmaf(v, v, sq_[j]);
        }
    }
#pragma unroll
    for (int off = 8; off >= 1; off >>= 1) {
#pragma unroll
        for (int j = 0; j < 4; ++j) {
            sm[j] += __shfl_xor(sm[j], off);
            sq_[j] += __shfl_xor(sq_[j], off);
        }
    }
    if ((lane & 15) == 0) {
#pragma unroll
        for (int j = 0; j < 4; ++j) {
            rs[rbase + j][wave] = sm[j];
            rq[rbase + j][wave] = sq_[j];
        }
    }
    __syncthreads();

#pragma unroll
    for (int j = 0; j < 4; ++j) {
        const int r = rbase + j;
        float tot = 0.f, totq = 0.f;
#pragma unroll
        for (int w = 0; w < 8; ++w) { tot += rs[r][w]; totq += rq[r][w]; }
        const float mean = tot * (1.f / HIDDEN);
        const float var  = totq * (1.f / HIDDEN) - mean * mean;
        const float inv  = rsqrtf(var + LN_EPS);
#pragma unroll
        for (int n = 0; n < 2; ++n) {
            const int c = cbase + n * 16;
            const float res = (acc[n][j] - mean) * inv * g[c] + b[c];
            y[(size_t)(n0 + r) * HIDDEN + c] = res;
            yb[(size_t)(n0 + r) * HIDDEN + c] = f2b(res);
        }
    }
}

// ---------------------------------------------------------------------------
extern "C" void kernel_launch(void* const* d_in, const int* in_sizes, int n_in,
                              void* d_out, int out_size, void* d_ws, size_t ws_size,
                              hipStream_t stream) {
    const float* x   = (const float*)d_in[0];
    const int*   ei  = (const int*)d_in[1];
    const float* ea  = (const float*)d_in[2];
    const float* Wq  = (const float*)d_in[3];
    const float* bq  = (const float*)d_in[4];
    const float* Wk  = (const float*)d_in[5];
    const float* bk  = (const float*)d_in[6];
    const float* Wv  = (const float*)d_in[7];
    const float* bv  = (const float*)d_in[8];
    const float* Wo  = (const float*)d_in[9];
    const float* bo  = (const float*)d_in[10];
    const float* We  = (const float*)d_in[11];
    const float* be  = (const float*)d_in[12];
    const float* g1  = (const float*)d_in[13];
    const float* b1  = (const float*)d_in[14];
    const float* g2  = (const float*)d_in[15];
    const float* b2  = (const float*)d_in[16];
    const float* Wf1 = (const float*)d_in[17];
    const float* bf1 = (const float*)d_in[18];
    const float* Wf2 = (const float*)d_in[19];
    const float* bf2 = (const float*)d_in[20];

    // ---- workspace layout (all write-before-read within each call) ----
    char* W = (char*)d_ws;
    unsigned short* Wqkv_t  = (unsigned short*)(W + (2u << 20));                // 384KB
    unsigned short* Wo_t    = (unsigned short*)(W + (2u << 20) + 384 * 1024);   // 128KB
    unsigned short* Wf1_t   = (unsigned short*)(W + (2u << 20) + 512 * 1024);   // 512KB
    unsigned short* Wf2_t   = (unsigned short*)(W + (2u << 20) + 1024 * 1024);  // 512KB
    float*          bias768 = (float*)(W + (2u << 20) + 1536 * 1024);           // 3KB
    unsigned short* qkvb    = (unsigned short*)(W + (4u << 20));                // 6MB (dead after attn_oproj)
    unsigned short* h1b     = (unsigned short*)(W + (4u << 20));                // 8MB (reuses qkvb region)
    float*          y       = (float*)(W + (12u << 20));                        // 4MB
    unsigned short* yb      = (unsigned short*)(W + (16u << 20));               // 2MB
    float*          part    = (float*)(W + (20u << 20));                        // 16MB [4][4096][256]

    const dim3 blk(256);

    pack_kernel<<<49, blk, 0, stream>>>(Wq, Wk, Wv, bq, bk, bv, Wqkv_t, bias768);

    gemm_qkv<<<912, blk, 0, stream>>>(x, Wqkv_t, bias768, qkvb,
                                      Wo, Wf1, Wf2, Wo_t, Wf1_t, Wf2_t);

    // attention + O-proj + residual(x) + LN1 -> y (fp32) + yb (bf16)
    attn_oproj_ln<<<N_NODES / 16, dim3(512), 0, stream>>>(
        qkvb, ei + NEDGE, ea, We, be, Wo_t, bo, x, g1, b1, y, yb);

    // FFN1 + ReLU -> h1b (bf16)
    gemm_mfma<256, true, true><<<dim3(16, 64), blk, 0, stream>>>(
        yb, Wf1_t, bf1, h1b, 4 * HIDDEN);

    // FFN2 K-split x4 -> fp32 partials
    gemm_partial<<<dim3(4, 64, 4), blk, 0, stream>>>(h1b, Wf2_t, part);

    // sum partials + residual(y) + LN2 -> d_out
    ln2_reduce<<<N_NODES / 16, blk, 0, stream>>>(part, y, bf2, g2, b2, (float*)d_out);
}

// Round 10
// 56.488 us; speedup vs baseline: 1.2331x; 1.0530x over previous
//
#include <hip/hip_runtime.h>
#include <cstddef>

#define N_NODES 4096
#define HIDDEN  256
#define NHEAD   4
#define DHEAD   64
#define EDGE_DIM 16
#define DEG     32
#define NEDGE   (N_NODES * DEG)
#define LN_EPS  1e-5f
#define QKV_STRIDE 768
#define KV_WIN  47

typedef short  s16x8 __attribute__((ext_vector_type(8)));
typedef float  f32x4 __attribute__((ext_vector_type(4)));
typedef unsigned short u16x8 __attribute__((ext_vector_type(8)));
typedef unsigned short u16x4 __attribute__((ext_vector_type(4)));

__device__ __forceinline__ unsigned short f2b(float f) {
    union { float f; unsigned u; } c{f};
    unsigned u = c.u;
    return (unsigned short)((u + 0x7fffu + ((u >> 16) & 1u)) >> 16);
}
__device__ __forceinline__ float b2f(unsigned short s) {
    union { unsigned u; float f; } c;
    c.u = ((unsigned)s) << 16;
    return c.f;
}

// ---------------------------------------------------------------------------
// pack one 64x64 tile: fp32 src[K][Nn] -> bf16 dst[Nn][K] (transposed).
// ---------------------------------------------------------------------------
__device__ __forceinline__ void pack_tile(const float* __restrict__ src,
                                          unsigned short* __restrict__ dst,
                                          int K, int Nn, int tt, int rowoff,
                                          float (*tile)[65], int tid) {
    const int tk = K / 64;
    const int k0 = (tt % tk) * 64, n0 = (tt / tk) * 64;

    const int kk = tid >> 2, nq = (tid & 3) * 16;
#pragma unroll
    for (int i = 0; i < 16; i += 4) {
        float4 vv = *(const float4*)&src[(size_t)(k0 + kk) * Nn + n0 + nq + i];
        tile[kk][nq + i + 0] = vv.x;
        tile[kk][nq + i + 1] = vv.y;
        tile[kk][nq + i + 2] = vv.z;
        tile[kk][nq + i + 3] = vv.w;
    }
    __syncthreads();
    const int nn = tid >> 2, kq = (tid & 3) * 16;
    unsigned short tmp[16];
#pragma unroll
    for (int i = 0; i < 16; ++i) tmp[i] = f2b(tile[kq + i][nn]);
    unsigned short* drow = dst + (size_t)(rowoff + n0 + nn) * K + k0 + kq;
    *(u16x8*)(drow + 0) = *(u16x8*)&tmp[0];
    *(u16x8*)(drow + 8) = *(u16x8*)&tmp[8];
}

// ---------------------------------------------------------------------------
// pack_kernel (49 blocks): 0..47 pack Wqkv into [768][256]; 48 packs bias768.
// ---------------------------------------------------------------------------
__global__ __launch_bounds__(256) void pack_kernel(
    const float* __restrict__ Wq, const float* __restrict__ Wk,
    const float* __restrict__ Wv,
    const float* __restrict__ bq, const float* __restrict__ bk,
    const float* __restrict__ bv,
    unsigned short* __restrict__ Wqkv_t, float* __restrict__ bias768) {
    const int b = blockIdx.x;
    const int tid = threadIdx.x;
    __shared__ float tile[64][65];

    if (b < 48) {
        int m = b / 16, tt = b % 16;
        const float* src = (m == 0) ? Wq : ((m == 1) ? Wk : Wv);
        pack_tile(src, Wqkv_t, 256, 256, tt, m * 256, tile, tid);
    } else {
        bias768[tid]       = bq[tid];
        bias768[256 + tid] = bk[tid];
        bias768[512 + tid] = bv[tid];
    }
}

// ---------------------------------------------------------------------------
// gemm_qkv (912 blocks): 0..767 compute qkv bf16 = x(fp32) @ Wqkv_t^T + bias.
// Blocks 768..911 pack Wo (16), Wf1 (64), Wf2 (64) for later dispatches.
// ---------------------------------------------------------------------------
__global__ __launch_bounds__(256) void gemm_qkv(const float* __restrict__ X,
                                                const unsigned short* __restrict__ Bt,
                                                const float* __restrict__ bias,
                                                unsigned short* __restrict__ Cout,
                                                const float* __restrict__ Wo,
                                                const float* __restrict__ Wf1,
                                                const float* __restrict__ Wf2,
                                                unsigned short* __restrict__ Wo_t,
                                                unsigned short* __restrict__ Wf1_t,
                                                unsigned short* __restrict__ Wf2_t) {
    __shared__ __align__(16) char smem[64 * 65 * 4];   // union: gemm | pack
    const int bid = blockIdx.x;
    const int tid = threadIdx.x;

    if (bid >= 768) {                                   // ---- pack tail ----
        float (*tile)[65] = (float(*)[65])smem;
        const int b2 = bid - 768;
        if (b2 < 16)       pack_tile(Wo,  Wo_t,  256,  256,  b2,      0, tile, tid);
        else if (b2 < 80)  pack_tile(Wf1, Wf1_t, 256,  1024, b2 - 16, 0, tile, tid);
        else               pack_tile(Wf2, Wf2_t, 1024, 256,  b2 - 80, 0, tile, tid);
        return;
    }

    unsigned short* sA = (unsigned short*)smem;         // 8KB
    unsigned short* sB = sA + 64 * 64;                  // 8KB
    const int wave = tid >> 6, lane = tid & 63;
    const int row0 = (bid / 12) * 64, col0 = (bid % 12) * 64;
    const int wr = wave >> 1, wc = wave & 1;

    f32x4 acc[2][2] = {};

    const int lo0 = tid * 16, lo1 = lo0 + 4096;
    const int r0 = lo0 >> 7, c0 = lo0 & 127;
    const int r1 = lo1 >> 7, c1 = lo1 & 127;
    const int so0 = (lo0 & ~127) | (c0 ^ ((r0 & 7) << 4));
    const int so1 = (lo1 & ~127) | (c1 ^ ((r1 & 7) << 4));

    const int ar  = tid >> 2;
    const int akb = (tid & 3) * 16;
    const int acb = akb * 2;
    const int axr = (ar & 7) << 4;
    const int aso0 = (ar * 128) | ((acb +  0) ^ axr);
    const int aso1 = (ar * 128) | ((acb + 16) ^ axr);

    float4 f0, f1, f2v, f3;
    s16x8 b0r, b1r;

#define QKV_LOAD(KT)                                                          \
    {                                                                         \
        const float* Ap = X + (size_t)(row0 + ar) * 256 + (KT) * 64 + akb;    \
        f0  = *(const float4*)(Ap + 0);                                       \
        f1  = *(const float4*)(Ap + 4);                                       \
        f2v = *(const float4*)(Ap + 8);                                       \
        f3  = *(const float4*)(Ap + 12);                                      \
        const char* Bb = (const char*)Bt + ((size_t)col0 * 256 + (KT) * 64) * 2; \
        b0r = *(const s16x8*)(Bb + (size_t)r0 * 512 + c0);                    \
        b1r = *(const s16x8*)(Bb + (size_t)r1 * 512 + c1);                    \
    }

    QKV_LOAD(0);
#pragma unroll
    for (int kt = 0; kt < 4; ++kt) {
        if (kt) __syncthreads();
        u16x8 pa0 = {f2b(f0.x), f2b(f0.y), f2b(f0.z), f2b(f0.w),
                     f2b(f1.x), f2b(f1.y), f2b(f1.z), f2b(f1.w)};
        u16x8 pa1 = {f2b(f2v.x), f2b(f2v.y), f2b(f2v.z), f2b(f2v.w),
                     f2b(f3.x), f2b(f3.y), f2b(f3.z), f2b(f3.w)};
        *(u16x8*)((char*)sA + aso0) = pa0;
        *(u16x8*)((char*)sA + aso1) = pa1;
        *(s16x8*)((char*)sB + so0) = b0r;
        *(s16x8*)((char*)sB + so1) = b1r;
        __syncthreads();
        if (kt < 3) QKV_LOAD(kt + 1);

        const char* sAc = (const char*)sA;
        const char* sBc = (const char*)sB;
#pragma unroll
        for (int kk = 0; kk < 64; kk += 32) {
            const int koffb = (kk + ((lane >> 4) << 3)) * 2;
            s16x8 a[2], bfr[2];
#pragma unroll
            for (int m = 0; m < 2; ++m) {
                const int r = wr * 32 + m * 16 + (lane & 15);
                int off = r * 128 + koffb;
                off ^= (r & 7) << 4;
                a[m] = *(const s16x8*)(sAc + off);
            }
#pragma unroll
            for (int n = 0; n < 2; ++n) {
                const int c = wc * 32 + n * 16 + (lane & 15);
                int off = c * 128 + koffb;
                off ^= (c & 7) << 4;
                bfr[n] = *(const s16x8*)(sBc + off);
            }
#pragma unroll
            for (int m = 0; m < 2; ++m)
#pragma unroll
                for (int n = 0; n < 2; ++n)
                    acc[m][n] = __builtin_amdgcn_mfma_f32_16x16x32_bf16(
                        a[m], bfr[n], acc[m][n], 0, 0, 0);
        }
    }
#undef QKV_LOAD

    const int crow = row0 + wr * 32 + ((lane >> 4) << 2);
    const int ccol = col0 + wc * 32 + (lane & 15);
#pragma unroll
    for (int n = 0; n < 2; ++n) {
        const int c = ccol + n * 16;
        const float bv = bias[c];
#pragma unroll
        for (int m = 0; m < 2; ++m)
#pragma unroll
            for (int j = 0; j < 4; ++j)
                Cout[(size_t)(crow + m * 16 + j) * QKV_STRIDE + c] =
                    f2b(acc[m][n][j] + bv);
    }
}

// ---------------------------------------------------------------------------
// bf16 MFMA GEMM (64x64 tile, compile-time K): C = A @ Bt^T + bias.
// ---------------------------------------------------------------------------
template <int K, bool RELU, bool OUTB>
__global__ __launch_bounds__(256) void gemm_mfma(const unsigned short* __restrict__ A,
                                                 const unsigned short* __restrict__ Bt,
                                                 const float* __restrict__ bias,
                                                 void* __restrict__ Cout,
                                                 int Nn) {
    constexpr int NT = K / 64;
    __shared__ unsigned short sA[64 * 64];
    __shared__ unsigned short sB[64 * 64];
    const int tid = threadIdx.x;
    const int wave = tid >> 6, lane = tid & 63;
    const int row0 = blockIdx.y * 64, col0 = blockIdx.x * 64;
    const int wr = wave >> 1, wc = wave & 1;

    f32x4 acc[2][2] = {};

    const int lo0 = tid * 16;
    const int lo1 = lo0 + 4096;
    const int r0 = lo0 >> 7, c0 = lo0 & 127;
    const int r1 = lo1 >> 7, c1 = lo1 & 127;
    const int so0 = (lo0 & ~127) | (c0 ^ ((r0 & 7) << 4));
    const int so1 = (lo1 & ~127) | (c1 ^ ((r1 & 7) << 4));

    s16x8 a0r, a1r, b0r, b1r;

#define GM_LOAD(KT)                                                           \
    {                                                                         \
        const char* Ab = (const char*)A + ((size_t)row0 * K + (KT) * 64) * 2; \
        const char* Bb = (const char*)Bt + ((size_t)col0 * K + (KT) * 64) * 2;\
        a0r = *(const s16x8*)(Ab + (size_t)r0 * (K * 2) + c0);                \
        a1r = *(const s16x8*)(Ab + (size_t)r1 * (K * 2) + c1);                \
        b0r = *(const s16x8*)(Bb + (size_t)r0 * (K * 2) + c0);                \
        b1r = *(const s16x8*)(Bb + (size_t)r1 * (K * 2) + c1);                \
    }

    GM_LOAD(0);
#pragma unroll
    for (int kt = 0; kt < NT; ++kt) {
        if (kt) __syncthreads();
        *(s16x8*)((char*)sA + so0) = a0r;
        *(s16x8*)((char*)sA + so1) = a1r;
        *(s16x8*)((char*)sB + so0) = b0r;
        *(s16x8*)((char*)sB + so1) = b1r;
        __syncthreads();
        if (kt + 1 < NT) GM_LOAD(kt + 1);

        const char* sAc = (const char*)sA;
        const char* sBc = (const char*)sB;
#pragma unroll
        for (int kk = 0; kk < 64; kk += 32) {
            const int koffb = (kk + ((lane >> 4) << 3)) * 2;
            s16x8 a[2], bfr[2];
#pragma unroll
            for (int m = 0; m < 2; ++m) {
                const int r = wr * 32 + m * 16 + (lane & 15);
                int off = r * 128 + koffb;
                off ^= (r & 7) << 4;
                a[m] = *(const s16x8*)(sAc + off);
            }
#pragma unroll
            for (int n = 0; n < 2; ++n) {
                const int c = wc * 32 + n * 16 + (lane & 15);
                int off = c * 128 + koffb;
                off ^= (c & 7) << 4;
                bfr[n] = *(const s16x8*)(sBc + off);
            }
#pragma unroll
            for (int m = 0; m < 2; ++m)
#pragma unroll
                for (int n = 0; n < 2; ++n)
                    acc[m][n] = __builtin_amdgcn_mfma_f32_16x16x32_bf16(
                        a[m], bfr[n], acc[m][n], 0, 0, 0);
        }
    }
#undef GM_LOAD

    const int crow = row0 + wr * 32 + ((lane >> 4) << 2);
    const int ccol = col0 + wc * 32 + (lane & 15);
#pragma unroll
    for (int n = 0; n < 2; ++n) {
        const int c = ccol + n * 16;
        const float bv = bias[c];
#pragma unroll
        for (int m = 0; m < 2; ++m) {
#pragma unroll
            for (int j = 0; j < 4; ++j) {
                const int r = crow + m * 16 + j;
                float v = acc[m][n][j] + bv;
                if (RELU) v = fmaxf(v, 0.f);
                if (OUTB)
                    ((unsigned short*)Cout)[(size_t)r * Nn + c] = f2b(v);
                else
                    ((float*)Cout)[(size_t)r * Nn + c] = v;
            }
        }
    }
}

// ---------------------------------------------------------------------------
// gemm_partial: K-split FFN2. Grid (4 colTiles, 64 rowTiles, 4 kChunks).
// part[z][4096][256] (fp32) = h1b[:, z*256:(z+1)*256] @ Wf2_t[:, z*256:..]^T.
// ---------------------------------------------------------------------------
__global__ __launch_bounds__(256) void gemm_partial(const unsigned short* __restrict__ A,
                                                    const unsigned short* __restrict__ Bt,
                                                    float* __restrict__ part) {
    constexpr int KF = 1024;   // full K (row stride of A and Bt)
    __shared__ unsigned short sA[64 * 64];
    __shared__ unsigned short sB[64 * 64];
    const int tid = threadIdx.x;
    const int wave = tid >> 6, lane = tid & 63;
    const int row0 = blockIdx.y * 64, col0 = blockIdx.x * 64;
    const int z = blockIdx.z;
    const int wr = wave >> 1, wc = wave & 1;

    f32x4 acc[2][2] = {};

    const int lo0 = tid * 16;
    const int lo1 = lo0 + 4096;
    const int r0 = lo0 >> 7, c0 = lo0 & 127;
    const int r1 = lo1 >> 7, c1 = lo1 & 127;
    const int so0 = (lo0 & ~127) | (c0 ^ ((r0 & 7) << 4));
    const int so1 = (lo1 & ~127) | (c1 ^ ((r1 & 7) << 4));

    const char* Abase = (const char*)A + ((size_t)row0 * KF + z * 256) * 2;
    const char* Bbase = (const char*)Bt + ((size_t)col0 * KF + z * 256) * 2;

    s16x8 a0r, a1r, b0r, b1r;

#define GP_LOAD(KT)                                                           \
    {                                                                         \
        a0r = *(const s16x8*)(Abase + (KT) * 128 + (size_t)r0 * (KF * 2) + c0); \
        a1r = *(const s16x8*)(Abase + (KT) * 128 + (size_t)r1 * (KF * 2) + c1); \
        b0r = *(const s16x8*)(Bbase + (KT) * 128 + (size_t)r0 * (KF * 2) + c0); \
        b1r = *(const s16x8*)(Bbase + (KT) * 128 + (size_t)r1 * (KF * 2) + c1); \
    }

    GP_LOAD(0);
#pragma unroll
    for (int kt = 0; kt < 4; ++kt) {
        if (kt) __syncthreads();
        *(s16x8*)((char*)sA + so0) = a0r;
        *(s16x8*)((char*)sA + so1) = a1r;
        *(s16x8*)((char*)sB + so0) = b0r;
        *(s16x8*)((char*)sB + so1) = b1r;
        __syncthreads();
        if (kt + 1 < 4) GP_LOAD(kt + 1);

        const char* sAc = (const char*)sA;
        const char* sBc = (const char*)sB;
#pragma unroll
        for (int kk = 0; kk < 64; kk += 32) {
            const int koffb = (kk + ((lane >> 4) << 3)) * 2;
            s16x8 a[2], bfr[2];
#pragma unroll
            for (int m = 0; m < 2; ++m) {
                const int r = wr * 32 + m * 16 + (lane & 15);
                int off = r * 128 + koffb;
                off ^= (r & 7) << 4;
                a[m] = *(const s16x8*)(sAc + off);
            }
#pragma unroll
            for (int n = 0; n < 2; ++n) {
                const int c = wc * 32 + n * 16 + (lane & 15);
                int off = c * 128 + koffb;
                off ^= (c & 7) << 4;
                bfr[n] = *(const s16x8*)(sBc + off);
            }
#pragma unroll
            for (int m = 0; m < 2; ++m)
#pragma unroll
                for (int n = 0; n < 2; ++n)
                    acc[m][n] = __builtin_amdgcn_mfma_f32_16x16x32_bf16(
                        a[m], bfr[n], acc[m][n], 0, 0, 0);
        }
    }
#undef GP_LOAD

    const int crow = row0 + wr * 32 + ((lane >> 4) << 2);
    const int ccol = col0 + wc * 32 + (lane & 15);
    float* pz = part + (size_t)z * N_NODES * HIDDEN;
#pragma unroll
    for (int n = 0; n < 2; ++n) {
        const int c = ccol + n * 16;
#pragma unroll
        for (int m = 0; m < 2; ++m)
#pragma unroll
            for (int j = 0; j < 4; ++j)
                pz[(size_t)(crow + m * 16 + j) * HIDDEN + c] = acc[m][n][j];
    }
}

// ---------------------------------------------------------------------------
// ln2_reduce: out = LN(y + bf2 + sum_z part[z]) * g2 + b2.
// ---------------------------------------------------------------------------
__global__ __launch_bounds__(256) void ln2_reduce(const float* __restrict__ part,
                                                  const float* __restrict__ y,
                                                  const float* __restrict__ bf2,
                                                  const float* __restrict__ g2,
                                                  const float* __restrict__ b2,
                                                  float* __restrict__ out) {
    const int tid = threadIdx.x;
    const int row = blockIdx.x * 16 + (tid >> 4);
    const int cb = (tid & 15) * 16;
    const size_t rb = (size_t)row * HIDDEN;
    constexpr size_t ZS = (size_t)N_NODES * HIDDEN;

    float vals[16];
#pragma unroll
    for (int q = 0; q < 4; ++q) {
        const int c = cb + q * 4;
        float4 vy = *(const float4*)&y[rb + c];
        float4 vb = *(const float4*)&bf2[c];
        float4 s0 = *(const float4*)&part[0 * ZS + rb + c];
        float4 s1 = *(const float4*)&part[1 * ZS + rb + c];
        float4 s2 = *(const float4*)&part[2 * ZS + rb + c];
        float4 s3 = *(const float4*)&part[3 * ZS + rb + c];
        vals[q * 4 + 0] = vy.x + vb.x + s0.x + s1.x + s2.x + s3.x;
        vals[q * 4 + 1] = vy.y + vb.y + s0.y + s1.y + s2.y + s3.y;
        vals[q * 4 + 2] = vy.z + vb.z + s0.z + s1.z + s2.z + s3.z;
        vals[q * 4 + 3] = vy.w + vb.w + s0.w + s1.w + s2.w + s3.w;
    }
    float sm = 0.f, sq = 0.f;
#pragma unroll
    for (int i = 0; i < 16; ++i) { sm += vals[i]; sq = fmaf(vals[i], vals[i], sq); }
#pragma unroll
    for (int off = 8; off >= 1; off >>= 1) {
        sm += __shfl_xor(sm, off);
        sq += __shfl_xor(sq, off);
    }
    const float mean = sm * (1.f / HIDDEN);
    const float var  = sq * (1.f / HIDDEN) - mean * mean;
    const float inv  = rsqrtf(var + LN_EPS);
#pragma unroll
    for (int q = 0; q < 4; ++q) {
        const int c = cb + q * 4;
        float4 vg = *(const float4*)&g2[c];
        float4 vbb = *(const float4*)&b2[c];
        float4 o;
        o.x = (vals[q * 4 + 0] - mean) * inv * vg.x + vbb.x;
        o.y = (vals[q * 4 + 1] - mean) * inv * vg.y + vbb.y;
        o.z = (vals[q * 4 + 2] - mean) * inv * vg.z + vbb.z;
        o.w = (vals[q * 4 + 3] - mean) * inv * vg.w + vbb.w;
        *(float4*)&out[rb + c] = o;
    }
}

// ---------------------------------------------------------------------------
// attn_oproj_ln: fused attention + O-projection + residual + LN1.
// Block = 16 nodes, 512 thr. NEW: K/V rows for the block's neighbor window
// [n0+1, n0+47] staged once into LDS (chunk-XOR swizzled); stages 1-2 read
// LDS instead of gathered global (~5x less L2 traffic, same math order).
// ---------------------------------------------------------------------------
__global__ __launch_bounds__(512) void attn_oproj_ln(
    const unsigned short* __restrict__ qkv,
    const int* __restrict__ edge_dst,
    const float* __restrict__ edge_attr,
    const float* __restrict__ We, const float* __restrict__ be,
    const unsigned short* __restrict__ Wo_t,
    const float* __restrict__ bo,
    const float* __restrict__ x,
    const float* __restrict__ g, const float* __restrict__ b,
    float* __restrict__ y, unsigned short* __restrict__ yb) {
    __shared__ float sQ[16][260];                 // ~16.6KB (fp32 q rows)
    __shared__ float sP[16][NHEAD][DEG];          // 8KB
    __shared__ int   sDst[16][DEG];               // 2KB
    __shared__ float sWe[EDGE_DIM * NHEAD];
    __shared__ unsigned short sKV[2][KV_WIN * 256];   // 2 x 23.5KB k|v window
    __shared__ unsigned short sA[16 * 256];       // 8KB attn-out (swizzled)
    __shared__ unsigned short sB[2][256 * 64];    // 64KB Wo staging
    __shared__ float rs[16][8], rq[16][8];

    const int tid = threadIdx.x;
    const int wave = tid >> 6, lane = tid & 63;
    const int n0 = blockIdx.x * 16;

    // stage q rows (bf16 -> fp32)
    {
        const int r = tid >> 5, e = (tid & 31) * 8;
        u16x8 v = *(const u16x8*)(qkv + (size_t)(n0 + r) * QKV_STRIDE + e);
#pragma unroll
        for (int i = 0; i < 8; ++i) sQ[r][e + i] = b2f(v[i]);
    }
    // stage K/V window rows (n0+1 .. n0+47) mod N, swizzled 16B chunks
    for (int t = tid; t < 2 * KV_WIN * 32; t += 512) {
        const int half = (t >= KV_WIN * 32) ? 1 : 0;
        const int tt = t - half * (KV_WIN * 32);
        const int rr = tt >> 5, c16 = tt & 31;
        const int gsrc = (n0 + 1 + rr) & (N_NODES - 1);
        u16x8 v = *(const u16x8*)(qkv + (size_t)gsrc * QKV_STRIDE +
                                  (half ? 512 : 256) + c16 * 8);
        const int so = rr * 512 + ((c16 ^ (rr & 7)) * 16);
        *(u16x8*)((char*)sKV[half] + so) = v;
    }
    if (tid < EDGE_DIM * NHEAD) sWe[tid] = We[tid];
    __syncthreads();

    // ---- stage 1: logits + softmax (K from LDS) ----
    {
        const int node = tid >> 5, j = tid & 31;
        const int dstj = edge_dst[(n0 + node) * DEG + j];
        sDst[node][j] = dstj;
        const int idx = (dstj - n0 - 1) & (N_NODES - 1);   // 0..46 (ring)
        const char* krow = (const char*)sKV[0] + idx * 512;
        const int swz = (idx & 7);
        float lg[4];
#pragma unroll
        for (int h = 0; h < 4; ++h) {
            float dot = 0.f;
            const float* qh = &sQ[node][h * 64];
#pragma unroll
            for (int q8 = 0; q8 < 8; ++q8) {
                const int c16 = h * 8 + q8;
                u16x8 kv = *(const u16x8*)(krow + ((c16 ^ swz) * 16));
#pragma unroll
                for (int d = 0; d < 8; ++d)
                    dot = fmaf(qh[q8 * 8 + d], b2f(kv[d]), dot);
            }
            lg[h] = dot * 0.125f + be[h];
        }
        const float* ea_ = edge_attr + (size_t)((n0 + node) * DEG + j) * EDGE_DIM;
#pragma unroll
        for (int c = 0; c < EDGE_DIM; ++c) {
            const float eav = ea_[c];
#pragma unroll
            for (int h = 0; h < 4; ++h)
                lg[h] = fmaf(eav, sWe[c * NHEAD + h], lg[h]);
        }
#pragma unroll
        for (int h = 0; h < 4; ++h) {
            float mx = lg[h];
#pragma unroll
            for (int off = 16; off >= 1; off >>= 1)
                mx = fmaxf(mx, __shfl_xor(mx, off));
            float p = __expf(lg[h] - mx);
            float sum = p;
#pragma unroll
            for (int off = 16; off >= 1; off >>= 1)
                sum += __shfl_xor(sum, off);
            sP[node][h][j] = p / sum;
        }
    }
    __syncthreads();

    // ---- stage 2: PV (V from LDS) -> sA bf16 (XOR-swizzled 16B chunks) ----
    {
        const int node = tid >> 5, oct = tid & 31;
        const int h = oct >> 3;
        const int chunk = oct;                    // h*8 + (oct&7) == oct
        float acc8[8] = {};
#pragma unroll 8
        for (int j = 0; j < DEG; ++j) {
            const float p = sP[node][h][j];
            const int idx = (sDst[node][j] - n0 - 1) & (N_NODES - 1);
            u16x8 vv = *(const u16x8*)((const char*)sKV[1] + idx * 512 +
                                       ((chunk ^ (idx & 7)) * 16));
#pragma unroll
            for (int i = 0; i < 8; ++i) acc8[i] = fmaf(p, b2f(vv[i]), acc8[i]);
        }
        u16x8 pk;
#pragma unroll
        for (int i = 0; i < 8; ++i) pk[i] = f2b(acc8[i]);
        const int so = node * 512 + ((oct * 16) ^ ((node & 7) << 4));
        *(u16x8*)((char*)sA + so) = pk;
    }

    // ---- stage 3: oproj (K=256, 4 k-tiles, dbuf B staging) ----
    s16x8 breg[4];
#define WO_LOAD(KT)                                                           \
    {                                                                         \
        _Pragma("unroll")                                                     \
        for (int p = 0; p < 4; ++p) {                                         \
            const int lo = tid * 16 + p * 8192;                               \
            const int r = lo >> 7, c = lo & 127;                              \
            breg[p] = *(const s16x8*)((const char*)Wo_t + (size_t)r * 512 +   \
                                      (KT) * 128 + c);                        \
        }                                                                     \
    }
#define WO_STORE(BUF)                                                         \
    {                                                                         \
        _Pragma("unroll")                                                     \
        for (int p = 0; p < 4; ++p) {                                         \
            const int lo = tid * 16 + p * 8192;                               \
            const int r = lo >> 7, c = lo & 127;                              \
            const int so = (lo & ~127) | (c ^ ((r & 7) << 4));                \
            *(s16x8*)((char*)sB[BUF] + so) = breg[p];                         \
        }                                                                     \
    }

    WO_LOAD(0);
    WO_STORE(0);
    __syncthreads();     // also orders stage-2 sA writes before MFMA reads

    f32x4 acc[2] = {};
#pragma unroll
    for (int kt = 0; kt < 4; ++kt) {
        if (kt + 1 < 4) WO_LOAD(kt + 1);

        const char* sBc = (const char*)sB[kt & 1];
#pragma unroll
        for (int kk = 0; kk < 64; kk += 32) {
            const int lk = ((lane >> 4) << 3);
            s16x8 a;
            {
                const int r = lane & 15;
                const int koffb = (kt * 64 + kk + lk) * 2;
                a = *(const s16x8*)((const char*)sA + r * 512 +
                                    (koffb ^ ((r & 7) << 4)));
            }
            s16x8 bfr[2];
            const int boffb = (kk + lk) * 2;
#pragma unroll
            for (int n = 0; n < 2; ++n) {
                const int c = wave * 32 + n * 16 + (lane & 15);
                bfr[n] = *(const s16x8*)(sBc + c * 128 + (boffb ^ ((c & 7) << 4)));
            }
#pragma unroll
            for (int n = 0; n < 2; ++n)
                acc[n] = __builtin_amdgcn_mfma_f32_16x16x32_bf16(a, bfr[n], acc[n], 0, 0, 0);
        }

        if (kt + 1 < 4) {
            WO_STORE((kt + 1) & 1);
            __syncthreads();
        }
    }
#undef WO_LOAD
#undef WO_STORE

    // ---- LN1 epilogue (residual x) ----
    const int rbase = ((lane >> 4) << 2);
    const int cbase = wave * 32 + (lane & 15);

    float sm[4] = {}, sq_[4] = {};
#pragma unroll
    for (int n = 0; n < 2; ++n) {
        const int c = cbase + n * 16;
        const float bv = bo[c];
#pragma unroll
        for (int j = 0; j < 4; ++j) {
            const int r = rbase + j;
            float v = acc[n][j] + bv + x[(size_t)(n0 + r) * HIDDEN + c];
            acc[n][j] = v;
            sm[j] += v;
            sq_[j] = fmaf(v, v, sq_[j]);
        }
    }
#pragma unroll
    for (int off = 8; off >= 1; off >>= 1) {
#pragma unroll
        for (int j = 0; j < 4; ++j) {
            sm[j] += __shfl_xor(sm[j], off);
            sq_[j] += __shfl_xor(sq_[j], off);
        }
    }
    if ((lane & 15) == 0) {
#pragma unroll
        for (int j = 0; j < 4; ++j) {
            rs[rbase + j][wave] = sm[j];
            rq[rbase + j][wave] = sq_[j];
        }
    }
    __syncthreads();

#pragma unroll
    for (int j = 0; j < 4; ++j) {
        const int r = rbase + j;
        float tot = 0.f, totq = 0.f;
#pragma unroll
        for (int w = 0; w < 8; ++w) { tot += rs[r][w]; totq += rq[r][w]; }
        const float mean = tot * (1.f / HIDDEN);
        const float var  = totq * (1.f / HIDDEN) - mean * mean;
        const float inv  = rsqrtf(var + LN_EPS);
#pragma unroll
        for (int n = 0; n < 2; ++n) {
            const int c = cbase + n * 16;
            const float res = (acc[n][j] - mean) * inv * g[c] + b[c];
            y[(size_t)(n0 + r) * HIDDEN + c] = res;
            yb[(size_t)(n0 + r) * HIDDEN + c] = f2b(res);
        }
    }
}

// ---------------------------------------------------------------------------
extern "C" void kernel_launch(void* const* d_in, const int* in_sizes, int n_in,
                              void* d_out, int out_size, void* d_ws, size_t ws_size,
                              hipStream_t stream) {
    const float* x   = (const float*)d_in[0];
    const int*   ei  = (const int*)d_in[1];
    const float* ea  = (const float*)d_in[2];
    const float* Wq  = (const float*)d_in[3];
    const float* bq  = (const float*)d_in[4];
    const float* Wk  = (const float*)d_in[5];
    const float* bk  = (const float*)d_in[6];
    const float* Wv  = (const float*)d_in[7];
    const float* bv  = (const float*)d_in[8];
    const float* Wo  = (const float*)d_in[9];
    const float* bo  = (const float*)d_in[10];
    const float* We  = (const float*)d_in[11];
    const float* be  = (const float*)d_in[12];
    const float* g1  = (const float*)d_in[13];
    const float* b1  = (const float*)d_in[14];
    const float* g2  = (const float*)d_in[15];
    const float* b2  = (const float*)d_in[16];
    const float* Wf1 = (const float*)d_in[17];
    const float* bf1 = (const float*)d_in[18];
    const float* Wf2 = (const float*)d_in[19];
    const float* bf2 = (const float*)d_in[20];

    // ---- workspace layout (all write-before-read within each call) ----
    char* W = (char*)d_ws;
    unsigned short* Wqkv_t  = (unsigned short*)(W + (2u << 20));                // 384KB
    unsigned short* Wo_t    = (unsigned short*)(W + (2u << 20) + 384 * 1024);   // 128KB
    unsigned short* Wf1_t   = (unsigned short*)(W + (2u << 20) + 512 * 1024);   // 512KB
    unsigned short* Wf2_t   = (unsigned short*)(W + (2u << 20) + 1024 * 1024);  // 512KB
    float*          bias768 = (float*)(W + (2u << 20) + 1536 * 1024);           // 3KB
    unsigned short* qkvb    = (unsigned short*)(W + (4u << 20));                // 6MB (dead after attn_oproj)
    unsigned short* h1b     = (unsigned short*)(W + (4u << 20));                // 8MB (reuses qkvb region)
    float*          y       = (float*)(W + (12u << 20));                        // 4MB
    unsigned short* yb      = (unsigned short*)(W + (16u << 20));               // 2MB
    float*          part    = (float*)(W + (20u << 20));                        // 16MB [4][4096][256]

    const dim3 blk(256);

    pack_kernel<<<49, blk, 0, stream>>>(Wq, Wk, Wv, bq, bk, bv, Wqkv_t, bias768);

    gemm_qkv<<<912, blk, 0, stream>>>(x, Wqkv_t, bias768, qkvb,
                                      Wo, Wf1, Wf2, Wo_t, Wf1_t, Wf2_t);

    // attention + O-proj + residual(x) + LN1 -> y (fp32) + yb (bf16)
    attn_oproj_ln<<<N_NODES / 16, dim3(512), 0, stream>>>(
        qkvb, ei + NEDGE, ea, We, be, Wo_t, bo, x, g1, b1, y, yb);

    // FFN1 + ReLU -> h1b (bf16)
    gemm_mfma<256, true, true><<<dim3(16, 64), blk, 0, stream>>>(
        yb, Wf1_t, bf1, h1b, 4 * HIDDEN);

    // FFN2 K-split x4 -> fp32 partials
    gemm_partial<<<dim3(4, 64, 4), blk, 0, stream>>>(h1b, Wf2_t, part);

    // sum partials + residual(y) + LN2 -> d_out
    ln2_reduce<<<N_NODES / 16, blk, 0, stream>>>(part, y, bf2, g2, b2, (float*)d_out);
}

// Round 11
// 55.537 us; speedup vs baseline: 1.2542x; 1.0171x over previous
//
#include <hip/hip_runtime.h>
#include <cstddef>

#define N_NODES 4096
#define HIDDEN  256
#define NHEAD   4
#define DHEAD   64
#define EDGE_DIM 16
#define DEG     32
#define NEDGE   (N_NODES * DEG)
#define LN_EPS  1e-5f
#define QKV_STRIDE 768
#define KV_WIN  47

typedef short  s16x8 __attribute__((ext_vector_type(8)));
typedef float  f32x4 __attribute__((ext_vector_type(4)));
typedef unsigned short u16x8 __attribute__((ext_vector_type(8)));
typedef unsigned short u16x4 __attribute__((ext_vector_type(4)));

__device__ __forceinline__ unsigned short f2b(float f) {
    union { float f; unsigned u; } c{f};
    unsigned u = c.u;
    return (unsigned short)((u + 0x7fffu + ((u >> 16) & 1u)) >> 16);
}
__device__ __forceinline__ float b2f(unsigned short s) {
    union { unsigned u; float f; } c;
    c.u = ((unsigned)s) << 16;
    return c.f;
}
// XCD-aware bijective swizzle: total must be divisible by 8. Each XCD gets a
// contiguous chunk of tile space (T1; m157/m192).
__device__ __forceinline__ int xcd_swz(int bid, int total) {
    const int q = total >> 3;
    return (bid & 7) * q + (bid >> 3);
}

// ---------------------------------------------------------------------------
// pack one 64x64 tile: fp32 src[K][Nn] -> bf16 dst[Nn][K] (transposed).
// ---------------------------------------------------------------------------
__device__ __forceinline__ void pack_tile(const float* __restrict__ src,
                                          unsigned short* __restrict__ dst,
                                          int K, int Nn, int tt, int rowoff,
                                          float (*tile)[65], int tid) {
    const int tk = K / 64;
    const int k0 = (tt % tk) * 64, n0 = (tt / tk) * 64;

    const int kk = tid >> 2, nq = (tid & 3) * 16;
#pragma unroll
    for (int i = 0; i < 16; i += 4) {
        float4 vv = *(const float4*)&src[(size_t)(k0 + kk) * Nn + n0 + nq + i];
        tile[kk][nq + i + 0] = vv.x;
        tile[kk][nq + i + 1] = vv.y;
        tile[kk][nq + i + 2] = vv.z;
        tile[kk][nq + i + 3] = vv.w;
    }
    __syncthreads();
    const int nn = tid >> 2, kq = (tid & 3) * 16;
    unsigned short tmp[16];
#pragma unroll
    for (int i = 0; i < 16; ++i) tmp[i] = f2b(tile[kq + i][nn]);
    unsigned short* drow = dst + (size_t)(rowoff + n0 + nn) * K + k0 + kq;
    *(u16x8*)(drow + 0) = *(u16x8*)&tmp[0];
    *(u16x8*)(drow + 8) = *(u16x8*)&tmp[8];
}

// ---------------------------------------------------------------------------
// pack_kernel (49 blocks): 0..47 pack Wqkv into [768][256]; 48 packs bias768.
// ---------------------------------------------------------------------------
__global__ __launch_bounds__(256) void pack_kernel(
    const float* __restrict__ Wq, const float* __restrict__ Wk,
    const float* __restrict__ Wv,
    const float* __restrict__ bq, const float* __restrict__ bk,
    const float* __restrict__ bv,
    unsigned short* __restrict__ Wqkv_t, float* __restrict__ bias768) {
    const int b = blockIdx.x;
    const int tid = threadIdx.x;
    __shared__ float tile[64][65];

    if (b < 48) {
        int m = b / 16, tt = b % 16;
        const float* src = (m == 0) ? Wq : ((m == 1) ? Wk : Wv);
        pack_tile(src, Wqkv_t, 256, 256, tt, m * 256, tile, tid);
    } else {
        bias768[tid]       = bq[tid];
        bias768[256 + tid] = bk[tid];
        bias768[512 + tid] = bv[tid];
    }
}

// ---------------------------------------------------------------------------
// gemm_qkv (912 blocks): 0..767 compute qkv bf16 = x(fp32) @ Wqkv_t^T + bias
// (XCD-swizzled tile mapping). Blocks 768..911 pack Wo/Wf1/Wf2.
// ---------------------------------------------------------------------------
__global__ __launch_bounds__(256) void gemm_qkv(const float* __restrict__ X,
                                                const unsigned short* __restrict__ Bt,
                                                const float* __restrict__ bias,
                                                unsigned short* __restrict__ Cout,
                                                const float* __restrict__ Wo,
                                                const float* __restrict__ Wf1,
                                                const float* __restrict__ Wf2,
                                                unsigned short* __restrict__ Wo_t,
                                                unsigned short* __restrict__ Wf1_t,
                                                unsigned short* __restrict__ Wf2_t) {
    __shared__ __align__(16) char smem[64 * 65 * 4];   // union: gemm | pack
    const int bid = blockIdx.x;
    const int tid = threadIdx.x;

    if (bid >= 768) {                                   // ---- pack tail ----
        float (*tile)[65] = (float(*)[65])smem;
        const int b2 = bid - 768;
        if (b2 < 16)       pack_tile(Wo,  Wo_t,  256,  256,  b2,      0, tile, tid);
        else if (b2 < 80)  pack_tile(Wf1, Wf1_t, 256,  1024, b2 - 16, 0, tile, tid);
        else               pack_tile(Wf2, Wf2_t, 1024, 256,  b2 - 80, 0, tile, tid);
        return;
    }

    unsigned short* sA = (unsigned short*)smem;         // 8KB
    unsigned short* sB = sA + 64 * 64;                  // 8KB
    const int wave = tid >> 6, lane = tid & 63;
    const int b2 = xcd_swz(bid, 768);
    const int row0 = (b2 / 12) * 64, col0 = (b2 % 12) * 64;
    const int wr = wave >> 1, wc = wave & 1;

    f32x4 acc[2][2] = {};

    const int lo0 = tid * 16, lo1 = lo0 + 4096;
    const int r0 = lo0 >> 7, c0 = lo0 & 127;
    const int r1 = lo1 >> 7, c1 = lo1 & 127;
    const int so0 = (lo0 & ~127) | (c0 ^ ((r0 & 7) << 4));
    const int so1 = (lo1 & ~127) | (c1 ^ ((r1 & 7) << 4));

    const int ar  = tid >> 2;
    const int akb = (tid & 3) * 16;
    const int acb = akb * 2;
    const int axr = (ar & 7) << 4;
    const int aso0 = (ar * 128) | ((acb +  0) ^ axr);
    const int aso1 = (ar * 128) | ((acb + 16) ^ axr);

    float4 f0, f1, f2v, f3;
    s16x8 b0r, b1r;

#define QKV_LOAD(KT)                                                          \
    {                                                                         \
        const float* Ap = X + (size_t)(row0 + ar) * 256 + (KT) * 64 + akb;    \
        f0  = *(const float4*)(Ap + 0);                                       \
        f1  = *(const float4*)(Ap + 4);                                       \
        f2v = *(const float4*)(Ap + 8);                                       \
        f3  = *(const float4*)(Ap + 12);                                      \
        const char* Bb = (const char*)Bt + ((size_t)col0 * 256 + (KT) * 64) * 2; \
        b0r = *(const s16x8*)(Bb + (size_t)r0 * 512 + c0);                    \
        b1r = *(const s16x8*)(Bb + (size_t)r1 * 512 + c1);                    \
    }

    QKV_LOAD(0);
#pragma unroll
    for (int kt = 0; kt < 4; ++kt) {
        if (kt) __syncthreads();
        u16x8 pa0 = {f2b(f0.x), f2b(f0.y), f2b(f0.z), f2b(f0.w),
                     f2b(f1.x), f2b(f1.y), f2b(f1.z), f2b(f1.w)};
        u16x8 pa1 = {f2b(f2v.x), f2b(f2v.y), f2b(f2v.z), f2b(f2v.w),
                     f2b(f3.x), f2b(f3.y), f2b(f3.z), f2b(f3.w)};
        *(u16x8*)((char*)sA + aso0) = pa0;
        *(u16x8*)((char*)sA + aso1) = pa1;
        *(s16x8*)((char*)sB + so0) = b0r;
        *(s16x8*)((char*)sB + so1) = b1r;
        __syncthreads();
        if (kt < 3) QKV_LOAD(kt + 1);

        const char* sAc = (const char*)sA;
        const char* sBc = (const char*)sB;
#pragma unroll
        for (int kk = 0; kk < 64; kk += 32) {
            const int koffb = (kk + ((lane >> 4) << 3)) * 2;
            s16x8 a[2], bfr[2];
#pragma unroll
            for (int m = 0; m < 2; ++m) {
                const int r = wr * 32 + m * 16 + (lane & 15);
                int off = r * 128 + koffb;
                off ^= (r & 7) << 4;
                a[m] = *(const s16x8*)(sAc + off);
            }
#pragma unroll
            for (int n = 0; n < 2; ++n) {
                const int c = wc * 32 + n * 16 + (lane & 15);
                int off = c * 128 + koffb;
                off ^= (c & 7) << 4;
                bfr[n] = *(const s16x8*)(sBc + off);
            }
#pragma unroll
            for (int m = 0; m < 2; ++m)
#pragma unroll
                for (int n = 0; n < 2; ++n)
                    acc[m][n] = __builtin_amdgcn_mfma_f32_16x16x32_bf16(
                        a[m], bfr[n], acc[m][n], 0, 0, 0);
        }
    }
#undef QKV_LOAD

    const int crow = row0 + wr * 32 + ((lane >> 4) << 2);
    const int ccol = col0 + wc * 32 + (lane & 15);
#pragma unroll
    for (int n = 0; n < 2; ++n) {
        const int c = ccol + n * 16;
        const float bv = bias[c];
#pragma unroll
        for (int m = 0; m < 2; ++m)
#pragma unroll
            for (int j = 0; j < 4; ++j)
                Cout[(size_t)(crow + m * 16 + j) * QKV_STRIDE + c] =
                    f2b(acc[m][n][j] + bv);
    }
}

// ---------------------------------------------------------------------------
// bf16 MFMA GEMM, 1D grid + XCD swizzle: C = A @ Bt^T + bias.
// grid = (M/64)*(Nn/64) blocks; tile = (b2/nct, b2%nct).
// ---------------------------------------------------------------------------
template <int K, bool RELU, bool OUTB>
__global__ __launch_bounds__(256) void gemm_mfma(const unsigned short* __restrict__ A,
                                                 const unsigned short* __restrict__ Bt,
                                                 const float* __restrict__ bias,
                                                 void* __restrict__ Cout,
                                                 int Nn, int nct, int total) {
    constexpr int NT = K / 64;
    __shared__ unsigned short sA[64 * 64];
    __shared__ unsigned short sB[64 * 64];
    const int tid = threadIdx.x;
    const int wave = tid >> 6, lane = tid & 63;
    const int b2 = xcd_swz(blockIdx.x, total);
    const int row0 = (b2 / nct) * 64, col0 = (b2 % nct) * 64;
    const int wr = wave >> 1, wc = wave & 1;

    f32x4 acc[2][2] = {};

    const int lo0 = tid * 16;
    const int lo1 = lo0 + 4096;
    const int r0 = lo0 >> 7, c0 = lo0 & 127;
    const int r1 = lo1 >> 7, c1 = lo1 & 127;
    const int so0 = (lo0 & ~127) | (c0 ^ ((r0 & 7) << 4));
    const int so1 = (lo1 & ~127) | (c1 ^ ((r1 & 7) << 4));

    s16x8 a0r, a1r, b0r, b1r;

#define GM_LOAD(KT)                                                           \
    {                                                                         \
        const char* Ab = (const char*)A + ((size_t)row0 * K + (KT) * 64) * 2; \
        const char* Bb = (const char*)Bt + ((size_t)col0 * K + (KT) * 64) * 2;\
        a0r = *(const s16x8*)(Ab + (size_t)r0 * (K * 2) + c0);                \
        a1r = *(const s16x8*)(Ab + (size_t)r1 * (K * 2) + c1);                \
        b0r = *(const s16x8*)(Bb + (size_t)r0 * (K * 2) + c0);                \
        b1r = *(const s16x8*)(Bb + (size_t)r1 * (K * 2) + c1);                \
    }

    GM_LOAD(0);
#pragma unroll
    for (int kt = 0; kt < NT; ++kt) {
        if (kt) __syncthreads();
        *(s16x8*)((char*)sA + so0) = a0r;
        *(s16x8*)((char*)sA + so1) = a1r;
        *(s16x8*)((char*)sB + so0) = b0r;
        *(s16x8*)((char*)sB + so1) = b1r;
        __syncthreads();
        if (kt + 1 < NT) GM_LOAD(kt + 1);

        const char* sAc = (const char*)sA;
        const char* sBc = (const char*)sB;
#pragma unroll
        for (int kk = 0; kk < 64; kk += 32) {
            const int koffb = (kk + ((lane >> 4) << 3)) * 2;
            s16x8 a[2], bfr[2];
#pragma unroll
            for (int m = 0; m < 2; ++m) {
                const int r = wr * 32 + m * 16 + (lane & 15);
                int off = r * 128 + koffb;
                off ^= (r & 7) << 4;
                a[m] = *(const s16x8*)(sAc + off);
            }
#pragma unroll
            for (int n = 0; n < 2; ++n) {
                const int c = wc * 32 + n * 16 + (lane & 15);
                int off = c * 128 + koffb;
                off ^= (c & 7) << 4;
                bfr[n] = *(const s16x8*)(sBc + off);
            }
#pragma unroll
            for (int m = 0; m < 2; ++m)
#pragma unroll
                for (int n = 0; n < 2; ++n)
                    acc[m][n] = __builtin_amdgcn_mfma_f32_16x16x32_bf16(
                        a[m], bfr[n], acc[m][n], 0, 0, 0);
        }
    }
#undef GM_LOAD

    const int crow = row0 + wr * 32 + ((lane >> 4) << 2);
    const int ccol = col0 + wc * 32 + (lane & 15);
#pragma unroll
    for (int n = 0; n < 2; ++n) {
        const int c = ccol + n * 16;
        const float bv = bias[c];
#pragma unroll
        for (int m = 0; m < 2; ++m) {
#pragma unroll
            for (int j = 0; j < 4; ++j) {
                const int r = crow + m * 16 + j;
                float v = acc[m][n][j] + bv;
                if (RELU) v = fmaxf(v, 0.f);
                if (OUTB)
                    ((unsigned short*)Cout)[(size_t)r * Nn + c] = f2b(v);
                else
                    ((float*)Cout)[(size_t)r * Nn + c] = v;
            }
        }
    }
}

// ---------------------------------------------------------------------------
// gemm_partial: K-split FFN2, z=2 chunks of 512. 1D grid 512 + XCD swizzle.
// part[z][4096][256] (fp32) = h1b[:, z*512:..] @ Wf2_t[:, z*512:..]^T.
// ---------------------------------------------------------------------------
__global__ __launch_bounds__(256) void gemm_partial(const unsigned short* __restrict__ A,
                                                    const unsigned short* __restrict__ Bt,
                                                    float* __restrict__ part) {
    constexpr int KF = 1024;   // full K (row stride of A and Bt)
    __shared__ unsigned short sA[64 * 64];
    __shared__ unsigned short sB[64 * 64];
    const int tid = threadIdx.x;
    const int wave = tid >> 6, lane = tid & 63;
    const int b2 = xcd_swz(blockIdx.x, 512);
    const int z = b2 >> 8;                       // 0..1
    const int rem = b2 & 255;
    const int row0 = (rem >> 2) * 64, col0 = (rem & 3) * 64;
    const int wr = wave >> 1, wc = wave & 1;

    f32x4 acc[2][2] = {};

    const int lo0 = tid * 16;
    const int lo1 = lo0 + 4096;
    const int r0 = lo0 >> 7, c0 = lo0 & 127;
    const int r1 = lo1 >> 7, c1 = lo1 & 127;
    const int so0 = (lo0 & ~127) | (c0 ^ ((r0 & 7) << 4));
    const int so1 = (lo1 & ~127) | (c1 ^ ((r1 & 7) << 4));

    const char* Abase = (const char*)A + ((size_t)row0 * KF + z * 512) * 2;
    const char* Bbase = (const char*)Bt + ((size_t)col0 * KF + z * 512) * 2;

    s16x8 a0r, a1r, b0r, b1r;

#define GP_LOAD(KT)                                                           \
    {                                                                         \
        a0r = *(const s16x8*)(Abase + (KT) * 128 + (size_t)r0 * (KF * 2) + c0); \
        a1r = *(const s16x8*)(Abase + (KT) * 128 + (size_t)r1 * (KF * 2) + c1); \
        b0r = *(const s16x8*)(Bbase + (KT) * 128 + (size_t)r0 * (KF * 2) + c0); \
        b1r = *(const s16x8*)(Bbase + (KT) * 128 + (size_t)r1 * (KF * 2) + c1); \
    }

    GP_LOAD(0);
#pragma unroll
    for (int kt = 0; kt < 8; ++kt) {
        if (kt) __syncthreads();
        *(s16x8*)((char*)sA + so0) = a0r;
        *(s16x8*)((char*)sA + so1) = a1r;
        *(s16x8*)((char*)sB + so0) = b0r;
        *(s16x8*)((char*)sB + so1) = b1r;
        __syncthreads();
        if (kt + 1 < 8) GP_LOAD(kt + 1);

        const char* sAc = (const char*)sA;
        const char* sBc = (const char*)sB;
#pragma unroll
        for (int kk = 0; kk < 64; kk += 32) {
            const int koffb = (kk + ((lane >> 4) << 3)) * 2;
            s16x8 a[2], bfr[2];
#pragma unroll
            for (int m = 0; m < 2; ++m) {
                const int r = wr * 32 + m * 16 + (lane & 15);
                int off = r * 128 + koffb;
                off ^= (r & 7) << 4;
                a[m] = *(const s16x8*)(sAc + off);
            }
#pragma unroll
            for (int n = 0; n < 2; ++n) {
                const int c = wc * 32 + n * 16 + (lane & 15);
                int off = c * 128 + koffb;
                off ^= (c & 7) << 4;
                bfr[n] = *(const s16x8*)(sBc + off);
            }
#pragma unroll
            for (int m = 0; m < 2; ++m)
#pragma unroll
                for (int n = 0; n < 2; ++n)
                    acc[m][n] = __builtin_amdgcn_mfma_f32_16x16x32_bf16(
                        a[m], bfr[n], acc[m][n], 0, 0, 0);
        }
    }
#undef GP_LOAD

    const int crow = row0 + wr * 32 + ((lane >> 4) << 2);
    const int ccol = col0 + wc * 32 + (lane & 15);
    float* pz = part + (size_t)z * N_NODES * HIDDEN;
#pragma unroll
    for (int n = 0; n < 2; ++n) {
        const int c = ccol + n * 16;
#pragma unroll
        for (int m = 0; m < 2; ++m)
#pragma unroll
            for (int j = 0; j < 4; ++j)
                pz[(size_t)(crow + m * 16 + j) * HIDDEN + c] = acc[m][n][j];
    }
}

// ---------------------------------------------------------------------------
// ln2_reduce: out = LN(y + bf2 + part[0] + part[1]) * g2 + b2.
// ---------------------------------------------------------------------------
__global__ __launch_bounds__(256) void ln2_reduce(const float* __restrict__ part,
                                                  const float* __restrict__ y,
                                                  const float* __restrict__ bf2,
                                                  const float* __restrict__ g2,
                                                  const float* __restrict__ b2,
                                                  float* __restrict__ out) {
    const int tid = threadIdx.x;
    const int row = blockIdx.x * 16 + (tid >> 4);
    const int cb = (tid & 15) * 16;
    const size_t rb = (size_t)row * HIDDEN;
    constexpr size_t ZS = (size_t)N_NODES * HIDDEN;

    float vals[16];
#pragma unroll
    for (int q = 0; q < 4; ++q) {
        const int c = cb + q * 4;
        float4 vy = *(const float4*)&y[rb + c];
        float4 vb = *(const float4*)&bf2[c];
        float4 s0 = *(const float4*)&part[0 * ZS + rb + c];
        float4 s1 = *(const float4*)&part[1 * ZS + rb + c];
        vals[q * 4 + 0] = vy.x + vb.x + s0.x + s1.x;
        vals[q * 4 + 1] = vy.y + vb.y + s0.y + s1.y;
        vals[q * 4 + 2] = vy.z + vb.z + s0.z + s1.z;
        vals[q * 4 + 3] = vy.w + vb.w + s0.w + s1.w;
    }
    float sm = 0.f, sq = 0.f;
#pragma unroll
    for (int i = 0; i < 16; ++i) { sm += vals[i]; sq = fmaf(vals[i], vals[i], sq); }
#pragma unroll
    for (int off = 8; off >= 1; off >>= 1) {
        sm += __shfl_xor(sm, off);
        sq += __shfl_xor(sq, off);
    }
    const float mean = sm * (1.f / HIDDEN);
    const float var  = sq * (1.f / HIDDEN) - mean * mean;
    const float inv  = rsqrtf(var + LN_EPS);
#pragma unroll
    for (int q = 0; q < 4; ++q) {
        const int c = cb + q * 4;
        float4 vg = *(const float4*)&g2[c];
        float4 vbb = *(const float4*)&b2[c];
        float4 o;
        o.x = (vals[q * 4 + 0] - mean) * inv * vg.x + vbb.x;
        o.y = (vals[q * 4 + 1] - mean) * inv * vg.y + vbb.y;
        o.z = (vals[q * 4 + 2] - mean) * inv * vg.z + vbb.z;
        o.w = (vals[q * 4 + 3] - mean) * inv * vg.w + vbb.w;
        *(float4*)&out[rb + c] = o;
    }
}

// ---------------------------------------------------------------------------
// attn_oproj_ln: fused attention + O-projection + residual + LN1.
// Block = 16 nodes, 512 thr. K/V window [n0+1, n0+47] staged once into LDS.
// ---------------------------------------------------------------------------
__global__ __launch_bounds__(512) void attn_oproj_ln(
    const unsigned short* __restrict__ qkv,
    const int* __restrict__ edge_dst,
    const float* __restrict__ edge_attr,
    const float* __restrict__ We, const float* __restrict__ be,
    const unsigned short* __restrict__ Wo_t,
    const float* __restrict__ bo,
    const float* __restrict__ x,
    const float* __restrict__ g, const float* __restrict__ b,
    float* __restrict__ y, unsigned short* __restrict__ yb) {
    __shared__ float sQ[16][260];                 // ~16.6KB (fp32 q rows)
    __shared__ float sP[16][NHEAD][DEG];          // 8KB
    __shared__ int   sDst[16][DEG];               // 2KB
    __shared__ float sWe[EDGE_DIM * NHEAD];
    __shared__ unsigned short sKV[2][KV_WIN * 256];   // 2 x 23.5KB k|v window
    __shared__ unsigned short sA[16 * 256];       // 8KB attn-out (swizzled)
    __shared__ unsigned short sB[2][256 * 64];    // 64KB Wo staging
    __shared__ float rs[16][8], rq[16][8];

    const int tid = threadIdx.x;
    const int wave = tid >> 6, lane = tid & 63;
    const int n0 = blockIdx.x * 16;

    // stage q rows (bf16 -> fp32)
    {
        const int r = tid >> 5, e = (tid & 31) * 8;
        u16x8 v = *(const u16x8*)(qkv + (size_t)(n0 + r) * QKV_STRIDE + e);
#pragma unroll
        for (int i = 0; i < 8; ++i) sQ[r][e + i] = b2f(v[i]);
    }
    // stage K/V window rows (n0+1 .. n0+47) mod N, swizzled 16B chunks
    for (int t = tid; t < 2 * KV_WIN * 32; t += 512) {
        const int half = (t >= KV_WIN * 32) ? 1 : 0;
        const int tt = t - half * (KV_WIN * 32);
        const int rr = tt >> 5, c16 = tt & 31;
        const int gsrc = (n0 + 1 + rr) & (N_NODES - 1);
        u16x8 v = *(const u16x8*)(qkv + (size_t)gsrc * QKV_STRIDE +
                                  (half ? 512 : 256) + c16 * 8);
        const int so = rr * 512 + ((c16 ^ (rr & 7)) * 16);
        *(u16x8*)((char*)sKV[half] + so) = v;
    }
    if (tid < EDGE_DIM * NHEAD) sWe[tid] = We[tid];
    __syncthreads();

    // ---- stage 1: logits + softmax (K from LDS) ----
    {
        const int node = tid >> 5, j = tid & 31;
        const int dstj = edge_dst[(n0 + node) * DEG + j];
        sDst[node][j] = dstj;
        const int idx = (dstj - n0 - 1) & (N_NODES - 1);   // 0..46 (ring)
        const char* krow = (const char*)sKV[0] + idx * 512;
        const int swz = (idx & 7);
        float lg[4];
#pragma unroll
        for (int h = 0; h < 4; ++h) {
            float dot = 0.f;
            const float* qh = &sQ[node][h * 64];
#pragma unroll
            for (int q8 = 0; q8 < 8; ++q8) {
                const int c16 = h * 8 + q8;
                u16x8 kv = *(const u16x8*)(krow + ((c16 ^ swz) * 16));
#pragma unroll
                for (int d = 0; d < 8; ++d)
                    dot = fmaf(qh[q8 * 8 + d], b2f(kv[d]), dot);
            }
            lg[h] = dot * 0.125f + be[h];
        }
        const float* ea_ = edge_attr + (size_t)((n0 + node) * DEG + j) * EDGE_DIM;
#pragma unroll
        for (int c = 0; c < EDGE_DIM; ++c) {
            const float eav = ea_[c];
#pragma unroll
            for (int h = 0; h < 4; ++h)
                lg[h] = fmaf(eav, sWe[c * NHEAD + h], lg[h]);
        }
#pragma unroll
        for (int h = 0; h < 4; ++h) {
            float mx = lg[h];
#pragma unroll
            for (int off = 16; off >= 1; off >>= 1)
                mx = fmaxf(mx, __shfl_xor(mx, off));
            float p = __expf(lg[h] - mx);
            float sum = p;
#pragma unroll
            for (int off = 16; off >= 1; off >>= 1)
                sum += __shfl_xor(sum, off);
            sP[node][h][j] = p / sum;
        }
    }
    __syncthreads();

    // ---- stage 2: PV (V from LDS) -> sA bf16 (XOR-swizzled 16B chunks) ----
    {
        const int node = tid >> 5, oct = tid & 31;
        const int h = oct >> 3;
        const int chunk = oct;                    // h*8 + (oct&7) == oct
        float acc8[8] = {};
#pragma unroll 8
        for (int j = 0; j < DEG; ++j) {
            const float p = sP[node][h][j];
            const int idx = (sDst[node][j] - n0 - 1) & (N_NODES - 1);
            u16x8 vv = *(const u16x8*)((const char*)sKV[1] + idx * 512 +
                                       ((chunk ^ (idx & 7)) * 16));
#pragma unroll
            for (int i = 0; i < 8; ++i) acc8[i] = fmaf(p, b2f(vv[i]), acc8[i]);
        }
        u16x8 pk;
#pragma unroll
        for (int i = 0; i < 8; ++i) pk[i] = f2b(acc8[i]);
        const int so = node * 512 + ((oct * 16) ^ ((node & 7) << 4));
        *(u16x8*)((char*)sA + so) = pk;
    }

    // ---- stage 3: oproj (K=256, 4 k-tiles, dbuf B staging) ----
    s16x8 breg[4];
#define WO_LOAD(KT)                                                           \
    {                                                                         \
        _Pragma("unroll")                                                     \
        for (int p = 0; p < 4; ++p) {                                         \
            const int lo = tid * 16 + p * 8192;                               \
            const int r = lo >> 7, c = lo & 127;                              \
            breg[p] = *(const s16x8*)((const char*)Wo_t + (size_t)r * 512 +   \
                                      (KT) * 128 + c);                        \
        }                                                                     \
    }
#define WO_STORE(BUF)                                                         \
    {                                                                         \
        _Pragma("unroll")                                                     \
        for (int p = 0; p < 4; ++p) {                                         \
            const int lo = tid * 16 + p * 8192;                               \
            const int r = lo >> 7, c = lo & 127;                              \
            const int so = (lo & ~127) | (c ^ ((r & 7) << 4));                \
            *(s16x8*)((char*)sB[BUF] + so) = breg[p];                         \
        }                                                                     \
    }

    WO_LOAD(0);
    WO_STORE(0);
    __syncthreads();     // also orders stage-2 sA writes before MFMA reads

    f32x4 acc[2] = {};
#pragma unroll
    for (int kt = 0; kt < 4; ++kt) {
        if (kt + 1 < 4) WO_LOAD(kt + 1);

        const char* sBc = (const char*)sB[kt & 1];
#pragma unroll
        for (int kk = 0; kk < 64; kk += 32) {
            const int lk = ((lane >> 4) << 3);
            s16x8 a;
            {
                const int r = lane & 15;
                const int koffb = (kt * 64 + kk + lk) * 2;
                a = *(const s16x8*)((const char*)sA + r * 512 +
                                    (koffb ^ ((r & 7) << 4)));
            }
            s16x8 bfr[2];
            const int boffb = (kk + lk) * 2;
#pragma unroll
            for (int n = 0; n < 2; ++n) {
                const int c = wave * 32 + n * 16 + (lane & 15);
                bfr[n] = *(const s16x8*)(sBc + c * 128 + (boffb ^ ((c & 7) << 4)));
            }
#pragma unroll
            for (int n = 0; n < 2; ++n)
                acc[n] = __builtin_amdgcn_mfma_f32_16x16x32_bf16(a, bfr[n], acc[n], 0, 0, 0);
        }

        if (kt + 1 < 4) {
            WO_STORE((kt + 1) & 1);
            __syncthreads();
        }
    }
#undef WO_LOAD
#undef WO_STORE

    // ---- LN1 epilogue (residual x) ----
    const int rbase = ((lane >> 4) << 2);
    const int cbase = wave * 32 + (lane & 15);

    float sm[4] = {}, sq_[4] = {};
#pragma unroll
    for (int n = 0; n < 2; ++n) {
        const int c = cbase + n * 16;
        const float bv = bo[c];
#pragma unroll
        for (int j = 0; j < 4; ++j) {
            const int r = rbase + j;
            float v = acc[n][j] + bv + x[(size_t)(n0 + r) * HIDDEN + c];
            acc[n][j] = v;
            sm[j] += v;
            sq_[j] = fmaf(v, v, sq_[j]);
        }
    }
#pragma unroll
    for (int off = 8; off >= 1; off >>= 1) {
#pragma unroll
        for (int j = 0; j < 4; ++j) {
            sm[j] += __shfl_xor(sm[j], off);
            sq_[j] += __shfl_xor(sq_[j], off);
        }
    }
    if ((lane & 15) == 0) {
#pragma unroll
        for (int j = 0; j < 4; ++j) {
            rs[rbase + j][wave] = sm[j];
            rq[rbase + j][wave] = sq_[j];
        }
    }
    __syncthreads();

#pragma unroll
    for (int j = 0; j < 4; ++j) {
        const int r = rbase + j;
        float tot = 0.f, totq = 0.f;
#pragma unroll
        for (int w = 0; w < 8; ++w) { tot += rs[r][w]; totq += rq[r][w]; }
        const float mean = tot * (1.f / HIDDEN);
        const float var  = totq * (1.f / HIDDEN) - mean * mean;
        const float inv  = rsqrtf(var + LN_EPS);
#pragma unroll
        for (int n = 0; n < 2; ++n) {
            const int c = cbase + n * 16;
            const float res = (acc[n][j] - mean) * inv * g[c] + b[c];
            y[(size_t)(n0 + r) * HIDDEN + c] = res;
            yb[(size_t)(n0 + r) * HIDDEN + c] = f2b(res);
        }
    }
}

// ---------------------------------------------------------------------------
extern "C" void kernel_launch(void* const* d_in, const int* in_sizes, int n_in,
                              void* d_out, int out_size, void* d_ws, size_t ws_size,
                              hipStream_t stream) {
    const float* x   = (const float*)d_in[0];
    const int*   ei  = (const int*)d_in[1];
    const float* ea  = (const float*)d_in[2];
    const float* Wq  = (const float*)d_in[3];
    const float* bq  = (const float*)d_in[4];
    const float* Wk  = (const float*)d_in[5];
    const float* bk  = (const float*)d_in[6];
    const float* Wv  = (const float*)d_in[7];
    const float* bv  = (const float*)d_in[8];
    const float* Wo  = (const float*)d_in[9];
    const float* bo  = (const float*)d_in[10];
    const float* We  = (const float*)d_in[11];
    const float* be  = (const float*)d_in[12];
    const float* g1  = (const float*)d_in[13];
    const float* b1  = (const float*)d_in[14];
    const float* g2  = (const float*)d_in[15];
    const float* b2  = (const float*)d_in[16];
    const float* Wf1 = (const float*)d_in[17];
    const float* bf1 = (const float*)d_in[18];
    const float* Wf2 = (const float*)d_in[19];
    const float* bf2 = (const float*)d_in[20];

    // ---- workspace layout (all write-before-read within each call) ----
    char* W = (char*)d_ws;
    unsigned short* Wqkv_t  = (unsigned short*)(W + (2u << 20));                // 384KB
    unsigned short* Wo_t    = (unsigned short*)(W + (2u << 20) + 384 * 1024);   // 128KB
    unsigned short* Wf1_t   = (unsigned short*)(W + (2u << 20) + 512 * 1024);   // 512KB
    unsigned short* Wf2_t   = (unsigned short*)(W + (2u << 20) + 1024 * 1024);  // 512KB
    float*          bias768 = (float*)(W + (2u << 20) + 1536 * 1024);           // 3KB
    unsigned short* qkvb    = (unsigned short*)(W + (4u << 20));                // 6MB (dead after attn_oproj)
    unsigned short* h1b     = (unsigned short*)(W + (4u << 20));                // 8MB (reuses qkvb region)
    float*          y       = (float*)(W + (12u << 20));                        // 4MB
    unsigned short* yb      = (unsigned short*)(W + (16u << 20));               // 2MB
    float*          part    = (float*)(W + (20u << 20));                        // 8MB [2][4096][256]

    const dim3 blk(256);

    pack_kernel<<<49, blk, 0, stream>>>(Wq, Wk, Wv, bq, bk, bv, Wqkv_t, bias768);

    gemm_qkv<<<912, blk, 0, stream>>>(x, Wqkv_t, bias768, qkvb,
                                      Wo, Wf1, Wf2, Wo_t, Wf1_t, Wf2_t);

    // attention + O-proj + residual(x) + LN1 -> y (fp32) + yb (bf16)
    attn_oproj_ln<<<N_NODES / 16, dim3(512), 0, stream>>>(
        qkvb, ei + NEDGE, ea, We, be, Wo_t, bo, x, g1, b1, y, yb);

    // FFN1 + ReLU -> h1b (bf16)   [1024 blocks, XCD-swizzled]
    gemm_mfma<256, true, true><<<1024, blk, 0, stream>>>(
        yb, Wf1_t, bf1, h1b, 4 * HIDDEN, 16, 1024);

    // FFN2 K-split x2 -> fp32 partials  [512 blocks, XCD-swizzled]
    gemm_partial<<<512, blk, 0, stream>>>(h1b, Wf2_t, part);

    // sum partials + residual(y) + LN2 -> d_out
    ln2_reduce<<<N_NODES / 16, blk, 0, stream>>>(part, y, bf2, g2, b2, (float*)d_out);
}

// Round 12
// 53.757 us; speedup vs baseline: 1.2957x; 1.0331x over previous
//
#include <hip/hip_runtime.h>
#include <cstddef>

#define N_NODES 4096
#define HIDDEN  256
#define NHEAD   4
#define DHEAD   64
#define EDGE_DIM 16
#define DEG     32
#define NEDGE   (N_NODES * DEG)
#define LN_EPS  1e-5f
#define QKV_STRIDE 768
#define KV_WIN  47

typedef short  s16x8 __attribute__((ext_vector_type(8)));
typedef float  f32x4 __attribute__((ext_vector_type(4)));
typedef unsigned short u16x8 __attribute__((ext_vector_type(8)));
typedef unsigned short u16x4 __attribute__((ext_vector_type(4)));

__device__ __forceinline__ unsigned short f2b(float f) {
    union { float f; unsigned u; } c{f};
    unsigned u = c.u;
    return (unsigned short)((u + 0x7fffu + ((u >> 16) & 1u)) >> 16);
}
__device__ __forceinline__ float b2f(unsigned short s) {
    union { unsigned u; float f; } c;
    c.u = ((unsigned)s) << 16;
    return c.f;
}
// XCD-aware bijective swizzle (total % 8 == 0): each XCD gets a contiguous
// chunk of tile space (T1).
__device__ __forceinline__ int xcd_swz(int bid, int total) {
    const int q = total >> 3;
    return (bid & 7) * q + (bid >> 3);
}

// ---------------------------------------------------------------------------
// pack one 64x64 tile: fp32 src[K][Nn] -> bf16 dst[Nn][K] (transposed).
// ---------------------------------------------------------------------------
__device__ __forceinline__ void pack_tile(const float* __restrict__ src,
                                          unsigned short* __restrict__ dst,
                                          int K, int Nn, int tt, int rowoff,
                                          float (*tile)[65], int tid) {
    const int tk = K / 64;
    const int k0 = (tt % tk) * 64, n0 = (tt / tk) * 64;

    const int kk = tid >> 2, nq = (tid & 3) * 16;
#pragma unroll
    for (int i = 0; i < 16; i += 4) {
        float4 vv = *(const float4*)&src[(size_t)(k0 + kk) * Nn + n0 + nq + i];
        tile[kk][nq + i + 0] = vv.x;
        tile[kk][nq + i + 1] = vv.y;
        tile[kk][nq + i + 2] = vv.z;
        tile[kk][nq + i + 3] = vv.w;
    }
    __syncthreads();
    const int nn = tid >> 2, kq = (tid & 3) * 16;
    unsigned short tmp[16];
#pragma unroll
    for (int i = 0; i < 16; ++i) tmp[i] = f2b(tile[kq + i][nn]);
    unsigned short* drow = dst + (size_t)(rowoff + n0 + nn) * K + k0 + kq;
    *(u16x8*)(drow + 0) = *(u16x8*)&tmp[0];
    *(u16x8*)(drow + 8) = *(u16x8*)&tmp[8];
}

// ---------------------------------------------------------------------------
// pack_kernel (193 blocks, one block-round): 0..47 Wqkv, 48..63 Wo,
// 64..127 Wf1, 128..191 Wf2, 192 bias768.
// ---------------------------------------------------------------------------
__global__ __launch_bounds__(256) void pack_kernel(
    const float* __restrict__ Wq, const float* __restrict__ Wk,
    const float* __restrict__ Wv, const float* __restrict__ Wo,
    const float* __restrict__ Wf1, const float* __restrict__ Wf2,
    const float* __restrict__ bq, const float* __restrict__ bk,
    const float* __restrict__ bv,
    unsigned short* __restrict__ Wqkv_t, unsigned short* __restrict__ Wo_t,
    unsigned short* __restrict__ Wf1_t, unsigned short* __restrict__ Wf2_t,
    float* __restrict__ bias768) {
    const int b = blockIdx.x;
    const int tid = threadIdx.x;
    __shared__ float tile[64][65];

    if (b < 48) {
        int m = b / 16, tt = b % 16;
        const float* src = (m == 0) ? Wq : ((m == 1) ? Wk : Wv);
        pack_tile(src, Wqkv_t, 256, 256, tt, m * 256, tile, tid);
    } else if (b < 64) {
        pack_tile(Wo, Wo_t, 256, 256, b - 48, 0, tile, tid);
    } else if (b < 128) {
        pack_tile(Wf1, Wf1_t, 256, 1024, b - 64, 0, tile, tid);
    } else if (b < 192) {
        pack_tile(Wf2, Wf2_t, 1024, 256, b - 128, 0, tile, tid);
    } else {
        bias768[tid]       = bq[tid];
        bias768[256 + tid] = bk[tid];
        bias768[512 + tid] = bv[tid];
    }
}

// ---------------------------------------------------------------------------
// gemm_qkv (768 blocks, XCD-swizzled): qkv bf16 = x(fp32) @ Wqkv_t^T + bias.
// ---------------------------------------------------------------------------
__global__ __launch_bounds__(256) void gemm_qkv(const float* __restrict__ X,
                                                const unsigned short* __restrict__ Bt,
                                                const float* __restrict__ bias,
                                                unsigned short* __restrict__ Cout) {
    __shared__ unsigned short sA[64 * 64];
    __shared__ unsigned short sB[64 * 64];
    const int tid = threadIdx.x;
    const int wave = tid >> 6, lane = tid & 63;
    const int b2 = xcd_swz(blockIdx.x, 768);
    const int row0 = (b2 / 12) * 64, col0 = (b2 % 12) * 64;
    const int wr = wave >> 1, wc = wave & 1;

    f32x4 acc[2][2] = {};

    const int lo0 = tid * 16, lo1 = lo0 + 4096;
    const int r0 = lo0 >> 7, c0 = lo0 & 127;
    const int r1 = lo1 >> 7, c1 = lo1 & 127;
    const int so0 = (lo0 & ~127) | (c0 ^ ((r0 & 7) << 4));
    const int so1 = (lo1 & ~127) | (c1 ^ ((r1 & 7) << 4));

    const int ar  = tid >> 2;
    const int akb = (tid & 3) * 16;
    const int acb = akb * 2;
    const int axr = (ar & 7) << 4;
    const int aso0 = (ar * 128) | ((acb +  0) ^ axr);
    const int aso1 = (ar * 128) | ((acb + 16) ^ axr);

    float4 f0, f1, f2v, f3;
    s16x8 b0r, b1r;

#define QKV_LOAD(KT)                                                          \
    {                                                                         \
        const float* Ap = X + (size_t)(row0 + ar) * 256 + (KT) * 64 + akb;    \
        f0  = *(const float4*)(Ap + 0);                                       \
        f1  = *(const float4*)(Ap + 4);                                       \
        f2v = *(const float4*)(Ap + 8);                                       \
        f3  = *(const float4*)(Ap + 12);                                      \
        const char* Bb = (const char*)Bt + ((size_t)col0 * 256 + (KT) * 64) * 2; \
        b0r = *(const s16x8*)(Bb + (size_t)r0 * 512 + c0);                    \
        b1r = *(const s16x8*)(Bb + (size_t)r1 * 512 + c1);                    \
    }

    QKV_LOAD(0);
#pragma unroll
    for (int kt = 0; kt < 4; ++kt) {
        if (kt) __syncthreads();
        u16x8 pa0 = {f2b(f0.x), f2b(f0.y), f2b(f0.z), f2b(f0.w),
                     f2b(f1.x), f2b(f1.y), f2b(f1.z), f2b(f1.w)};
        u16x8 pa1 = {f2b(f2v.x), f2b(f2v.y), f2b(f2v.z), f2b(f2v.w),
                     f2b(f3.x), f2b(f3.y), f2b(f3.z), f2b(f3.w)};
        *(u16x8*)((char*)sA + aso0) = pa0;
        *(u16x8*)((char*)sA + aso1) = pa1;
        *(s16x8*)((char*)sB + so0) = b0r;
        *(s16x8*)((char*)sB + so1) = b1r;
        __syncthreads();
        if (kt < 3) QKV_LOAD(kt + 1);

        const char* sAc = (const char*)sA;
        const char* sBc = (const char*)sB;
#pragma unroll
        for (int kk = 0; kk < 64; kk += 32) {
            const int koffb = (kk + ((lane >> 4) << 3)) * 2;
            s16x8 a[2], bfr[2];
#pragma unroll
            for (int m = 0; m < 2; ++m) {
                const int r = wr * 32 + m * 16 + (lane & 15);
                int off = r * 128 + koffb;
                off ^= (r & 7) << 4;
                a[m] = *(const s16x8*)(sAc + off);
            }
#pragma unroll
            for (int n = 0; n < 2; ++n) {
                const int c = wc * 32 + n * 16 + (lane & 15);
                int off = c * 128 + koffb;
                off ^= (c & 7) << 4;
                bfr[n] = *(const s16x8*)(sBc + off);
            }
#pragma unroll
            for (int m = 0; m < 2; ++m)
#pragma unroll
                for (int n = 0; n < 2; ++n)
                    acc[m][n] = __builtin_amdgcn_mfma_f32_16x16x32_bf16(
                        a[m], bfr[n], acc[m][n], 0, 0, 0);
        }
    }
#undef QKV_LOAD

    const int crow = row0 + wr * 32 + ((lane >> 4) << 2);
    const int ccol = col0 + wc * 32 + (lane & 15);
#pragma unroll
    for (int n = 0; n < 2; ++n) {
        const int c = ccol + n * 16;
        const float bv = bias[c];
#pragma unroll
        for (int m = 0; m < 2; ++m)
#pragma unroll
            for (int j = 0; j < 4; ++j)
                Cout[(size_t)(crow + m * 16 + j) * QKV_STRIDE + c] =
                    f2b(acc[m][n][j] + bv);
    }
}

// ---------------------------------------------------------------------------
// gemm_ffn1 (512 blocks, XCD-swizzled): h1b = relu(yb @ Wf1_t^T + bf1), bf16.
// 64x128 tile: 4 waves (2x2), each 32 rows x 64 cols -> acc[2][4].
// Per-output accumulation order identical to the 64x64 version.
// ---------------------------------------------------------------------------
__global__ __launch_bounds__(256) void gemm_ffn1(const unsigned short* __restrict__ A,
                                                 const unsigned short* __restrict__ Bt,
                                                 const float* __restrict__ bias,
                                                 unsigned short* __restrict__ Cout) {
    constexpr int K = 256;
    __shared__ unsigned short sA[64 * 64];     // 8KB
    __shared__ unsigned short sB[128 * 64];    // 16KB
    const int tid = threadIdx.x;
    const int wave = tid >> 6, lane = tid & 63;
    const int b2 = xcd_swz(blockIdx.x, 512);
    const int row0 = (b2 >> 3) * 64, col0 = (b2 & 7) * 128;
    const int wr = wave >> 1, wc = wave & 1;

    f32x4 acc[2][4] = {};

    const int lo0 = tid * 16, lo1 = lo0 + 4096;
    const int r0 = lo0 >> 7, c0 = lo0 & 127;
    const int r1 = lo1 >> 7, c1 = lo1 & 127;
    const int so0 = (lo0 & ~127) | (c0 ^ ((r0 & 7) << 4));
    const int so1 = (lo1 & ~127) | (c1 ^ ((r1 & 7) << 4));

    s16x8 a0r, a1r, breg[4];

#define F1_LOAD(KT)                                                           \
    {                                                                         \
        const char* Ab = (const char*)A + ((size_t)row0 * K + (KT) * 64) * 2; \
        a0r = *(const s16x8*)(Ab + (size_t)r0 * (K * 2) + c0);                \
        a1r = *(const s16x8*)(Ab + (size_t)r1 * (K * 2) + c1);                \
        const char* Bb = (const char*)Bt + ((size_t)col0 * K + (KT) * 64) * 2;\
        _Pragma("unroll")                                                     \
        for (int p = 0; p < 4; ++p) {                                         \
            const int lo = tid * 16 + p * 4096;                               \
            const int r = lo >> 7, c = lo & 127;                              \
            breg[p] = *(const s16x8*)(Bb + (size_t)r * (K * 2) + c);          \
        }                                                                     \
    }

    F1_LOAD(0);
#pragma unroll
    for (int kt = 0; kt < 4; ++kt) {
        if (kt) __syncthreads();
        *(s16x8*)((char*)sA + so0) = a0r;
        *(s16x8*)((char*)sA + so1) = a1r;
#pragma unroll
        for (int p = 0; p < 4; ++p) {
            const int lo = tid * 16 + p * 4096;
            const int r = lo >> 7, c = lo & 127;
            const int so = (lo & ~127) | (c ^ ((r & 7) << 4));
            *(s16x8*)((char*)sB + so) = breg[p];
        }
        __syncthreads();
        if (kt + 1 < 4) F1_LOAD(kt + 1);

        const char* sAc = (const char*)sA;
        const char* sBc = (const char*)sB;
#pragma unroll
        for (int kk = 0; kk < 64; kk += 32) {
            const int koffb = (kk + ((lane >> 4) << 3)) * 2;
            s16x8 a[2], bfr[4];
#pragma unroll
            for (int m = 0; m < 2; ++m) {
                const int r = wr * 32 + m * 16 + (lane & 15);
                int off = r * 128 + koffb;
                off ^= (r & 7) << 4;
                a[m] = *(const s16x8*)(sAc + off);
            }
#pragma unroll
            for (int n = 0; n < 4; ++n) {
                const int c = wc * 64 + n * 16 + (lane & 15);
                int off = c * 128 + koffb;
                off ^= (c & 7) << 4;
                bfr[n] = *(const s16x8*)(sBc + off);
            }
#pragma unroll
            for (int m = 0; m < 2; ++m)
#pragma unroll
                for (int n = 0; n < 4; ++n)
                    acc[m][n] = __builtin_amdgcn_mfma_f32_16x16x32_bf16(
                        a[m], bfr[n], acc[m][n], 0, 0, 0);
        }
    }
#undef F1_LOAD

    const int crow = row0 + wr * 32 + ((lane >> 4) << 2);
    const int ccol = col0 + wc * 64 + (lane & 15);
#pragma unroll
    for (int n = 0; n < 4; ++n) {
        const int c = ccol + n * 16;
        const float bv = bias[c];
#pragma unroll
        for (int m = 0; m < 2; ++m)
#pragma unroll
            for (int j = 0; j < 4; ++j) {
                const int r = crow + m * 16 + j;
                Cout[(size_t)r * 1024 + c] = f2b(fmaxf(acc[m][n][j] + bv, 0.f));
            }
    }
}

// ---------------------------------------------------------------------------
// gemm_partial: K-split FFN2, z=2 chunks of 512. 1D grid 512 + XCD swizzle.
// part[z][4096][256] (fp32) = h1b[:, z*512:..] @ Wf2_t[:, z*512:..]^T.
// ---------------------------------------------------------------------------
__global__ __launch_bounds__(256) void gemm_partial(const unsigned short* __restrict__ A,
                                                    const unsigned short* __restrict__ Bt,
                                                    float* __restrict__ part) {
    constexpr int KF = 1024;   // full K (row stride of A and Bt)
    __shared__ unsigned short sA[64 * 64];
    __shared__ unsigned short sB[64 * 64];
    const int tid = threadIdx.x;
    const int wave = tid >> 6, lane = tid & 63;
    const int b2 = xcd_swz(blockIdx.x, 512);
    const int z = b2 >> 8;                       // 0..1
    const int rem = b2 & 255;
    const int row0 = (rem >> 2) * 64, col0 = (rem & 3) * 64;
    const int wr = wave >> 1, wc = wave & 1;

    f32x4 acc[2][2] = {};

    const int lo0 = tid * 16;
    const int lo1 = lo0 + 4096;
    const int r0 = lo0 >> 7, c0 = lo0 & 127;
    const int r1 = lo1 >> 7, c1 = lo1 & 127;
    const int so0 = (lo0 & ~127) | (c0 ^ ((r0 & 7) << 4));
    const int so1 = (lo1 & ~127) | (c1 ^ ((r1 & 7) << 4));

    const char* Abase = (const char*)A + ((size_t)row0 * KF + z * 512) * 2;
    const char* Bbase = (const char*)Bt + ((size_t)col0 * KF + z * 512) * 2;

    s16x8 a0r, a1r, b0r, b1r;

#define GP_LOAD(KT)                                                           \
    {                                                                         \
        a0r = *(const s16x8*)(Abase + (KT) * 128 + (size_t)r0 * (KF * 2) + c0); \
        a1r = *(const s16x8*)(Abase + (KT) * 128 + (size_t)r1 * (KF * 2) + c1); \
        b0r = *(const s16x8*)(Bbase + (KT) * 128 + (size_t)r0 * (KF * 2) + c0); \
        b1r = *(const s16x8*)(Bbase + (KT) * 128 + (size_t)r1 * (KF * 2) + c1); \
    }

    GP_LOAD(0);
#pragma unroll
    for (int kt = 0; kt < 8; ++kt) {
        if (kt) __syncthreads();
        *(s16x8*)((char*)sA + so0) = a0r;
        *(s16x8*)((char*)sA + so1) = a1r;
        *(s16x8*)((char*)sB + so0) = b0r;
        *(s16x8*)((char*)sB + so1) = b1r;
        __syncthreads();
        if (kt + 1 < 8) GP_LOAD(kt + 1);

        const char* sAc = (const char*)sA;
        const char* sBc = (const char*)sB;
#pragma unroll
        for (int kk = 0; kk < 64; kk += 32) {
            const int koffb = (kk + ((lane >> 4) << 3)) * 2;
            s16x8 a[2], bfr[2];
#pragma unroll
            for (int m = 0; m < 2; ++m) {
                const int r = wr * 32 + m * 16 + (lane & 15);
                int off = r * 128 + koffb;
                off ^= (r & 7) << 4;
                a[m] = *(const s16x8*)(sAc + off);
            }
#pragma unroll
            for (int n = 0; n < 2; ++n) {
                const int c = wc * 32 + n * 16 + (lane & 15);
                int off = c * 128 + koffb;
                off ^= (c & 7) << 4;
                bfr[n] = *(const s16x8*)(sBc + off);
            }
#pragma unroll
            for (int m = 0; m < 2; ++m)
#pragma unroll
                for (int n = 0; n < 2; ++n)
                    acc[m][n] = __builtin_amdgcn_mfma_f32_16x16x32_bf16(
                        a[m], bfr[n], acc[m][n], 0, 0, 0);
        }
    }
#undef GP_LOAD

    const int crow = row0 + wr * 32 + ((lane >> 4) << 2);
    const int ccol = col0 + wc * 32 + (lane & 15);
    float* pz = part + (size_t)z * N_NODES * HIDDEN;
#pragma unroll
    for (int n = 0; n < 2; ++n) {
        const int c = ccol + n * 16;
#pragma unroll
        for (int m = 0; m < 2; ++m)
#pragma unroll
            for (int j = 0; j < 4; ++j)
                pz[(size_t)(crow + m * 16 + j) * HIDDEN + c] = acc[m][n][j];
    }
}

// ---------------------------------------------------------------------------
// ln2_reduce (512 blocks): out = LN(y + bf2 + part[0] + part[1]) * g2 + b2.
// 8 rows/block, 32 threads per row (8 cols each).
// ---------------------------------------------------------------------------
__global__ __launch_bounds__(256) void ln2_reduce(const float* __restrict__ part,
                                                  const float* __restrict__ y,
                                                  const float* __restrict__ bf2,
                                                  const float* __restrict__ g2,
                                                  const float* __restrict__ b2,
                                                  float* __restrict__ out) {
    const int tid = threadIdx.x;
    const int row = blockIdx.x * 8 + (tid >> 5);
    const int cb = (tid & 31) * 8;
    const size_t rb = (size_t)row * HIDDEN;
    constexpr size_t ZS = (size_t)N_NODES * HIDDEN;

    float vals[8];
#pragma unroll
    for (int q = 0; q < 2; ++q) {
        const int c = cb + q * 4;
        float4 vy = *(const float4*)&y[rb + c];
        float4 vb = *(const float4*)&bf2[c];
        float4 s0 = *(const float4*)&part[0 * ZS + rb + c];
        float4 s1 = *(const float4*)&part[1 * ZS + rb + c];
        vals[q * 4 + 0] = vy.x + vb.x + s0.x + s1.x;
        vals[q * 4 + 1] = vy.y + vb.y + s0.y + s1.y;
        vals[q * 4 + 2] = vy.z + vb.z + s0.z + s1.z;
        vals[q * 4 + 3] = vy.w + vb.w + s0.w + s1.w;
    }
    float sm = 0.f, sq = 0.f;
#pragma unroll
    for (int i = 0; i < 8; ++i) { sm += vals[i]; sq = fmaf(vals[i], vals[i], sq); }
#pragma unroll
    for (int off = 16; off >= 1; off >>= 1) {
        sm += __shfl_xor(sm, off);
        sq += __shfl_xor(sq, off);
    }
    const float mean = sm * (1.f / HIDDEN);
    const float var  = sq * (1.f / HIDDEN) - mean * mean;
    const float inv  = rsqrtf(var + LN_EPS);
#pragma unroll
    for (int q = 0; q < 2; ++q) {
        const int c = cb + q * 4;
        float4 vg = *(const float4*)&g2[c];
        float4 vbb = *(const float4*)&b2[c];
        float4 o;
        o.x = (vals[q * 4 + 0] - mean) * inv * vg.x + vbb.x;
        o.y = (vals[q * 4 + 1] - mean) * inv * vg.y + vbb.y;
        o.z = (vals[q * 4 + 2] - mean) * inv * vg.z + vbb.z;
        o.w = (vals[q * 4 + 3] - mean) * inv * vg.w + vbb.w;
        *(float4*)&out[rb + c] = o;
    }
}

// ---------------------------------------------------------------------------
// attn_oproj_ln: fused attention + O-projection + residual + LN1.
// Block = 16 nodes, 512 thr. K/V window [n0+1, n0+47] staged once into LDS.
// ---------------------------------------------------------------------------
__global__ __launch_bounds__(512) void attn_oproj_ln(
    const unsigned short* __restrict__ qkv,
    const int* __restrict__ edge_dst,
    const float* __restrict__ edge_attr,
    const float* __restrict__ We, const float* __restrict__ be,
    const unsigned short* __restrict__ Wo_t,
    const float* __restrict__ bo,
    const float* __restrict__ x,
    const float* __restrict__ g, const float* __restrict__ b,
    float* __restrict__ y, unsigned short* __restrict__ yb) {
    __shared__ float sQ[16][260];                 // ~16.6KB (fp32 q rows)
    __shared__ float sP[16][NHEAD][DEG];          // 8KB
    __shared__ int   sDst[16][DEG];               // 2KB
    __shared__ float sWe[EDGE_DIM * NHEAD];
    __shared__ unsigned short sKV[2][KV_WIN * 256];   // 2 x 23.5KB k|v window
    __shared__ unsigned short sA[16 * 256];       // 8KB attn-out (swizzled)
    __shared__ unsigned short sB[2][256 * 64];    // 64KB Wo staging
    __shared__ float rs[16][8], rq[16][8];

    const int tid = threadIdx.x;
    const int wave = tid >> 6, lane = tid & 63;
    const int n0 = blockIdx.x * 16;

    // stage q rows (bf16 -> fp32)
    {
        const int r = tid >> 5, e = (tid & 31) * 8;
        u16x8 v = *(const u16x8*)(qkv + (size_t)(n0 + r) * QKV_STRIDE + e);
#pragma unroll
        for (int i = 0; i < 8; ++i) sQ[r][e + i] = b2f(v[i]);
    }
    // stage K/V window rows (n0+1 .. n0+47) mod N, swizzled 16B chunks
    for (int t = tid; t < 2 * KV_WIN * 32; t += 512) {
        const int half = (t >= KV_WIN * 32) ? 1 : 0;
        const int tt = t - half * (KV_WIN * 32);
        const int rr = tt >> 5, c16 = tt & 31;
        const int gsrc = (n0 + 1 + rr) & (N_NODES - 1);
        u16x8 v = *(const u16x8*)(qkv + (size_t)gsrc * QKV_STRIDE +
                                  (half ? 512 : 256) + c16 * 8);
        const int so = rr * 512 + ((c16 ^ (rr & 7)) * 16);
        *(u16x8*)((char*)sKV[half] + so) = v;
    }
    if (tid < EDGE_DIM * NHEAD) sWe[tid] = We[tid];
    __syncthreads();

    // ---- stage 1: logits + softmax (K from LDS) ----
    {
        const int node = tid >> 5, j = tid & 31;
        const int dstj = edge_dst[(n0 + node) * DEG + j];
        sDst[node][j] = dstj;
        const int idx = (dstj - n0 - 1) & (N_NODES - 1);   // 0..46 (ring)
        const char* krow = (const char*)sKV[0] + idx * 512;
        const int swz = (idx & 7);
        float lg[4];
#pragma unroll
        for (int h = 0; h < 4; ++h) {
            float dot = 0.f;
            const float* qh = &sQ[node][h * 64];
#pragma unroll
            for (int q8 = 0; q8 < 8; ++q8) {
                const int c16 = h * 8 + q8;
                u16x8 kv = *(const u16x8*)(krow + ((c16 ^ swz) * 16));
#pragma unroll
                for (int d = 0; d < 8; ++d)
                    dot = fmaf(qh[q8 * 8 + d], b2f(kv[d]), dot);
            }
            lg[h] = dot * 0.125f + be[h];
        }
        const float* ea_ = edge_attr + (size_t)((n0 + node) * DEG + j) * EDGE_DIM;
#pragma unroll
        for (int c = 0; c < EDGE_DIM; ++c) {
            const float eav = ea_[c];
#pragma unroll
            for (int h = 0; h < 4; ++h)
                lg[h] = fmaf(eav, sWe[c * NHEAD + h], lg[h]);
        }
#pragma unroll
        for (int h = 0; h < 4; ++h) {
            float mx = lg[h];
#pragma unroll
            for (int off = 16; off >= 1; off >>= 1)
                mx = fmaxf(mx, __shfl_xor(mx, off));
            float p = __expf(lg[h] - mx);
            float sum = p;
#pragma unroll
            for (int off = 16; off >= 1; off >>= 1)
                sum += __shfl_xor(sum, off);
            sP[node][h][j] = p / sum;
        }
    }
    __syncthreads();

    // ---- stage 2: PV (V from LDS) -> sA bf16 (XOR-swizzled 16B chunks) ----
    {
        const int node = tid >> 5, oct = tid & 31;
        const int h = oct >> 3;
        const int chunk = oct;                    // h*8 + (oct&7) == oct
        float acc8[8] = {};
#pragma unroll 8
        for (int j = 0; j < DEG; ++j) {
            const float p = sP[node][h][j];
            const int idx = (sDst[node][j] - n0 - 1) & (N_NODES - 1);
            u16x8 vv = *(const u16x8*)((const char*)sKV[1] + idx * 512 +
                                       ((chunk ^ (idx & 7)) * 16));
#pragma unroll
            for (int i = 0; i < 8; ++i) acc8[i] = fmaf(p, b2f(vv[i]), acc8[i]);
        }
        u16x8 pk;
#pragma unroll
        for (int i = 0; i < 8; ++i) pk[i] = f2b(acc8[i]);
        const int so = node * 512 + ((oct * 16) ^ ((node & 7) << 4));
        *(u16x8*)((char*)sA + so) = pk;
    }

    // ---- stage 3: oproj (K=256, 4 k-tiles, dbuf B staging) ----
    s16x8 breg[4];
#define WO_LOAD(KT)                                                           \
    {                                                                         \
        _Pragma("unroll")                                                     \
        for (int p = 0; p < 4; ++p) {                                         \
            const int lo = tid * 16 + p * 8192;                               \
            const int r = lo >> 7, c = lo & 127;                              \
            breg[p] = *(const s16x8*)((const char*)Wo_t + (size_t)r * 512 +   \
                                      (KT) * 128 + c);                        \
        }                                                                     \
    }
#define WO_STORE(BUF)                                                         \
    {                                                                         \
        _Pragma("unroll")                                                     \
        for (int p = 0; p < 4; ++p) {                                         \
            const int lo = tid * 16 + p * 8192;                               \
            const int r = lo >> 7, c = lo & 127;                              \
            const int so = (lo & ~127) | (c ^ ((r & 7) << 4));                \
            *(s16x8*)((char*)sB[BUF] + so) = breg[p];                         \
        }                                                                     \
    }

    WO_LOAD(0);
    WO_STORE(0);
    __syncthreads();     // also orders stage-2 sA writes before MFMA reads

    f32x4 acc[2] = {};
#pragma unroll
    for (int kt = 0; kt < 4; ++kt) {
        if (kt + 1 < 4) WO_LOAD(kt + 1);

        const char* sBc = (const char*)sB[kt & 1];
#pragma unroll
        for (int kk = 0; kk < 64; kk += 32) {
            const int lk = ((lane >> 4) << 3);
            s16x8 a;
            {
                const int r = lane & 15;
                const int koffb = (kt * 64 + kk + lk) * 2;
                a = *(const s16x8*)((const char*)sA + r * 512 +
                                    (koffb ^ ((r & 7) << 4)));
            }
            s16x8 bfr[2];
            const int boffb = (kk + lk) * 2;
#pragma unroll
            for (int n = 0; n < 2; ++n) {
                const int c = wave * 32 + n * 16 + (lane & 15);
                bfr[n] = *(const s16x8*)(sBc + c * 128 + (boffb ^ ((c & 7) << 4)));
            }
#pragma unroll
            for (int n = 0; n < 2; ++n)
                acc[n] = __builtin_amdgcn_mfma_f32_16x16x32_bf16(a, bfr[n], acc[n], 0, 0, 0);
        }

        if (kt + 1 < 4) {
            WO_STORE((kt + 1) & 1);
            __syncthreads();
        }
    }
#undef WO_LOAD
#undef WO_STORE

    // ---- LN1 epilogue (residual x) ----
    const int rbase = ((lane >> 4) << 2);
    const int cbase = wave * 32 + (lane & 15);

    float sm[4] = {}, sq_[4] = {};
#pragma unroll
    for (int n = 0; n < 2; ++n) {
        const int c = cbase + n * 16;
        const float bv = bo[c];
#pragma unroll
        for (int j = 0; j < 4; ++j) {
            const int r = rbase + j;
            float v = acc[n][j] + bv + x[(size_t)(n0 + r) * HIDDEN + c];
            acc[n][j] = v;
            sm[j] += v;
            sq_[j] = fmaf(v, v, sq_[j]);
        }
    }
#pragma unroll
    for (int off = 8; off >= 1; off >>= 1) {
#pragma unroll
        for (int j = 0; j < 4; ++j) {
            sm[j] += __shfl_xor(sm[j], off);
            sq_[j] += __shfl_xor(sq_[j], off);
        }
    }
    if ((lane & 15) == 0) {
#pragma unroll
        for (int j = 0; j < 4; ++j) {
            rs[rbase + j][wave] = sm[j];
            rq[rbase + j][wave] = sq_[j];
        }
    }
    __syncthreads();

#pragma unroll
    for (int j = 0; j < 4; ++j) {
        const int r = rbase + j;
        float tot = 0.f, totq = 0.f;
#pragma unroll
        for (int w = 0; w < 8; ++w) { tot += rs[r][w]; totq += rq[r][w]; }
        const float mean = tot * (1.f / HIDDEN);
        const float var  = totq * (1.f / HIDDEN) - mean * mean;
        const float inv  = rsqrtf(var + LN_EPS);
#pragma unroll
        for (int n = 0; n < 2; ++n) {
            const int c = cbase + n * 16;
            const float res = (acc[n][j] - mean) * inv * g[c] + b[c];
            y[(size_t)(n0 + r) * HIDDEN + c] = res;
            yb[(size_t)(n0 + r) * HIDDEN + c] = f2b(res);
        }
    }
}

// ---------------------------------------------------------------------------
extern "C" void kernel_launch(void* const* d_in, const int* in_sizes, int n_in,
                              void* d_out, int out_size, void* d_ws, size_t ws_size,
                              hipStream_t stream) {
    const float* x   = (const float*)d_in[0];
    const int*   ei  = (const int*)d_in[1];
    const float* ea  = (const float*)d_in[2];
    const float* Wq  = (const float*)d_in[3];
    const float* bq  = (const float*)d_in[4];
    const float* Wk  = (const float*)d_in[5];
    const float* bk  = (const float*)d_in[6];
    const float* Wv  = (const float*)d_in[7];
    const float* bv  = (const float*)d_in[8];
    const float* Wo  = (const float*)d_in[9];
    const float* bo  = (const float*)d_in[10];
    const float* We  = (const float*)d_in[11];
    const float* be  = (const float*)d_in[12];
    const float* g1  = (const float*)d_in[13];
    const float* b1  = (const float*)d_in[14];
    const float* g2  = (const float*)d_in[15];
    const float* b2  = (const float*)d_in[16];
    const float* Wf1 = (const float*)d_in[17];
    const float* bf1 = (const float*)d_in[18];
    const float* Wf2 = (const float*)d_in[19];
    const float* bf2 = (const float*)d_in[20];

    // ---- workspace layout (all write-before-read within each call) ----
    char* W = (char*)d_ws;
    unsigned short* Wqkv_t  = (unsigned short*)(W + (2u << 20));                // 384KB
    unsigned short* Wo_t    = (unsigned short*)(W + (2u << 20) + 384 * 1024);   // 128KB
    unsigned short* Wf1_t   = (unsigned short*)(W + (2u << 20) + 512 * 1024);   // 512KB
    unsigned short* Wf2_t   = (unsigned short*)(W + (2u << 20) + 1024 * 1024);  // 512KB
    float*          bias768 = (float*)(W + (2u << 20) + 1536 * 1024);           // 3KB
    unsigned short* qkvb    = (unsigned short*)(W + (4u << 20));                // 6MB (dead after attn_oproj)
    unsigned short* h1b     = (unsigned short*)(W + (4u << 20));                // 8MB (reuses qkvb region)
    float*          y       = (float*)(W + (12u << 20));                        // 4MB
    unsigned short* yb      = (unsigned short*)(W + (16u << 20));               // 2MB
    float*          part    = (float*)(W + (20u << 20));                        // 8MB [2][4096][256]

    const dim3 blk(256);

    pack_kernel<<<193, blk, 0, stream>>>(Wq, Wk, Wv, Wo, Wf1, Wf2, bq, bk, bv,
                                         Wqkv_t, Wo_t, Wf1_t, Wf2_t, bias768);

    gemm_qkv<<<768, blk, 0, stream>>>(x, Wqkv_t, bias768, qkvb);

    // attention + O-proj + residual(x) + LN1 -> y (fp32) + yb (bf16)
    attn_oproj_ln<<<N_NODES / 16, dim3(512), 0, stream>>>(
        qkvb, ei + NEDGE, ea, We, be, Wo_t, bo, x, g1, b1, y, yb);

    // FFN1 + ReLU -> h1b (bf16)   [512 blocks, 64x128 tile, XCD-swizzled]
    gemm_ffn1<<<512, blk, 0, stream>>>(yb, Wf1_t, bf1, h1b);

    // FFN2 K-split x2 -> fp32 partials  [512 blocks, XCD-swizzled]
    gemm_partial<<<512, blk, 0, stream>>>(h1b, Wf2_t, part);

    // sum partials + residual(y) + LN2 -> d_out  [512 blocks]
    ln2_reduce<<<N_NODES / 8, blk, 0, stream>>>(part, y, bf2, g2, b2, (float*)d_out);
}

// Round 13
// 53.542 us; speedup vs baseline: 1.3009x; 1.0040x over previous
//
#include <hip/hip_runtime.h>
#include <cstddef>

#define N_NODES 4096
#define HIDDEN  256
#define NHEAD   4
#define DHEAD   64
#define EDGE_DIM 16
#define DEG     32
#define NEDGE   (N_NODES * DEG)
#define LN_EPS  1e-5f
#define QKV_STRIDE 768
#define KV_WIN  47

typedef short  s16x8 __attribute__((ext_vector_type(8)));
typedef float  f32x4 __attribute__((ext_vector_type(4)));
typedef unsigned short u16x8 __attribute__((ext_vector_type(8)));
typedef unsigned short u16x4 __attribute__((ext_vector_type(4)));

__device__ __forceinline__ unsigned short f2b(float f) {
    union { float f; unsigned u; } c{f};
    unsigned u = c.u;
    return (unsigned short)((u + 0x7fffu + ((u >> 16) & 1u)) >> 16);
}
__device__ __forceinline__ float b2f(unsigned short s) {
    union { unsigned u; float f; } c;
    c.u = ((unsigned)s) << 16;
    return c.f;
}
// XCD-aware bijective swizzle (total % 8 == 0).
__device__ __forceinline__ int xcd_swz(int bid, int total) {
    const int q = total >> 3;
    return (bid & 7) * q + (bid >> 3);
}

// ---------------------------------------------------------------------------
// pack one 64x64 tile: fp32 src[K][Nn] -> bf16 dst[Nn][K] (transposed).
// ---------------------------------------------------------------------------
__device__ __forceinline__ void pack_tile(const float* __restrict__ src,
                                          unsigned short* __restrict__ dst,
                                          int K, int Nn, int tt, int rowoff,
                                          float (*tile)[65], int tid) {
    const int tk = K / 64;
    const int k0 = (tt % tk) * 64, n0 = (tt / tk) * 64;

    const int kk = tid >> 2, nq = (tid & 3) * 16;
#pragma unroll
    for (int i = 0; i < 16; i += 4) {
        float4 vv = *(const float4*)&src[(size_t)(k0 + kk) * Nn + n0 + nq + i];
        tile[kk][nq + i + 0] = vv.x;
        tile[kk][nq + i + 1] = vv.y;
        tile[kk][nq + i + 2] = vv.z;
        tile[kk][nq + i + 3] = vv.w;
    }
    __syncthreads();
    const int nn = tid >> 2, kq = (tid & 3) * 16;
    unsigned short tmp[16];
#pragma unroll
    for (int i = 0; i < 16; ++i) tmp[i] = f2b(tile[kq + i][nn]);
    unsigned short* drow = dst + (size_t)(rowoff + n0 + nn) * K + k0 + kq;
    *(u16x8*)(drow + 0) = *(u16x8*)&tmp[0];
    *(u16x8*)(drow + 8) = *(u16x8*)&tmp[8];
}

// ---------------------------------------------------------------------------
// pack_kernel (193 blocks, one block-round): 0..47 Wqkv, 48..63 Wo,
// 64..127 Wf1, 128..191 Wf2, 192 bias768.
// ---------------------------------------------------------------------------
__global__ __launch_bounds__(256) void pack_kernel(
    const float* __restrict__ Wq, const float* __restrict__ Wk,
    const float* __restrict__ Wv, const float* __restrict__ Wo,
    const float* __restrict__ Wf1, const float* __restrict__ Wf2,
    const float* __restrict__ bq, const float* __restrict__ bk,
    const float* __restrict__ bv,
    unsigned short* __restrict__ Wqkv_t, unsigned short* __restrict__ Wo_t,
    unsigned short* __restrict__ Wf1_t, unsigned short* __restrict__ Wf2_t,
    float* __restrict__ bias768) {
    const int b = blockIdx.x;
    const int tid = threadIdx.x;
    __shared__ float tile[64][65];

    if (b < 48) {
        int m = b / 16, tt = b % 16;
        const float* src = (m == 0) ? Wq : ((m == 1) ? Wk : Wv);
        pack_tile(src, Wqkv_t, 256, 256, tt, m * 256, tile, tid);
    } else if (b < 64) {
        pack_tile(Wo, Wo_t, 256, 256, b - 48, 0, tile, tid);
    } else if (b < 128) {
        pack_tile(Wf1, Wf1_t, 256, 1024, b - 64, 0, tile, tid);
    } else if (b < 192) {
        pack_tile(Wf2, Wf2_t, 1024, 256, b - 128, 0, tile, tid);
    } else {
        bias768[tid]       = bq[tid];
        bias768[256 + tid] = bk[tid];
        bias768[512 + tid] = bv[tid];
    }
}

// ---------------------------------------------------------------------------
// gemm_qkv (512 blocks, 64x96 tile, XCD-swizzled): qkv bf16 = x @ Wqkv^T + b.
// 4 waves (2x2), each 32 rows x 48 cols -> acc[2][3].
// ---------------------------------------------------------------------------
__global__ __launch_bounds__(256) void gemm_qkv(const float* __restrict__ X,
                                                const unsigned short* __restrict__ Bt,
                                                const float* __restrict__ bias,
                                                unsigned short* __restrict__ Cout) {
    __shared__ unsigned short sA[64 * 64];     // 8KB
    __shared__ unsigned short sB[96 * 64];     // 12KB
    const int tid = threadIdx.x;
    const int wave = tid >> 6, lane = tid & 63;
    const int b2 = xcd_swz(blockIdx.x, 512);
    const int row0 = (b2 >> 3) * 64, col0 = (b2 & 7) * 96;
    const int wr = wave >> 1, wc = wave & 1;

    f32x4 acc[2][3] = {};

    // A staging (fp32 -> bf16): row ar = tid>>2, 16 k-elems at (tid&3)*16
    const int ar  = tid >> 2;
    const int akb = (tid & 3) * 16;
    const int acb = akb * 2;
    const int axr = (ar & 7) << 4;
    const int aso0 = (ar * 128) | ((acb +  0) ^ axr);
    const int aso1 = (ar * 128) | ((acb + 16) ^ axr);

    float4 f0, f1, f2v, f3;
    s16x8 breg[3];

#define QKV_LOAD(KT)                                                          \
    {                                                                         \
        const float* Ap = X + (size_t)(row0 + ar) * 256 + (KT) * 64 + akb;    \
        f0  = *(const float4*)(Ap + 0);                                       \
        f1  = *(const float4*)(Ap + 4);                                       \
        f2v = *(const float4*)(Ap + 8);                                       \
        f3  = *(const float4*)(Ap + 12);                                      \
        const char* Bb = (const char*)Bt + ((size_t)col0 * 256 + (KT) * 64) * 2; \
        _Pragma("unroll")                                                     \
        for (int p = 0; p < 3; ++p) {                                         \
            const int lo = tid * 16 + p * 4096;                               \
            const int r = lo >> 7, c = lo & 127;                              \
            breg[p] = *(const s16x8*)(Bb + (size_t)r * 512 + c);              \
        }                                                                     \
    }

    QKV_LOAD(0);
#pragma unroll
    for (int kt = 0; kt < 4; ++kt) {
        if (kt) __syncthreads();
        u16x8 pa0 = {f2b(f0.x), f2b(f0.y), f2b(f0.z), f2b(f0.w),
                     f2b(f1.x), f2b(f1.y), f2b(f1.z), f2b(f1.w)};
        u16x8 pa1 = {f2b(f2v.x), f2b(f2v.y), f2b(f2v.z), f2b(f2v.w),
                     f2b(f3.x), f2b(f3.y), f2b(f3.z), f2b(f3.w)};
        *(u16x8*)((char*)sA + aso0) = pa0;
        *(u16x8*)((char*)sA + aso1) = pa1;
#pragma unroll
        for (int p = 0; p < 3; ++p) {
            const int lo = tid * 16 + p * 4096;
            const int r = lo >> 7, c = lo & 127;
            const int so = (lo & ~127) | (c ^ ((r & 7) << 4));
            *(s16x8*)((char*)sB + so) = breg[p];
        }
        __syncthreads();
        if (kt < 3) QKV_LOAD(kt + 1);

        const char* sAc = (const char*)sA;
        const char* sBc = (const char*)sB;
#pragma unroll
        for (int kk = 0; kk < 64; kk += 32) {
            const int koffb = (kk + ((lane >> 4) << 3)) * 2;
            s16x8 a[2], bfr[3];
#pragma unroll
            for (int m = 0; m < 2; ++m) {
                const int r = wr * 32 + m * 16 + (lane & 15);
                int off = r * 128 + koffb;
                off ^= (r & 7) << 4;
                a[m] = *(const s16x8*)(sAc + off);
            }
#pragma unroll
            for (int n = 0; n < 3; ++n) {
                const int c = wc * 48 + n * 16 + (lane & 15);
                int off = c * 128 + koffb;
                off ^= (c & 7) << 4;
                bfr[n] = *(const s16x8*)(sBc + off);
            }
#pragma unroll
            for (int m = 0; m < 2; ++m)
#pragma unroll
                for (int n = 0; n < 3; ++n)
                    acc[m][n] = __builtin_amdgcn_mfma_f32_16x16x32_bf16(
                        a[m], bfr[n], acc[m][n], 0, 0, 0);
        }
    }
#undef QKV_LOAD

    const int crow = row0 + wr * 32 + ((lane >> 4) << 2);
    const int ccol = col0 + wc * 48 + (lane & 15);
#pragma unroll
    for (int n = 0; n < 3; ++n) {
        const int c = ccol + n * 16;
        const float bv = bias[c];
#pragma unroll
        for (int m = 0; m < 2; ++m)
#pragma unroll
            for (int j = 0; j < 4; ++j)
                Cout[(size_t)(crow + m * 16 + j) * QKV_STRIDE + c] =
                    f2b(acc[m][n][j] + bv);
    }
}

// ---------------------------------------------------------------------------
// gemm_ffn1 (512 blocks, XCD-swizzled): h1b = relu(yb @ Wf1_t^T + bf1), bf16.
// 64x128 tile: 4 waves (2x2), each 32 rows x 64 cols -> acc[2][4].
// ---------------------------------------------------------------------------
__global__ __launch_bounds__(256) void gemm_ffn1(const unsigned short* __restrict__ A,
                                                 const unsigned short* __restrict__ Bt,
                                                 const float* __restrict__ bias,
                                                 unsigned short* __restrict__ Cout) {
    constexpr int K = 256;
    __shared__ unsigned short sA[64 * 64];     // 8KB
    __shared__ unsigned short sB[128 * 64];    // 16KB
    const int tid = threadIdx.x;
    const int wave = tid >> 6, lane = tid & 63;
    const int b2 = xcd_swz(blockIdx.x, 512);
    const int row0 = (b2 >> 3) * 64, col0 = (b2 & 7) * 128;
    const int wr = wave >> 1, wc = wave & 1;

    f32x4 acc[2][4] = {};

    const int lo0 = tid * 16, lo1 = lo0 + 4096;
    const int r0 = lo0 >> 7, c0 = lo0 & 127;
    const int r1 = lo1 >> 7, c1 = lo1 & 127;
    const int so0 = (lo0 & ~127) | (c0 ^ ((r0 & 7) << 4));
    const int so1 = (lo1 & ~127) | (c1 ^ ((r1 & 7) << 4));

    s16x8 a0r, a1r, breg[4];

#define F1_LOAD(KT)                                                           \
    {                                                                         \
        const char* Ab = (const char*)A + ((size_t)row0 * K + (KT) * 64) * 2; \
        a0r = *(const s16x8*)(Ab + (size_t)r0 * (K * 2) + c0);                \
        a1r = *(const s16x8*)(Ab + (size_t)r1 * (K * 2) + c1);                \
        const char* Bb = (const char*)Bt + ((size_t)col0 * K + (KT) * 64) * 2;\
        _Pragma("unroll")                                                     \
        for (int p = 0; p < 4; ++p) {                                         \
            const int lo = tid * 16 + p * 4096;                               \
            const int r = lo >> 7, c = lo & 127;                              \
            breg[p] = *(const s16x8*)(Bb + (size_t)r * (K * 2) + c);          \
        }                                                                     \
    }

    F1_LOAD(0);
#pragma unroll
    for (int kt = 0; kt < 4; ++kt) {
        if (kt) __syncthreads();
        *(s16x8*)((char*)sA + so0) = a0r;
        *(s16x8*)((char*)sA + so1) = a1r;
#pragma unroll
        for (int p = 0; p < 4; ++p) {
            const int lo = tid * 16 + p * 4096;
            const int r = lo >> 7, c = lo & 127;
            const int so = (lo & ~127) | (c ^ ((r & 7) << 4));
            *(s16x8*)((char*)sB + so) = breg[p];
        }
        __syncthreads();
        if (kt + 1 < 4) F1_LOAD(kt + 1);

        const char* sAc = (const char*)sA;
        const char* sBc = (const char*)sB;
#pragma unroll
        for (int kk = 0; kk < 64; kk += 32) {
            const int koffb = (kk + ((lane >> 4) << 3)) * 2;
            s16x8 a[2], bfr[4];
#pragma unroll
            for (int m = 0; m < 2; ++m) {
                const int r = wr * 32 + m * 16 + (lane & 15);
                int off = r * 128 + koffb;
                off ^= (r & 7) << 4;
                a[m] = *(const s16x8*)(sAc + off);
            }
#pragma unroll
            for (int n = 0; n < 4; ++n) {
                const int c = wc * 64 + n * 16 + (lane & 15);
                int off = c * 128 + koffb;
                off ^= (c & 7) << 4;
                bfr[n] = *(const s16x8*)(sBc + off);
            }
#pragma unroll
            for (int m = 0; m < 2; ++m)
#pragma unroll
                for (int n = 0; n < 4; ++n)
                    acc[m][n] = __builtin_amdgcn_mfma_f32_16x16x32_bf16(
                        a[m], bfr[n], acc[m][n], 0, 0, 0);
        }
    }
#undef F1_LOAD

    const int crow = row0 + wr * 32 + ((lane >> 4) << 2);
    const int ccol = col0 + wc * 64 + (lane & 15);
#pragma unroll
    for (int n = 0; n < 4; ++n) {
        const int c = ccol + n * 16;
        const float bv = bias[c];
#pragma unroll
        for (int m = 0; m < 2; ++m)
#pragma unroll
            for (int j = 0; j < 4; ++j) {
                const int r = crow + m * 16 + j;
                Cout[(size_t)r * 1024 + c] = f2b(fmaxf(acc[m][n][j] + bv, 0.f));
            }
    }
}

// ---------------------------------------------------------------------------
// gemm_partial: K-split FFN2, z=2 chunks of 512. 1D grid 512 + XCD swizzle.
// ---------------------------------------------------------------------------
__global__ __launch_bounds__(256) void gemm_partial(const unsigned short* __restrict__ A,
                                                    const unsigned short* __restrict__ Bt,
                                                    float* __restrict__ part) {
    constexpr int KF = 1024;
    __shared__ unsigned short sA[64 * 64];
    __shared__ unsigned short sB[64 * 64];
    const int tid = threadIdx.x;
    const int wave = tid >> 6, lane = tid & 63;
    const int b2 = xcd_swz(blockIdx.x, 512);
    const int z = b2 >> 8;
    const int rem = b2 & 255;
    const int row0 = (rem >> 2) * 64, col0 = (rem & 3) * 64;
    const int wr = wave >> 1, wc = wave & 1;

    f32x4 acc[2][2] = {};

    const int lo0 = tid * 16;
    const int lo1 = lo0 + 4096;
    const int r0 = lo0 >> 7, c0 = lo0 & 127;
    const int r1 = lo1 >> 7, c1 = lo1 & 127;
    const int so0 = (lo0 & ~127) | (c0 ^ ((r0 & 7) << 4));
    const int so1 = (lo1 & ~127) | (c1 ^ ((r1 & 7) << 4));

    const char* Abase = (const char*)A + ((size_t)row0 * KF + z * 512) * 2;
    const char* Bbase = (const char*)Bt + ((size_t)col0 * KF + z * 512) * 2;

    s16x8 a0r, a1r, b0r, b1r;

#define GP_LOAD(KT)                                                           \
    {                                                                         \
        a0r = *(const s16x8*)(Abase + (KT) * 128 + (size_t)r0 * (KF * 2) + c0); \
        a1r = *(const s16x8*)(Abase + (KT) * 128 + (size_t)r1 * (KF * 2) + c1); \
        b0r = *(const s16x8*)(Bbase + (KT) * 128 + (size_t)r0 * (KF * 2) + c0); \
        b1r = *(const s16x8*)(Bbase + (KT) * 128 + (size_t)r1 * (KF * 2) + c1); \
    }

    GP_LOAD(0);
#pragma unroll
    for (int kt = 0; kt < 8; ++kt) {
        if (kt) __syncthreads();
        *(s16x8*)((char*)sA + so0) = a0r;
        *(s16x8*)((char*)sA + so1) = a1r;
        *(s16x8*)((char*)sB + so0) = b0r;
        *(s16x8*)((char*)sB + so1) = b1r;
        __syncthreads();
        if (kt + 1 < 8) GP_LOAD(kt + 1);

        const char* sAc = (const char*)sA;
        const char* sBc = (const char*)sB;
#pragma unroll
        for (int kk = 0; kk < 64; kk += 32) {
            const int koffb = (kk + ((lane >> 4) << 3)) * 2;
            s16x8 a[2], bfr[2];
#pragma unroll
            for (int m = 0; m < 2; ++m) {
                const int r = wr * 32 + m * 16 + (lane & 15);
                int off = r * 128 + koffb;
                off ^= (r & 7) << 4;
                a[m] = *(const s16x8*)(sAc + off);
            }
#pragma unroll
            for (int n = 0; n < 2; ++n) {
                const int c = wc * 32 + n * 16 + (lane & 15);
                int off = c * 128 + koffb;
                off ^= (c & 7) << 4;
                bfr[n] = *(const s16x8*)(sBc + off);
            }
#pragma unroll
            for (int m = 0; m < 2; ++m)
#pragma unroll
                for (int n = 0; n < 2; ++n)
                    acc[m][n] = __builtin_amdgcn_mfma_f32_16x16x32_bf16(
                        a[m], bfr[n], acc[m][n], 0, 0, 0);
        }
    }
#undef GP_LOAD

    const int crow = row0 + wr * 32 + ((lane >> 4) << 2);
    const int ccol = col0 + wc * 32 + (lane & 15);
    float* pz = part + (size_t)z * N_NODES * HIDDEN;
#pragma unroll
    for (int n = 0; n < 2; ++n) {
        const int c = ccol + n * 16;
#pragma unroll
        for (int m = 0; m < 2; ++m)
#pragma unroll
            for (int j = 0; j < 4; ++j)
                pz[(size_t)(crow + m * 16 + j) * HIDDEN + c] = acc[m][n][j];
    }
}

// ---------------------------------------------------------------------------
// ln2_reduce (512 blocks): out = LN(yb + bf2 + part[0] + part[1]) * g2 + b2.
// Residual read from bf16 yb (fp32 y eliminated).
// ---------------------------------------------------------------------------
__global__ __launch_bounds__(256) void ln2_reduce(const float* __restrict__ part,
                                                  const unsigned short* __restrict__ yb,
                                                  const float* __restrict__ bf2,
                                                  const float* __restrict__ g2,
                                                  const float* __restrict__ b2,
                                                  float* __restrict__ out) {
    const int tid = threadIdx.x;
    const int row = blockIdx.x * 8 + (tid >> 5);
    const int cb = (tid & 31) * 8;
    const size_t rb = (size_t)row * HIDDEN;
    constexpr size_t ZS = (size_t)N_NODES * HIDDEN;

    u16x8 yv = *(const u16x8*)&yb[rb + cb];
    float vals[8];
#pragma unroll
    for (int q = 0; q < 2; ++q) {
        const int c = cb + q * 4;
        float4 vb = *(const float4*)&bf2[c];
        float4 s0 = *(const float4*)&part[0 * ZS + rb + c];
        float4 s1 = *(const float4*)&part[1 * ZS + rb + c];
        vals[q * 4 + 0] = b2f(yv[q * 4 + 0]) + vb.x + s0.x + s1.x;
        vals[q * 4 + 1] = b2f(yv[q * 4 + 1]) + vb.y + s0.y + s1.y;
        vals[q * 4 + 2] = b2f(yv[q * 4 + 2]) + vb.z + s0.z + s1.z;
        vals[q * 4 + 3] = b2f(yv[q * 4 + 3]) + vb.w + s0.w + s1.w;
    }
    float sm = 0.f, sq = 0.f;
#pragma unroll
    for (int i = 0; i < 8; ++i) { sm += vals[i]; sq = fmaf(vals[i], vals[i], sq); }
#pragma unroll
    for (int off = 16; off >= 1; off >>= 1) {
        sm += __shfl_xor(sm, off);
        sq += __shfl_xor(sq, off);
    }
    const float mean = sm * (1.f / HIDDEN);
    const float var  = sq * (1.f / HIDDEN) - mean * mean;
    const float inv  = rsqrtf(var + LN_EPS);
#pragma unroll
    for (int q = 0; q < 2; ++q) {
        const int c = cb + q * 4;
        float4 vg = *(const float4*)&g2[c];
        float4 vbb = *(const float4*)&b2[c];
        float4 o;
        o.x = (vals[q * 4 + 0] - mean) * inv * vg.x + vbb.x;
        o.y = (vals[q * 4 + 1] - mean) * inv * vg.y + vbb.y;
        o.z = (vals[q * 4 + 2] - mean) * inv * vg.z + vbb.z;
        o.w = (vals[q * 4 + 3] - mean) * inv * vg.w + vbb.w;
        *(float4*)&out[rb + c] = o;
    }
}

// ---------------------------------------------------------------------------
// attn_oproj_ln: fused attention + O-projection + residual + LN1 -> yb (bf16).
// Block = 16 nodes, 512 thr. K/V window [n0+1, n0+47] staged once into LDS.
// ---------------------------------------------------------------------------
__global__ __launch_bounds__(512) void attn_oproj_ln(
    const unsigned short* __restrict__ qkv,
    const int* __restrict__ edge_dst,
    const float* __restrict__ edge_attr,
    const float* __restrict__ We, const float* __restrict__ be,
    const unsigned short* __restrict__ Wo_t,
    const float* __restrict__ bo,
    const float* __restrict__ x,
    const float* __restrict__ g, const float* __restrict__ b,
    unsigned short* __restrict__ yb) {
    __shared__ float sQ[16][260];                 // ~16.6KB (fp32 q rows)
    __shared__ float sP[16][NHEAD][DEG];          // 8KB
    __shared__ int   sDst[16][DEG];               // 2KB
    __shared__ float sWe[EDGE_DIM * NHEAD];
    __shared__ unsigned short sKV[2][KV_WIN * 256];   // 2 x 23.5KB k|v window
    __shared__ unsigned short sA[16 * 256];       // 8KB attn-out (swizzled)
    __shared__ unsigned short sB[2][256 * 64];    // 64KB Wo staging
    __shared__ float rs[16][8], rq[16][8];

    const int tid = threadIdx.x;
    const int wave = tid >> 6, lane = tid & 63;
    const int n0 = blockIdx.x * 16;

    // stage q rows (bf16 -> fp32)
    {
        const int r = tid >> 5, e = (tid & 31) * 8;
        u16x8 v = *(const u16x8*)(qkv + (size_t)(n0 + r) * QKV_STRIDE + e);
#pragma unroll
        for (int i = 0; i < 8; ++i) sQ[r][e + i] = b2f(v[i]);
    }
    // stage K/V window rows (n0+1 .. n0+47) mod N, swizzled 16B chunks
    for (int t = tid; t < 2 * KV_WIN * 32; t += 512) {
        const int half = (t >= KV_WIN * 32) ? 1 : 0;
        const int tt = t - half * (KV_WIN * 32);
        const int rr = tt >> 5, c16 = tt & 31;
        const int gsrc = (n0 + 1 + rr) & (N_NODES - 1);
        u16x8 v = *(const u16x8*)(qkv + (size_t)gsrc * QKV_STRIDE +
                                  (half ? 512 : 256) + c16 * 8);
        const int so = rr * 512 + ((c16 ^ (rr & 7)) * 16);
        *(u16x8*)((char*)sKV[half] + so) = v;
    }
    if (tid < EDGE_DIM * NHEAD) sWe[tid] = We[tid];
    __syncthreads();

    // ---- stage 1: logits + softmax (K from LDS) ----
    {
        const int node = tid >> 5, j = tid & 31;
        const int dstj = edge_dst[(n0 + node) * DEG + j];
        sDst[node][j] = dstj;
        const int idx = (dstj - n0 - 1) & (N_NODES - 1);   // 0..46 (ring)
        const char* krow = (const char*)sKV[0] + idx * 512;
        const int swz = (idx & 7);
        float lg[4];
#pragma unroll
        for (int h = 0; h < 4; ++h) {
            float dot = 0.f;
            const float* qh = &sQ[node][h * 64];
#pragma unroll
            for (int q8 = 0; q8 < 8; ++q8) {
                const int c16 = h * 8 + q8;
                u16x8 kv = *(const u16x8*)(krow + ((c16 ^ swz) * 16));
#pragma unroll
                for (int d = 0; d < 8; ++d)
                    dot = fmaf(qh[q8 * 8 + d], b2f(kv[d]), dot);
            }
            lg[h] = dot * 0.125f + be[h];
        }
        const float* ea_ = edge_attr + (size_t)((n0 + node) * DEG + j) * EDGE_DIM;
#pragma unroll
        for (int c = 0; c < EDGE_DIM; ++c) {
            const float eav = ea_[c];
#pragma unroll
            for (int h = 0; h < 4; ++h)
                lg[h] = fmaf(eav, sWe[c * NHEAD + h], lg[h]);
        }
#pragma unroll
        for (int h = 0; h < 4; ++h) {
            float mx = lg[h];
#pragma unroll
            for (int off = 16; off >= 1; off >>= 1)
                mx = fmaxf(mx, __shfl_xor(mx, off));
            float p = __expf(lg[h] - mx);
            float sum = p;
#pragma unroll
            for (int off = 16; off >= 1; off >>= 1)
                sum += __shfl_xor(sum, off);
            sP[node][h][j] = p / sum;
        }
    }
    __syncthreads();

    // ---- stage 2: PV (V from LDS) -> sA bf16 (XOR-swizzled 16B chunks) ----
    {
        const int node = tid >> 5, oct = tid & 31;
        const int h = oct >> 3;
        const int chunk = oct;
        float acc8[8] = {};
#pragma unroll 8
        for (int j = 0; j < DEG; ++j) {
            const float p = sP[node][h][j];
            const int idx = (sDst[node][j] - n0 - 1) & (N_NODES - 1);
            u16x8 vv = *(const u16x8*)((const char*)sKV[1] + idx * 512 +
                                       ((chunk ^ (idx & 7)) * 16));
#pragma unroll
            for (int i = 0; i < 8; ++i) acc8[i] = fmaf(p, b2f(vv[i]), acc8[i]);
        }
        u16x8 pk;
#pragma unroll
        for (int i = 0; i < 8; ++i) pk[i] = f2b(acc8[i]);
        const int so = node * 512 + ((oct * 16) ^ ((node & 7) << 4));
        *(u16x8*)((char*)sA + so) = pk;
    }

    // ---- stage 3: oproj (K=256, 4 k-tiles, dbuf B staging) ----
    s16x8 breg[4];
#define WO_LOAD(KT)                                                           \
    {                                                                         \
        _Pragma("unroll")                                                     \
        for (int p = 0; p < 4; ++p) {                                         \
            const int lo = tid * 16 + p * 8192;                               \
            const int r = lo >> 7, c = lo & 127;                              \
            breg[p] = *(const s16x8*)((const char*)Wo_t + (size_t)r * 512 +   \
                                      (KT) * 128 + c);                        \
        }                                                                     \
    }
#define WO_STORE(BUF)                                                         \
    {                                                                         \
        _Pragma("unroll")                                                     \
        for (int p = 0; p < 4; ++p) {                                         \
            const int lo = tid * 16 + p * 8192;                               \
            const int r = lo >> 7, c = lo & 127;                              \
            const int so = (lo & ~127) | (c ^ ((r & 7) << 4));                \
            *(s16x8*)((char*)sB[BUF] + so) = breg[p];                         \
        }                                                                     \
    }

    WO_LOAD(0);
    WO_STORE(0);
    __syncthreads();     // also orders stage-2 sA writes before MFMA reads

    f32x4 acc[2] = {};
#pragma unroll
    for (int kt = 0; kt < 4; ++kt) {
        if (kt + 1 < 4) WO_LOAD(kt + 1);

        const char* sBc = (const char*)sB[kt & 1];
#pragma unroll
        for (int kk = 0; kk < 64; kk += 32) {
            const int lk = ((lane >> 4) << 3);
            s16x8 a;
            {
                const int r = lane & 15;
                const int koffb = (kt * 64 + kk + lk) * 2;
                a = *(const s16x8*)((const char*)sA + r * 512 +
                                    (koffb ^ ((r & 7) << 4)));
            }
            s16x8 bfr[2];
            const int boffb = (kk + lk) * 2;
#pragma unroll
            for (int n = 0; n < 2; ++n) {
                const int c = wave * 32 + n * 16 + (lane & 15);
                bfr[n] = *(const s16x8*)(sBc + c * 128 + (boffb ^ ((c & 7) << 4)));
            }
#pragma unroll
            for (int n = 0; n < 2; ++n)
                acc[n] = __builtin_amdgcn_mfma_f32_16x16x32_bf16(a, bfr[n], acc[n], 0, 0, 0);
        }

        if (kt + 1 < 4) {
            WO_STORE((kt + 1) & 1);
            __syncthreads();
        }
    }
#undef WO_LOAD
#undef WO_STORE

    // ---- LN1 epilogue (residual x) -> yb only ----
    const int rbase = ((lane >> 4) << 2);
    const int cbase = wave * 32 + (lane & 15);

    float sm[4] = {}, sq_[4] = {};
#pragma unroll
    for (int n = 0; n < 2; ++n) {
        const int c = cbase + n * 16;
        const float bv = bo[c];
#pragma unroll
        for (int j = 0; j < 4; ++j) {
            const int r = rbase + j;
            float v = acc[n][j] + bv + x[(size_t)(n0 + r) * HIDDEN + c];
            acc[n][j] = v;
            sm[j] += v;
            sq_[j] = fmaf(v, v, sq_[j]);
        }
    }
#pragma unroll
    for (int off = 8; off >= 1; off >>= 1) {
#pragma unroll
        for (int j = 0; j < 4; ++j) {
            sm[j] += __shfl_xor(sm[j], off);
            sq_[j] += __shfl_xor(sq_[j], off);
        }
    }
    if ((lane & 15) == 0) {
#pragma unroll
        for (int j = 0; j < 4; ++j) {
            rs[rbase + j][wave] = sm[j];
            rq[rbase + j][wave] = sq_[j];
        }
    }
    __syncthreads();

#pragma unroll
    for (int j = 0; j < 4; ++j) {
        const int r = rbase + j;
        float tot = 0.f, totq = 0.f;
#pragma unroll
        for (int w = 0; w < 8; ++w) { tot += rs[r][w]; totq += rq[r][w]; }
        const float mean = tot * (1.f / HIDDEN);
        const float var  = totq * (1.f / HIDDEN) - mean * mean;
        const float inv  = rsqrtf(var + LN_EPS);
#pragma unroll
        for (int n = 0; n < 2; ++n) {
            const int c = cbase + n * 16;
            const float res = (acc[n][j] - mean) * inv * g[c] + b[c];
            yb[(size_t)(n0 + r) * HIDDEN + c] = f2b(res);
        }
    }
}

// ---------------------------------------------------------------------------
extern "C" void kernel_launch(void* const* d_in, const int* in_sizes, int n_in,
                              void* d_out, int out_size, void* d_ws, size_t ws_size,
                              hipStream_t stream) {
    const float* x   = (const float*)d_in[0];
    const int*   ei  = (const int*)d_in[1];
    const float* ea  = (const float*)d_in[2];
    const float* Wq  = (const float*)d_in[3];
    const float* bq  = (const float*)d_in[4];
    const float* Wk  = (const float*)d_in[5];
    const float* bk  = (const float*)d_in[6];
    const float* Wv  = (const float*)d_in[7];
    const float* bv  = (const float*)d_in[8];
    const float* Wo  = (const float*)d_in[9];
    const float* bo  = (const float*)d_in[10];
    const float* We  = (const float*)d_in[11];
    const float* be  = (const float*)d_in[12];
    const float* g1  = (const float*)d_in[13];
    const float* b1  = (const float*)d_in[14];
    const float* g2  = (const float*)d_in[15];
    const float* b2  = (const float*)d_in[16];
    const float* Wf1 = (const float*)d_in[17];
    const float* bf1 = (const float*)d_in[18];
    const float* Wf2 = (const float*)d_in[19];
    const float* bf2 = (const float*)d_in[20];

    // ---- workspace layout (all write-before-read within each call) ----
    char* W = (char*)d_ws;
    unsigned short* Wqkv_t  = (unsigned short*)(W + (2u << 20));                // 384KB
    unsigned short* Wo_t    = (unsigned short*)(W + (2u << 20) + 384 * 1024);   // 128KB
    unsigned short* Wf1_t   = (unsigned short*)(W + (2u << 20) + 512 * 1024);   // 512KB
    unsigned short* Wf2_t   = (unsigned short*)(W + (2u << 20) + 1024 * 1024);  // 512KB
    float*          bias768 = (float*)(W + (2u << 20) + 1536 * 1024);           // 3KB
    unsigned short* qkvb    = (unsigned short*)(W + (4u << 20));                // 6MB (dead after attn_oproj)
    unsigned short* h1b     = (unsigned short*)(W + (4u << 20));                // 8MB (reuses qkvb region)
    unsigned short* yb      = (unsigned short*)(W + (16u << 20));               // 2MB
    float*          part    = (float*)(W + (20u << 20));                        // 8MB [2][4096][256]

    const dim3 blk(256);

    pack_kernel<<<193, blk, 0, stream>>>(Wq, Wk, Wv, Wo, Wf1, Wf2, bq, bk, bv,
                                         Wqkv_t, Wo_t, Wf1_t, Wf2_t, bias768);

    gemm_qkv<<<512, blk, 0, stream>>>(x, Wqkv_t, bias768, qkvb);

    // attention + O-proj + residual(x) + LN1 -> yb (bf16)
    attn_oproj_ln<<<N_NODES / 16, dim3(512), 0, stream>>>(
        qkvb, ei + NEDGE, ea, We, be, Wo_t, bo, x, g1, b1, yb);

    // FFN1 + ReLU -> h1b (bf16)   [512 blocks, 64x128 tile, XCD-swizzled]
    gemm_ffn1<<<512, blk, 0, stream>>>(yb, Wf1_t, bf1, h1b);

    // FFN2 K-split x2 -> fp32 partials  [512 blocks, XCD-swizzled]
    gemm_partial<<<512, blk, 0, stream>>>(h1b, Wf2_t, part);

    // sum partials + residual(yb) + LN2 -> d_out  [512 blocks]
    ln2_reduce<<<N_NODES / 8, blk, 0, stream>>>(part, yb, bf2, g2, b2, (float*)d_out);
}